// Round 2
// baseline (5958.222 us; speedup 1.0000x reference)
//
#include <hip/hip_runtime.h>
#include <math.h>

#define Bsz 2048

__device__ __forceinline__ float fast_tanh(float x){
    float e = __expf(2.0f * x);
    return 1.0f - 2.0f / (e + 1.0f);
}
__device__ __forceinline__ float fast_sigmoid(float x){
    return 1.0f / (1.0f + __expf(-x));
}

// ===================== fused encoder: x -> z1 (one block per image) ========
// LDS ping-pong: H0 (21632 f) <-> H1 (18432 f). Total 160,256 B.
__global__ void __launch_bounds__(256)
k_enc(const float* __restrict__ x,
      const float* __restrict__ c0w, const float* __restrict__ c0b,
      const float* __restrict__ c1w, const float* __restrict__ c1b,
      const float* __restrict__ c2w, const float* __restrict__ c2b,
      const float* __restrict__ elw, const float* __restrict__ elb,
      float* __restrict__ z1){
    __shared__ float H0[21632];
    __shared__ float H1[18432];
    const int tid = threadIdx.x, b = blockIdx.x;
    const int lane = tid & 63;
    const int cog = __builtin_amdgcn_readfirstlane(tid >> 6);  // wave-uniform co-octet

    // stage x (28x28) into H1 head
    for (int i = tid; i < 784; i += 256) H1[i] = x[b*784 + i];
    __syncthreads();

    // conv0: 1->32, out 26x26 -> H0[co*676 + pos]
    for (int pos = tid; pos < 676; pos += 256){
        int y = pos / 26, xx = pos - y*26;
        float v[9];
#pragma unroll
        for (int r = 0; r < 3; r++)
#pragma unroll
            for (int s = 0; s < 3; s++)
                v[r*3+s] = H1[(y+r)*28 + xx + s];
#pragma unroll
        for (int co = 0; co < 32; co++){
            float a = c0b[co];
#pragma unroll
            for (int k = 0; k < 9; k++) a += v[k] * c0w[co*9 + k];
            H0[co*676 + pos] = fast_tanh(a);
        }
    }
    __syncthreads();

    // conv1: 32->32, out 24x24 -> H1[co*576 + pos]; wave handles co octet `cog`
    for (int pos = lane; pos < 576; pos += 64){
        int y = pos / 24, xx = pos - y*24;
        float acc[8];
#pragma unroll
        for (int u = 0; u < 8; u++) acc[u] = c1b[cog*8 + u];
#pragma unroll 1
        for (int ci = 0; ci < 32; ci++){
            const float* hp = &H0[ci*676 + y*26 + xx];
            float v[9];
#pragma unroll
            for (int r = 0; r < 3; r++)
#pragma unroll
                for (int s = 0; s < 3; s++)
                    v[r*3+s] = hp[r*26 + s];
            const float* wp = c1w + cog*8*288 + ci*9;   // ((cog*8+u)*32+ci)*9
#pragma unroll
            for (int u = 0; u < 8; u++)
#pragma unroll
                for (int k = 0; k < 9; k++)
                    acc[u] += v[k] * wp[u*288 + k];
        }
#pragma unroll
        for (int u = 0; u < 8; u++)
            H1[(cog*8+u)*576 + pos] = fast_tanh(acc[u]);
    }
    __syncthreads();

    // conv2: 32->32, out 22x22 -> H0[co*484 + pos]
    for (int pos = lane; pos < 484; pos += 64){
        int y = pos / 22, xx = pos - y*22;
        float acc[8];
#pragma unroll
        for (int u = 0; u < 8; u++) acc[u] = c2b[cog*8 + u];
#pragma unroll 1
        for (int ci = 0; ci < 32; ci++){
            const float* hp = &H1[ci*576 + y*24 + xx];
            float v[9];
#pragma unroll
            for (int r = 0; r < 3; r++)
#pragma unroll
                for (int s = 0; s < 3; s++)
                    v[r*3+s] = hp[r*24 + s];
            const float* wp = c2w + cog*8*288 + ci*9;
#pragma unroll
            for (int u = 0; u < 8; u++)
#pragma unroll
                for (int k = 0; k < 9; k++)
                    acc[u] += v[k] * wp[u*288 + k];
        }
#pragma unroll
        for (int u = 0; u < 8; u++)
            H0[(cog*8+u)*484 + pos] = fast_tanh(acc[u]);
    }
    __syncthreads();

    // encoder GEMV: z1[b,l] = elb[l] + sum_f H0[f] * elw[f*16+l]
    {
        int fg = tid >> 4, l = tid & 15;
        float a0 = 0.f, a1 = 0.f, a2 = 0.f, a3 = 0.f;
        for (int f = fg; f < 15488; f += 64){           // 15488 = 64*242 exactly
            a0 += H0[f]      * elw[ f      *16 + l];
            a1 += H0[f + 16] * elw[(f + 16)*16 + l];
            a2 += H0[f + 32] * elw[(f + 32)*16 + l];
            a3 += H0[f + 48] * elw[(f + 48)*16 + l];
        }
        float acc = (a0 + a1) + (a2 + a3);
        __syncthreads();                                // conv2 reads of H1 done long ago; H0 reads done
        H1[fg*17 + l] = acc;
        __syncthreads();
        if (tid < 16){
            float s = elb[tid];
#pragma unroll
            for (int g = 0; g < 16; g++) s += H1[g*17 + tid];
            z1[b*16 + tid] = s;
        }
    }
}

// ===================== fused decoder: z1 -> recon (one block per image) ====
__global__ void __launch_bounds__(256)
k_dec(const float* __restrict__ z1,
      const float* __restrict__ dlw, const float* __restrict__ dlb,
      const float* __restrict__ t0w, const float* __restrict__ t0b,
      const float* __restrict__ t1w, const float* __restrict__ t1b,
      const float* __restrict__ t2w, const float* __restrict__ t2b,
      float* __restrict__ out){
    __shared__ float D0[21632];   // d0 (15488) then d2 (21632)
    __shared__ float D1[18432];   // d1
    const int tid = threadIdx.x, b = blockIdx.x;
    const int lane = tid & 63;
    const int cog = __builtin_amdgcn_readfirstlane(tid >> 6);

    float zz[16];
#pragma unroll
    for (int l = 0; l < 16; l++) zz[l] = z1[b*16 + l];  // uniform -> s_loads

    // decoder GEMV: D0[f] = tanh(dlb[f] + sum_l zz[l]*dlw[l*15488+f])
    for (int f = tid; f < 15488; f += 256){
        float a = dlb[f];
#pragma unroll
        for (int l = 0; l < 16; l++) a += zz[l] * dlw[l*15488 + f];
        D0[f] = fast_tanh(a);
    }
    __syncthreads();

    // convT0: in 22x22 (D0), out 24x24 -> D1[co*576+pos]
    for (int pos = lane; pos < 576; pos += 64){
        int y = pos / 24, xx = pos - y*24;
        float acc[8];
#pragma unroll
        for (int u = 0; u < 8; u++) acc[u] = t0b[cog*8 + u];
#pragma unroll 1
        for (int ci = 0; ci < 32; ci++){
            float v[9];
#pragma unroll
            for (int r = 0; r < 3; r++)
#pragma unroll
                for (int s = 0; s < 3; s++){
                    int iy = y + r - 2, ix = xx + s - 2;
                    v[r*3+s] = ((unsigned)iy < 22u && (unsigned)ix < 22u)
                             ? D0[ci*484 + iy*22 + ix] : 0.f;
                }
            const float* wp = t0w + ci*288 + cog*72;    // (ci*32 + cog*8+u)*9
#pragma unroll
            for (int u = 0; u < 8; u++)
#pragma unroll
                for (int r = 0; r < 3; r++)
#pragma unroll
                    for (int s = 0; s < 3; s++)
                        acc[u] += v[r*3+s] * wp[u*9 + (2-r)*3 + (2-s)];
        }
#pragma unroll
        for (int u = 0; u < 8; u++)
            D1[(cog*8+u)*576 + pos] = fast_tanh(acc[u]);
    }
    __syncthreads();

    // convT1: in 24x24 (D1), out 26x26 -> D0[co*676+pos]
    for (int pos = lane; pos < 676; pos += 64){
        int y = pos / 26, xx = pos - y*26;
        float acc[8];
#pragma unroll
        for (int u = 0; u < 8; u++) acc[u] = t1b[cog*8 + u];
#pragma unroll 1
        for (int ci = 0; ci < 32; ci++){
            float v[9];
#pragma unroll
            for (int r = 0; r < 3; r++)
#pragma unroll
                for (int s = 0; s < 3; s++){
                    int iy = y + r - 2, ix = xx + s - 2;
                    v[r*3+s] = ((unsigned)iy < 24u && (unsigned)ix < 24u)
                             ? D1[ci*576 + iy*24 + ix] : 0.f;
                }
            const float* wp = t1w + ci*288 + cog*72;
#pragma unroll
            for (int u = 0; u < 8; u++)
#pragma unroll
                for (int r = 0; r < 3; r++)
#pragma unroll
                    for (int s = 0; s < 3; s++)
                        acc[u] += v[r*3+s] * wp[u*9 + (2-r)*3 + (2-s)];
        }
#pragma unroll
        for (int u = 0; u < 8; u++)
            D0[(cog*8+u)*676 + pos] = fast_tanh(acc[u]);
    }
    __syncthreads();

    // convT_out: in 26x26 (D0), out 28x28 -> global
    for (int o = tid; o < 784; o += 256){
        int y = o / 28, xx = o - y*28;
        float a = t2b[0];
#pragma unroll 1
        for (int ci = 0; ci < 32; ci++){
#pragma unroll
            for (int r = 0; r < 3; r++)
#pragma unroll
                for (int s = 0; s < 3; s++){
                    int iy = y + r - 2, ix = xx + s - 2;
                    if ((unsigned)iy < 26u && (unsigned)ix < 26u)
                        a += D0[ci*676 + iy*26 + ix] * t2w[ci*9 + (2-r)*3 + (2-s)];
                }
        }
        out[(size_t)b*784 + o] = a;
    }
}

// ===================== hypernetwork: 80 stages of (W, Ut, Bb, strace) ======
// per-stage layout (stride 2176): [0,1024)=W[w*16+d], [1024,2048)=Ut[d*64+w],
//                                 [2048,2112)=Bb[w],  [2112,2176)=strace[w]
__global__ void k_hyper(const float* __restrict__ h1w, const float* __restrict__ h1b,
                        const float* __restrict__ h2w, const float* __restrict__ h2b,
                        const float* __restrict__ h3w, const float* __restrict__ h3b,
                        float* __restrict__ hyp){
    int sidx = blockIdx.x;               // 0..79
    int i  = sidx >> 2, st = sidx & 3;
    float t = 10.0f - 0.5f * (float)i;   // dt = -0.5
    if (st == 1 || st == 2) t -= 0.25f;
    else if (st == 3)       t -= 0.5f;
    __shared__ float p1[64], p2[64];
    __shared__ float p3[3136];
    int tid = threadIdx.x;
    if (tid < 64) p1[tid] = fast_tanh(t * h1w[tid] + h1b[tid]);
    __syncthreads();
    if (tid < 64){
        float a = h2b[tid];
#pragma unroll
        for (int k = 0; k < 64; k++) a += p1[k] * h2w[k*64 + tid];
        p2[tid] = fast_tanh(a);
    }
    __syncthreads();
    for (int m = tid; m < 3136; m += 256){
        float a = h3b[m];
#pragma unroll
        for (int k = 0; k < 64; k++) a += p2[k] * h3w[k*3136 + m];
        p3[m] = a;
    }
    __syncthreads();
    float* g = hyp + sidx * 2176;
    for (int m = tid; m < 1024; m += 256){
        g[m] = p3[m];                                   // W
        float u = p3[1024 + m] * fast_sigmoid(p3[2048 + m]);
        g[1024 + (m & 15)*64 + (m >> 4)] = u;           // Ut (transposed)
        p3[1024 + m] = u;                               // keep U for strace
    }
    if (tid < 64) g[2048 + tid] = p3[3072 + tid];       // Bb
    __syncthreads();
    if (tid < 64){
        float s = 0.f;
#pragma unroll
        for (int d = 0; d < 16; d++) s += p3[tid*16 + d] * p3[1024 + tid*16 + d];
        g[2112 + tid] = s;                              // strace[w] = sum_d W*U
    }
}

// ===================== CNF RK4: 8 batch rows / block, 128 threads ==========
__global__ void __launch_bounds__(128)
k_cnf(const float* __restrict__ z1, const float* __restrict__ hyp,
      float* __restrict__ part){
    __shared__ float Wl[64*17];
    __shared__ __align__(16) float Utl[16*68];
    __shared__ __align__(16) float hhl[8*68];
    __shared__ float zsl[8*17];
    __shared__ float Bbl[64];
    __shared__ __align__(16) float sl[64];
    __shared__ float red[8];

    int tid  = threadIdx.x;
    int bloc = tid >> 4, d = tid & 15;
    int bglob = blockIdx.x * 8 + bloc;
    const float dt = -0.5f;

    float z  = z1[bglob*16 + d];
    float zs = z;
    float lp = 0.f;

    for (int step = 0; step < 20; step++){
        float zacc = 0.f, lacc = 0.f;
#pragma unroll 1
        for (int st = 0; st < 4; st++){
            __syncthreads();
            const float* g = hyp + (size_t)(step*4 + st) * 2176;
            for (int k = tid; k < 2176; k += 128){
                float v = g[k];
                if (k < 1024)       Wl[(k >> 4)*17 + (k & 15)] = v;
                else if (k < 2048){ int k2 = k - 1024; Utl[(k2 >> 6)*68 + (k2 & 63)] = v; }
                else if (k < 2112)  Bbl[k - 2048] = v;
                else                sl[k - 2112] = v;
            }
            zsl[bloc*17 + d] = zs;
            __syncthreads();
#pragma unroll
            for (int r = 0; r < 4; r++){
                int task = tid + r*128;
                int pb = task >> 6, pw = task & 63;
                float a = Bbl[pw];
#pragma unroll
                for (int dd = 0; dd < 16; dd++)
                    a += zsl[pb*17 + dd] * Wl[pw*17 + dd];
                hhl[pb*68 + pw] = fast_tanh(a);
            }
            __syncthreads();
            float dz = 0.f;
            const float4* h4p = (const float4*)(hhl + bloc*68);
            const float4* u4p = (const float4*)(Utl + d*68);
#pragma unroll
            for (int w4 = 0; w4 < 16; w4++){
                float4 h = h4p[w4], u = u4p[w4];
                dz += h.x*u.x + h.y*u.y + h.z*u.z + h.w*u.w;
            }
            float4 hh4 = h4p[d];
            float4 s4  = ((const float4*)sl)[d];
            float tr = (1.f - hh4.x*hh4.x)*s4.x + (1.f - hh4.y*hh4.y)*s4.y
                     + (1.f - hh4.z*hh4.z)*s4.z + (1.f - hh4.w*hh4.w)*s4.w;
#pragma unroll
            for (int off = 1; off < 16; off <<= 1)
                tr += __shfl_xor(tr, off, 16);
            dz *= (1.f/64.f);
            float dl = -tr * (1.f/64.f);
            float wgt = (st == 0 || st == 3) ? 1.f : 2.f;
            zacc += wgt * dz;
            lacc += wgt * dl;
            if (st < 3){
                float a = (st == 2) ? 1.0f : 0.5f;
                zs = z + a * dt * dz;
            }
        }
        z  += (dt/6.f) * zacc;
        lp += (dt/6.f) * lacc;
        zs = z;
    }
    float sq = z * z;
#pragma unroll
    for (int off = 1; off < 16; off <<= 1) sq += __shfl_xor(sq, off, 16);
    float logp = -0.5f * (16.f*1.8378770664093453f + 16.f*(-2.302585092994046f) + sq*10.f);
    float contrib = logp - lp;
    if (d == 0) red[bloc] = contrib;
    __syncthreads();
    if (tid == 0){
        float p = 0.f;
#pragma unroll
        for (int j = 0; j < 8; j++) p += red[j];
        part[blockIdx.x] = p;
    }
}

__global__ void k_final(const float* __restrict__ part, float* __restrict__ out){
    __shared__ float red[256];
    int tid = threadIdx.x;
    red[tid] = part[tid];
    __syncthreads();
    for (int s = 128; s > 0; s >>= 1){
        if (tid < s) red[tid] += red[tid + s];
        __syncthreads();
    }
    if (tid == 0) out[1605632] = red[0] * (1.f/2048.f);
}

extern "C" void kernel_launch(void* const* d_in, const int* in_sizes, int n_in,
                              void* d_out, int out_size, void* d_ws, size_t ws_size,
                              hipStream_t stream){
    const float* x   = (const float*)d_in[0];
    const float* c0w = (const float*)d_in[1];
    const float* c0b = (const float*)d_in[2];
    const float* c1w = (const float*)d_in[3];
    const float* c1b = (const float*)d_in[4];
    const float* c2w = (const float*)d_in[5];
    const float* c2b = (const float*)d_in[6];
    const float* elw = (const float*)d_in[7];
    const float* elb = (const float*)d_in[8];
    const float* dlw = (const float*)d_in[9];
    const float* dlb = (const float*)d_in[10];
    const float* t0w = (const float*)d_in[11];
    const float* t0b = (const float*)d_in[12];
    const float* t1w = (const float*)d_in[13];
    const float* t1b = (const float*)d_in[14];
    const float* t2w = (const float*)d_in[15];
    const float* t2b = (const float*)d_in[16];
    const float* h1w = (const float*)d_in[17];
    const float* h1b = (const float*)d_in[18];
    const float* h2w = (const float*)d_in[19];
    const float* h2b = (const float*)d_in[20];
    const float* h3w = (const float*)d_in[21];
    const float* h3b = (const float*)d_in[22];

    float* ws   = (float*)d_ws;
    float* z1   = ws;                 // 32,768 floats
    float* hyp  = z1 + 32768;         // 174,080 floats (80*2176)
    float* part = hyp + 174080;       // 256 floats          -> total ~828 KB
    float* rec  = (float*)d_out;

    k_hyper<<<80,   256, 0, stream>>>(h1w, h1b, h2w, h2b, h3w, h3b, hyp);
    k_enc  <<<2048, 256, 0, stream>>>(x, c0w, c0b, c1w, c1b, c2w, c2b, elw, elb, z1);
    k_cnf  <<<256,  128, 0, stream>>>(z1, hyp, part);
    k_dec  <<<2048, 256, 0, stream>>>(z1, dlw, dlb, t0w, t0b, t1w, t1b, t2w, t2b, rec);
    k_final<<<1,    256, 0, stream>>>(part, rec);
}

// Round 3
// 2392.238 us; speedup vs baseline: 2.4906x; 2.4906x over previous
//
#include <hip/hip_runtime.h>
#include <math.h>

#define Bsz 2048

using bf16x8 = __attribute__((ext_vector_type(8))) short;
using f32x4  = __attribute__((ext_vector_type(4))) float;

__device__ __forceinline__ float fast_tanh(float x){
    float e = __expf(2.0f * x);
    return 1.0f - 2.0f / (e + 1.0f);
}
__device__ __forceinline__ float fast_sigmoid(float x){
    return 1.0f / (1.0f + __expf(-x));
}
__device__ __forceinline__ unsigned short f2b(float f){
    union { float f; unsigned u; } v; v.f = f;
    unsigned r = v.u + 0x7FFFu + ((v.u >> 16) & 1u);
    return (unsigned short)(r >> 16);
}
__device__ __forceinline__ float b2f(unsigned short s){
    union { unsigned u; float f; } v; v.u = ((unsigned)s) << 16;
    return v.f;
}

// ===== weight prep: bf16 [shift][co][ci] for the four 32->32 layers ========
__global__ void k_prep(const float* __restrict__ c1w, const float* __restrict__ c2w,
                       const float* __restrict__ t0w, const float* __restrict__ t1w,
                       unsigned short* __restrict__ wc1, unsigned short* __restrict__ wc2,
                       unsigned short* __restrict__ wt0, unsigned short* __restrict__ wt1){
    for (int i = threadIdx.x; i < 9216; i += 256){
        int ci = i & 31, co = (i >> 5) & 31, s = i >> 10;   // i = s*1024 + co*32 + ci
        wc1[i] = f2b(c1w[(co*32 + ci)*9 + s]);
        wc2[i] = f2b(c2w[(co*32 + ci)*9 + s]);
        wt0[i] = f2b(t0w[(ci*32 + co)*9 + (8 - s)]);        // flip+transpose
        wt1[i] = f2b(t1w[(ci*32 + co)*9 + (8 - s)]);
    }
}

// ===== 9-shift MFMA conv GEMM over one image's LDS maps ====================
// in map: channel-last bf16, row stride INW pixels; out pixel = y*OUTW+x+OUTOFF
template<int LOUT, int INW, int OUTW, int OUTOFF>
__device__ __forceinline__ void conv_gemm(const unsigned short* __restrict__ Wg,
                                          const float* __restrict__ bias,
                                          const unsigned short* inL,
                                          unsigned short* outL, int tid){
    constexpr int N  = LOUT * LOUT;
    constexpr int NT = (N + 15) / 16;
    const int lane  = tid & 63;
    const int wave  = tid >> 6;
    const int mtile = wave & 1;
    const int quad  = lane >> 4;
    const int nn    = lane & 15;

    bf16x8 afr[9];
    const unsigned short* wp = Wg + (mtile*16 + nn)*32 + quad*8;
#pragma unroll
    for (int s = 0; s < 9; s++)
        afr[s] = *(const bf16x8*)(wp + s*1024);
    float4 bco = *(const float4*)(bias + mtile*16 + quad*4);

    for (int t = (wave >> 1); t < NT; t += 2){
        int pos = t*16 + nn;
        int pc  = pos < N ? pos : N - 1;
        int y = pc / LOUT, x = pc - y*LOUT;
        const unsigned short* ib = inL + (y*INW + x)*32 + quad*8;
        f32x4 acc = {0.f, 0.f, 0.f, 0.f};
#pragma unroll
        for (int r = 0; r < 3; r++)
#pragma unroll
            for (int s = 0; s < 3; s++)
                acc = __builtin_amdgcn_mfma_f32_16x16x32_bf16(
                        afr[r*3+s], *(const bf16x8*)(ib + (r*INW + s)*32), acc, 0, 0, 0);
        if (pos < N){
            ushort4 o;
            o.x = f2b(fast_tanh(acc[0] + bco.x));
            o.y = f2b(fast_tanh(acc[1] + bco.y));
            o.z = f2b(fast_tanh(acc[2] + bco.z));
            o.w = f2b(fast_tanh(acc[3] + bco.w));
            int opix = y*OUTW + x + OUTOFF;
            *(ushort4*)(outL + opix*32 + mtile*16 + quad*4) = o;
        }
    }
}

// ===== fused encoder: x -> z1 ==============================================
__global__ void __launch_bounds__(256)
k_enc(const float* __restrict__ x,
      const float* __restrict__ c0w, const float* __restrict__ c0b,
      const unsigned short* __restrict__ wc1, const float* __restrict__ c1b,
      const unsigned short* __restrict__ wc2, const float* __restrict__ c2b,
      const float* __restrict__ elw, const float* __restrict__ elb,
      float* __restrict__ z1){
    __shared__ float X[784];
    __shared__ __align__(16) unsigned short H0[21632];   // 26*26*32
    __shared__ __align__(16) unsigned short H1[18432];   // 24*24*32
    __shared__ __align__(16) unsigned short H2[15488];   // 22*22*32
    __shared__ float red[16*17];
    const int tid = threadIdx.x, b = blockIdx.x;

    for (int i = tid; i < 784; i += 256) X[i] = x[b*784 + i];
    __syncthreads();

    // conv0: 1->32, 26x26, fp32 VALU, write bf16 channel-last
    for (int pos = tid; pos < 676; pos += 256){
        int y = pos / 26, xx = pos - y*26;
        float v[9];
#pragma unroll
        for (int r = 0; r < 3; r++)
#pragma unroll
            for (int s = 0; s < 3; s++)
                v[r*3+s] = X[(y+r)*28 + xx + s];
#pragma unroll
        for (int g = 0; g < 8; g++){
            float a0 = c0b[g*4+0], a1 = c0b[g*4+1], a2 = c0b[g*4+2], a3 = c0b[g*4+3];
#pragma unroll
            for (int k = 0; k < 9; k++){
                a0 += v[k] * c0w[(g*4+0)*9 + k];
                a1 += v[k] * c0w[(g*4+1)*9 + k];
                a2 += v[k] * c0w[(g*4+2)*9 + k];
                a3 += v[k] * c0w[(g*4+3)*9 + k];
            }
            ushort4 o;
            o.x = f2b(fast_tanh(a0)); o.y = f2b(fast_tanh(a1));
            o.z = f2b(fast_tanh(a2)); o.w = f2b(fast_tanh(a3));
            *(ushort4*)(H0 + pos*32 + g*4) = o;
        }
    }
    __syncthreads();
    conv_gemm<24, 26, 24, 0>(wc1, c1b, H0, H1, tid);
    __syncthreads();
    conv_gemm<22, 24, 22, 0>(wc2, c2b, H1, H2, tid);
    __syncthreads();

    // encoder GEMV: z1[l] = elb[l] + sum_{ci,pos} h2 * elw[(ci*484+pos)*16+l]
    {
        int fg = tid >> 4, l = tid & 15;
        float a = 0.f;
        for (int ci = 0; ci < 32; ci++)
            for (int pos = fg; pos < 484; pos += 16)
                a += b2f(H2[pos*32 + ci]) * elw[(ci*484 + pos)*16 + l];
        red[fg*17 + l] = a;
        __syncthreads();
        if (tid < 16){
            float s = elb[tid];
#pragma unroll
            for (int g = 0; g < 16; g++) s += red[g*17 + tid];
            z1[b*16 + tid] = s;
        }
    }
}

// ===== fused decoder: z1 -> recon ==========================================
__global__ void __launch_bounds__(256)
k_dec(const float* __restrict__ z1,
      const float* __restrict__ dlw, const float* __restrict__ dlb,
      const unsigned short* __restrict__ wt0, const float* __restrict__ t0b,
      const unsigned short* __restrict__ wt1, const float* __restrict__ t1b,
      const float* __restrict__ t2w, const float* __restrict__ t2b,
      float* __restrict__ out){
    __shared__ __align__(16) unsigned short D0[21632];   // 22x22 in 26x26 pad
    __shared__ __align__(16) unsigned short D1[25088];   // 24x24 in 28x28 pad
    __shared__ __align__(16) unsigned short D2[28800];   // 26x26 in 30x30 pad
    const int tid = threadIdx.x, b = blockIdx.x;

    {   // zero-init all maps (pads must be 0)
        uint4 zq = {0,0,0,0};
        for (int i = tid; i < 2704; i += 256) ((uint4*)D0)[i] = zq;
        for (int i = tid; i < 3136; i += 256) ((uint4*)D1)[i] = zq;
        for (int i = tid; i < 3600; i += 256) ((uint4*)D2)[i] = zq;
    }
    float zz[16];
#pragma unroll
    for (int l = 0; l < 16; l++) zz[l] = z1[b*16 + l];
    __syncthreads();

    // decoder GEMV -> D0 interior (channel-last bf16)
    for (int f = tid; f < 15488; f += 256){
        float a = dlb[f];
#pragma unroll
        for (int l = 0; l < 16; l++) a += zz[l] * dlw[l*15488 + f];
        int ci = f / 484, pos = f - ci*484;
        int y = pos / 22, xx = pos - y*22;
        D0[((y+2)*26 + xx + 2)*32 + ci] = f2b(fast_tanh(a));
    }
    __syncthreads();
    conv_gemm<24, 26, 28, 58>(wt0, t0b, D0, D1, tid);   // out 24x24 into 28-pad
    __syncthreads();
    conv_gemm<26, 28, 30, 62>(wt1, t1b, D1, D2, tid);   // out 26x26 into 30-pad
    __syncthreads();

    // convT2: 32->1, out 28x28 fp32
    for (int o = tid; o < 784; o += 256){
        int y = o / 28, xx = o - y*28;
        float a = t2b[0];
#pragma unroll
        for (int r = 0; r < 3; r++)
#pragma unroll
            for (int s = 0; s < 3; s++){
                const unsigned short* pp = D2 + ((y+r)*30 + xx + s)*32;
                int wi = (2-r)*3 + (2-s);
#pragma unroll
                for (int g = 0; g < 4; g++){
                    bf16x8 h = *(const bf16x8*)(pp + g*8);
#pragma unroll
                    for (int j = 0; j < 8; j++)
                        a += b2f((unsigned short)h[j]) * t2w[(g*8+j)*9 + wi];
                }
            }
        out[(size_t)b*784 + o] = a;
    }
}

// ===== hypernetwork: 80 stages of (W, Ut, Bb, strace) ======================
__global__ void k_hyper(const float* __restrict__ h1w, const float* __restrict__ h1b,
                        const float* __restrict__ h2w, const float* __restrict__ h2b,
                        const float* __restrict__ h3w, const float* __restrict__ h3b,
                        float* __restrict__ hyp){
    int sidx = blockIdx.x;
    int i  = sidx >> 2, st = sidx & 3;
    float t = 10.0f - 0.5f * (float)i;
    if (st == 1 || st == 2) t -= 0.25f;
    else if (st == 3)       t -= 0.5f;
    __shared__ float p1[64], p2[64];
    __shared__ float p3[3136];
    int tid = threadIdx.x;
    if (tid < 64) p1[tid] = fast_tanh(t * h1w[tid] + h1b[tid]);
    __syncthreads();
    if (tid < 64){
        float a = h2b[tid];
#pragma unroll
        for (int k = 0; k < 64; k++) a += p1[k] * h2w[k*64 + tid];
        p2[tid] = fast_tanh(a);
    }
    __syncthreads();
    for (int m = tid; m < 3136; m += 256){
        float a = h3b[m];
#pragma unroll
        for (int k = 0; k < 64; k++) a += p2[k] * h3w[k*3136 + m];
        p3[m] = a;
    }
    __syncthreads();
    float* g = hyp + sidx * 2176;
    for (int m = tid; m < 1024; m += 256){
        g[m] = p3[m];
        float u = p3[1024 + m] * fast_sigmoid(p3[2048 + m]);
        g[1024 + (m & 15)*64 + (m >> 4)] = u;
        p3[1024 + m] = u;
    }
    if (tid < 64) g[2048 + tid] = p3[3072 + tid];
    __syncthreads();
    if (tid < 64){
        float s = 0.f;
#pragma unroll
        for (int d = 0; d < 16; d++) s += p3[tid*16 + d] * p3[1024 + tid*16 + d];
        g[2112 + tid] = s;
    }
}

// ===== CNF RK4: 8 batch rows / block, 128 threads ==========================
__global__ void __launch_bounds__(128)
k_cnf(const float* __restrict__ z1, const float* __restrict__ hyp,
      float* __restrict__ part){
    __shared__ float Wl[64*17];
    __shared__ __align__(16) float Utl[16*68];
    __shared__ __align__(16) float hhl[8*68];
    __shared__ float zsl[8*17];
    __shared__ float Bbl[64];
    __shared__ __align__(16) float sl[64];
    __shared__ float red[8];

    int tid  = threadIdx.x;
    int bloc = tid >> 4, d = tid & 15;
    int bglob = blockIdx.x * 8 + bloc;
    const float dt = -0.5f;

    float z  = z1[bglob*16 + d];
    float zs = z;
    float lp = 0.f;

    for (int step = 0; step < 20; step++){
        float zacc = 0.f, lacc = 0.f;
#pragma unroll 1
        for (int st = 0; st < 4; st++){
            __syncthreads();
            const float* g = hyp + (size_t)(step*4 + st) * 2176;
            for (int k = tid; k < 2176; k += 128){
                float v = g[k];
                if (k < 1024)       Wl[(k >> 4)*17 + (k & 15)] = v;
                else if (k < 2048){ int k2 = k - 1024; Utl[(k2 >> 6)*68 + (k2 & 63)] = v; }
                else if (k < 2112)  Bbl[k - 2048] = v;
                else                sl[k - 2112] = v;
            }
            zsl[bloc*17 + d] = zs;
            __syncthreads();
#pragma unroll
            for (int r = 0; r < 4; r++){
                int task = tid + r*128;
                int pb = task >> 6, pw = task & 63;
                float a = Bbl[pw];
#pragma unroll
                for (int dd = 0; dd < 16; dd++)
                    a += zsl[pb*17 + dd] * Wl[pw*17 + dd];
                hhl[pb*68 + pw] = fast_tanh(a);
            }
            __syncthreads();
            float dz = 0.f;
            const float4* h4p = (const float4*)(hhl + bloc*68);
            const float4* u4p = (const float4*)(Utl + d*68);
#pragma unroll
            for (int w4 = 0; w4 < 16; w4++){
                float4 h = h4p[w4], u = u4p[w4];
                dz += h.x*u.x + h.y*u.y + h.z*u.z + h.w*u.w;
            }
            float4 hh4 = h4p[d];
            float4 s4  = ((const float4*)sl)[d];
            float tr = (1.f - hh4.x*hh4.x)*s4.x + (1.f - hh4.y*hh4.y)*s4.y
                     + (1.f - hh4.z*hh4.z)*s4.z + (1.f - hh4.w*hh4.w)*s4.w;
#pragma unroll
            for (int off = 1; off < 16; off <<= 1)
                tr += __shfl_xor(tr, off, 16);
            dz *= (1.f/64.f);
            float dl = -tr * (1.f/64.f);
            float wgt = (st == 0 || st == 3) ? 1.f : 2.f;
            zacc += wgt * dz;
            lacc += wgt * dl;
            if (st < 3){
                float a = (st == 2) ? 1.0f : 0.5f;
                zs = z + a * dt * dz;
            }
        }
        z  += (dt/6.f) * zacc;
        lp += (dt/6.f) * lacc;
        zs = z;
    }
    float sq = z * z;
#pragma unroll
    for (int off = 1; off < 16; off <<= 1) sq += __shfl_xor(sq, off, 16);
    float logp = -0.5f * (16.f*1.8378770664093453f + 16.f*(-2.302585092994046f) + sq*10.f);
    float contrib = logp - lp;
    if (d == 0) red[bloc] = contrib;
    __syncthreads();
    if (tid == 0){
        float p = 0.f;
#pragma unroll
        for (int j = 0; j < 8; j++) p += red[j];
        part[blockIdx.x] = p;
    }
}

__global__ void k_final(const float* __restrict__ part, float* __restrict__ out){
    __shared__ float red[256];
    int tid = threadIdx.x;
    red[tid] = part[tid];
    __syncthreads();
    for (int s = 128; s > 0; s >>= 1){
        if (tid < s) red[tid] += red[tid + s];
        __syncthreads();
    }
    if (tid == 0) out[1605632] = red[0] * (1.f/2048.f);
}

extern "C" void kernel_launch(void* const* d_in, const int* in_sizes, int n_in,
                              void* d_out, int out_size, void* d_ws, size_t ws_size,
                              hipStream_t stream){
    const float* x   = (const float*)d_in[0];
    const float* c0w = (const float*)d_in[1];
    const float* c0b = (const float*)d_in[2];
    const float* c1w = (const float*)d_in[3];
    const float* c1b = (const float*)d_in[4];
    const float* c2w = (const float*)d_in[5];
    const float* c2b = (const float*)d_in[6];
    const float* elw = (const float*)d_in[7];
    const float* elb = (const float*)d_in[8];
    const float* dlw = (const float*)d_in[9];
    const float* dlb = (const float*)d_in[10];
    const float* t0w = (const float*)d_in[11];
    const float* t0b = (const float*)d_in[12];
    const float* t1w = (const float*)d_in[13];
    const float* t1b = (const float*)d_in[14];
    const float* t2w = (const float*)d_in[15];
    const float* t2b = (const float*)d_in[16];
    const float* h1w = (const float*)d_in[17];
    const float* h1b = (const float*)d_in[18];
    const float* h2w = (const float*)d_in[19];
    const float* h2b = (const float*)d_in[20];
    const float* h3w = (const float*)d_in[21];
    const float* h3b = (const float*)d_in[22];

    float* ws   = (float*)d_ws;
    float* z1   = ws;                 // 32768 floats
    float* hyp  = z1 + 32768;         // 174080 floats
    float* part = hyp + 174080;       // 256 floats
    unsigned short* wc1 = (unsigned short*)(part + 256);
    unsigned short* wc2 = wc1 + 9216;
    unsigned short* wt0 = wc2 + 9216;
    unsigned short* wt1 = wt0 + 9216;  // total ws ~902 KB
    float* rec  = (float*)d_out;

    k_prep <<<1,    256, 0, stream>>>(c1w, c2w, t0w, t1w, wc1, wc2, wt0, wt1);
    k_hyper<<<80,   256, 0, stream>>>(h1w, h1b, h2w, h2b, h3w, h3b, hyp);
    k_enc  <<<2048, 256, 0, stream>>>(x, c0w, c0b, wc1, c1b, wc2, c2b, elw, elb, z1);
    k_cnf  <<<256,  128, 0, stream>>>(z1, hyp, part);
    k_dec  <<<2048, 256, 0, stream>>>(z1, dlw, dlb, wt0, t0b, wt1, t1b, t2w, t2b, rec);
    k_final<<<1,    256, 0, stream>>>(part, rec);
}

// Round 4
// 1258.947 us; speedup vs baseline: 4.7327x; 1.9002x over previous
//
#include <hip/hip_runtime.h>
#include <math.h>

#define Bsz 2048

using bf16x8 = __attribute__((ext_vector_type(8))) short;
using f32x4  = __attribute__((ext_vector_type(4))) float;

__device__ __forceinline__ float fast_tanh(float x){
    float e = __expf(2.0f * x);
    return 1.0f - 2.0f / (e + 1.0f);
}
__device__ __forceinline__ float fast_sigmoid(float x){
    return 1.0f / (1.0f + __expf(-x));
}
__device__ __forceinline__ unsigned short f2b(float f){
    union { float f; unsigned u; } v; v.f = f;
    unsigned r = v.u + 0x7FFFu + ((v.u >> 16) & 1u);
    return (unsigned short)(r >> 16);
}
__device__ __forceinline__ float b2f(unsigned short s){
    union { unsigned u; float f; } v; v.u = ((unsigned)s) << 16;
    return v.f;
}

// ===== weight prep ==========================================================
// wc*/wt*: bf16 [shift][co][ci]. elwT: bf16 [l][pos*32+ci]. dlwT: bf16 [pos*32+ci][l]
__global__ void k_prep(const float* __restrict__ c1w, const float* __restrict__ c2w,
                       const float* __restrict__ t0w, const float* __restrict__ t1w,
                       const float* __restrict__ elw, const float* __restrict__ dlw,
                       unsigned short* __restrict__ wc1, unsigned short* __restrict__ wc2,
                       unsigned short* __restrict__ wt0, unsigned short* __restrict__ wt1,
                       unsigned short* __restrict__ elwT, unsigned short* __restrict__ dlwT,
                       int full){
    int gsz = gridDim.x * 256;
    for (int i = blockIdx.x*256 + threadIdx.x; i < 9216; i += gsz){
        int ci = i & 31, co = (i >> 5) & 31, s = i >> 10;
        wc1[i] = f2b(c1w[(co*32 + ci)*9 + s]);
        wc2[i] = f2b(c2w[(co*32 + ci)*9 + s]);
        wt0[i] = f2b(t0w[(ci*32 + co)*9 + (8 - s)]);
        wt1[i] = f2b(t1w[(ci*32 + co)*9 + (8 - s)]);
    }
    if (!full) return;
    for (int i = blockIdx.x*256 + threadIdx.x; i < 247808; i += gsz){
        int l = i / 15488, f2 = i - l*15488;
        int pos = f2 >> 5, ci = f2 & 31;
        elwT[i] = f2b(elw[(ci*484 + pos)*16 + l]);
    }
    for (int i = blockIdx.x*256 + threadIdx.x; i < 247808; i += gsz){
        int f2 = i >> 4, l = i & 15;
        int pos = f2 >> 5, ci = f2 & 31;
        dlwT[i] = f2b(dlw[l*15488 + ci*484 + pos]);
    }
}

// ===== FAST PATH: per-layer kernels ========================================

// conv0: 1->32, VALU, x fp32 -> A0 bf16 channel-last (26x26, 32 ci/pixel)
__global__ void __launch_bounds__(256)
k_conv0(const float* __restrict__ x, const float* __restrict__ c0w,
        const float* __restrict__ c0b, unsigned short* __restrict__ A0,
        int cb, int CH){
    int gid = blockIdx.x*256 + threadIdx.x;
    if (gid >= CH*676) return;
    int b = gid / 676, pos = gid - b*676;
    int y = pos / 26, xx = pos - y*26;
    const float* xin = x + (size_t)(cb + b)*784;
    float v[9];
#pragma unroll
    for (int r = 0; r < 3; r++)
#pragma unroll
        for (int s = 0; s < 3; s++)
            v[r*3+s] = xin[(y+r)*28 + xx + s];
    unsigned short* ob = A0 + (size_t)b*21632 + pos*32;
#pragma unroll
    for (int g = 0; g < 8; g++){
        float a0 = c0b[g*4+0], a1 = c0b[g*4+1], a2 = c0b[g*4+2], a3 = c0b[g*4+3];
#pragma unroll
        for (int k = 0; k < 9; k++){
            a0 += v[k] * c0w[(g*4+0)*9 + k];
            a1 += v[k] * c0w[(g*4+1)*9 + k];
            a2 += v[k] * c0w[(g*4+2)*9 + k];
            a3 += v[k] * c0w[(g*4+3)*9 + k];
        }
        ushort4 o;
        o.x = f2b(fast_tanh(a0)); o.y = f2b(fast_tanh(a1));
        o.z = f2b(fast_tanh(a2)); o.w = f2b(fast_tanh(a3));
        *(ushort4*)(ob + g*4) = o;
    }
}

// MFMA conv layer: VALID 3x3 over IL-wide map -> OL x OL outputs into OW-wide
// map at pixel offset OOFF. One block (4 waves) per image. No LDS.
template<int IL, int OL, int OW, int OOFF, int INS, int OUTS>
__global__ void __launch_bounds__(256)
k_convM(const unsigned short* __restrict__ in, const unsigned short* __restrict__ wg,
        const float* __restrict__ bias, unsigned short* __restrict__ out){
    constexpr int N  = OL * OL;
    constexpr int NT = (N + 15) / 16;
    const int tid = threadIdx.x;
    const int wave = tid >> 6, lane = tid & 63;
    const int q = lane >> 4, nn = lane & 15;
    const unsigned short* inb = in + (size_t)blockIdx.x * INS;
    unsigned short* outb = out + (size_t)blockIdx.x * OUTS;

    bf16x8 af[2][9];
#pragma unroll
    for (int mt = 0; mt < 2; mt++)
#pragma unroll
        for (int s = 0; s < 9; s++)
            af[mt][s] = *(const bf16x8*)(wg + s*1024 + (mt*16 + nn)*32 + q*8);
    float4 bc0 = *(const float4*)(bias + q*4);
    float4 bc1 = *(const float4*)(bias + 16 + q*4);

    for (int t = wave; t < NT; t += 4){
        int pos = t*16 + nn;
        int pc  = pos < N ? pos : N - 1;
        int oy = pc / OL, ox = pc - oy*OL;
        const unsigned short* ib = inb + (oy*IL + ox)*32 + q*8;
        f32x4 acc0 = {0.f,0.f,0.f,0.f}, acc1 = {0.f,0.f,0.f,0.f};
#pragma unroll
        for (int r = 0; r < 3; r++){
            bf16x8 b0 = *(const bf16x8*)(ib + (r*IL + 0)*32);
            bf16x8 b1 = *(const bf16x8*)(ib + (r*IL + 1)*32);
            bf16x8 b2 = *(const bf16x8*)(ib + (r*IL + 2)*32);
            acc0 = __builtin_amdgcn_mfma_f32_16x16x32_bf16(af[0][r*3+0], b0, acc0, 0,0,0);
            acc1 = __builtin_amdgcn_mfma_f32_16x16x32_bf16(af[1][r*3+0], b0, acc1, 0,0,0);
            acc0 = __builtin_amdgcn_mfma_f32_16x16x32_bf16(af[0][r*3+1], b1, acc0, 0,0,0);
            acc1 = __builtin_amdgcn_mfma_f32_16x16x32_bf16(af[1][r*3+1], b1, acc1, 0,0,0);
            acc0 = __builtin_amdgcn_mfma_f32_16x16x32_bf16(af[0][r*3+2], b2, acc0, 0,0,0);
            acc1 = __builtin_amdgcn_mfma_f32_16x16x32_bf16(af[1][r*3+2], b2, acc1, 0,0,0);
        }
        if (pos < N){
            int opix = oy*OW + ox + OOFF;
            ushort4 o0, o1;
            o0.x = f2b(fast_tanh(acc0[0] + bc0.x)); o0.y = f2b(fast_tanh(acc0[1] + bc0.y));
            o0.z = f2b(fast_tanh(acc0[2] + bc0.z)); o0.w = f2b(fast_tanh(acc0[3] + bc0.w));
            o1.x = f2b(fast_tanh(acc1[0] + bc1.x)); o1.y = f2b(fast_tanh(acc1[1] + bc1.y));
            o1.z = f2b(fast_tanh(acc1[2] + bc1.z)); o1.w = f2b(fast_tanh(acc1[3] + bc1.w));
            *(ushort4*)(outb + opix*32 + q*4)      = o0;
            *(ushort4*)(outb + opix*32 + 16 + q*4) = o1;
        }
    }
}

// encoder GEMM: z1[img,l] = elb[l] + sum_k A2[img,k]*elwT[l,k]; one wave=16 imgs
__global__ void __launch_bounds__(256)
k_encg(const unsigned short* __restrict__ A2, const unsigned short* __restrict__ elwT,
       const float* __restrict__ elb, float* __restrict__ z1, int cb, int CH){
    int wave = threadIdx.x >> 6, lane = threadIdx.x & 63;
    int q = lane >> 4, nn = lane & 15;
    int imgb = blockIdx.x*64 + wave*16;
    if (imgb >= CH) return;
    const unsigned short* ap = A2 + (size_t)(imgb + nn)*15488 + q*8;
    const unsigned short* bp = elwT + (size_t)nn*15488 + q*8;
    f32x4 acc = {0.f,0.f,0.f,0.f};
#pragma unroll 4
    for (int kk = 0; kk < 484; kk++){
        bf16x8 a = *(const bf16x8*)(ap + kk*32);
        bf16x8 b = *(const bf16x8*)(bp + kk*32);
        acc = __builtin_amdgcn_mfma_f32_16x16x32_bf16(a, b, acc, 0,0,0);
    }
    float eb = elb[nn];
#pragma unroll
    for (int i = 0; i < 4; i++)
        z1[(size_t)(cb + imgb + q*4 + i)*16 + nn] = acc[i] + eb;
}

// zero halos of D0 (26-map, interior 22 at +2) and D1 (28-map, interior 24 at +2)
__global__ void __launch_bounds__(256)
k_halo(unsigned short* __restrict__ D0, unsigned short* __restrict__ D1, int CH){
    int gid = blockIdx.x*256 + threadIdx.x;
    uint4 zq = {0,0,0,0};
    if (gid < CH*676){
        int img = gid / 676, px = gid - img*676;
        int y = px / 26, x = px - y*26;
        if (y < 2 || y >= 24 || x < 2 || x >= 24){
            uint4* p = (uint4*)(D0 + (size_t)img*21632 + px*32);
            p[0] = zq; p[1] = zq; p[2] = zq; p[3] = zq;
        }
    } else {
        int g2 = gid - CH*676;
        if (g2 >= CH*784) return;
        int img = g2 / 784, px = g2 - img*784;
        int y = px / 28, x = px - y*28;
        if (y < 2 || y >= 26 || x < 2 || x >= 26){
            uint4* p = (uint4*)(D1 + (size_t)img*25088 + px*32);
            p[0] = zq; p[1] = zq; p[2] = zq; p[3] = zq;
        }
    }
}

// decoder GEMV: D0 interior = tanh(dlb + z1 @ dlw); 16 images per block
__global__ void __launch_bounds__(256)
k_decg(const float* __restrict__ z1, const unsigned short* __restrict__ dlwT,
       const float* __restrict__ dlb, unsigned short* __restrict__ D0,
       int cb, int CH){
    __shared__ float zl[256];
    int tid = threadIdx.x, ib = blockIdx.y;
    zl[tid] = z1[(size_t)(cb + ib*16 + (tid >> 4))*16 + (tid & 15)];
    __syncthreads();
    int ci = tid & 31, po = tid >> 5;
    int pos = blockIdx.x*8 + po;
    if (pos >= 484) return;
    int y = pos / 22, xx = pos - y*22;
    float bias = dlb[ci*484 + pos];
    const unsigned short* w = dlwT + (size_t)(pos*32 + ci)*16;
    bf16x8 w0 = *(const bf16x8*)(w);
    bf16x8 w1 = *(const bf16x8*)(w + 8);
    float wf[16];
#pragma unroll
    for (int j = 0; j < 8; j++){
        wf[j]   = b2f((unsigned short)w0[j]);
        wf[8+j] = b2f((unsigned short)w1[j]);
    }
    int opix = ((y+2)*26 + xx + 2)*32 + ci;
#pragma unroll 1
    for (int i = 0; i < 16; i++){
        float a = bias;
#pragma unroll
        for (int l = 0; l < 16; l++) a += zl[i*16 + l] * wf[l];
        D0[(size_t)(ib*16 + i)*21632 + opix] = f2b(fast_tanh(a));
    }
}

// convT2: 32->1, bounds-checked VALU over D2 (26-map, no halo), fp32 out
__global__ void __launch_bounds__(256)
k_convT2(const unsigned short* __restrict__ D2, const float* __restrict__ t2w,
         const float* __restrict__ t2b, float* __restrict__ out, int cb, int CH){
    int gid = blockIdx.x*256 + threadIdx.x;
    if (gid >= CH*784) return;
    int b = gid / 784, o = gid - b*784;
    int y = o / 28, xx = o - y*28;
    const unsigned short* db = D2 + (size_t)b*21632;
    float a = t2b[0];
#pragma unroll
    for (int r = 0; r < 3; r++){
        int iy = y + r - 2;
        if ((unsigned)iy >= 26u) continue;
#pragma unroll
        for (int s = 0; s < 3; s++){
            int ix = xx + s - 2;
            if ((unsigned)ix >= 26u) continue;
            const unsigned short* pp = db + (iy*26 + ix)*32;
            int wi = (2-r)*3 + (2-s);
#pragma unroll
            for (int g = 0; g < 4; g++){
                bf16x8 h = *(const bf16x8*)(pp + g*8);
#pragma unroll
                for (int j = 0; j < 8; j++)
                    a += b2f((unsigned short)h[j]) * t2w[(g*8+j)*9 + wi];
            }
        }
    }
    out[(size_t)(cb + b)*784 + o] = a;
}

// ===== FUSED FALLBACK (round-3, proven; used when ws is tiny) ==============
template<int LOUT, int INW, int OUTW, int OUTOFF>
__device__ __forceinline__ void conv_gemm(const unsigned short* __restrict__ Wg,
                                          const float* __restrict__ bias,
                                          const unsigned short* inL,
                                          unsigned short* outL, int tid){
    constexpr int N  = LOUT * LOUT;
    constexpr int NT = (N + 15) / 16;
    const int lane  = tid & 63;
    const int wave  = tid >> 6;
    const int mtile = wave & 1;
    const int quad  = lane >> 4;
    const int nn    = lane & 15;
    bf16x8 afr[9];
    const unsigned short* wp = Wg + (mtile*16 + nn)*32 + quad*8;
#pragma unroll
    for (int s = 0; s < 9; s++)
        afr[s] = *(const bf16x8*)(wp + s*1024);
    float4 bco = *(const float4*)(bias + mtile*16 + quad*4);
    for (int t = (wave >> 1); t < NT; t += 2){
        int pos = t*16 + nn;
        int pc  = pos < N ? pos : N - 1;
        int y = pc / LOUT, x = pc - y*LOUT;
        const unsigned short* ib = inL + (y*INW + x)*32 + quad*8;
        f32x4 acc = {0.f, 0.f, 0.f, 0.f};
#pragma unroll
        for (int r = 0; r < 3; r++)
#pragma unroll
            for (int s = 0; s < 3; s++)
                acc = __builtin_amdgcn_mfma_f32_16x16x32_bf16(
                        afr[r*3+s], *(const bf16x8*)(ib + (r*INW + s)*32), acc, 0, 0, 0);
        if (pos < N){
            ushort4 o;
            o.x = f2b(fast_tanh(acc[0] + bco.x));
            o.y = f2b(fast_tanh(acc[1] + bco.y));
            o.z = f2b(fast_tanh(acc[2] + bco.z));
            o.w = f2b(fast_tanh(acc[3] + bco.w));
            int opix = y*OUTW + x + OUTOFF;
            *(ushort4*)(outL + opix*32 + mtile*16 + quad*4) = o;
        }
    }
}

__global__ void __launch_bounds__(256)
k_enc_f(const float* __restrict__ x,
        const float* __restrict__ c0w, const float* __restrict__ c0b,
        const unsigned short* __restrict__ wc1, const float* __restrict__ c1b,
        const unsigned short* __restrict__ wc2, const float* __restrict__ c2b,
        const float* __restrict__ elw, const float* __restrict__ elb,
        float* __restrict__ z1){
    __shared__ float X[784];
    __shared__ __align__(16) unsigned short H0[21632];
    __shared__ __align__(16) unsigned short H1[18432];
    __shared__ __align__(16) unsigned short H2[15488];
    __shared__ float red[16*17];
    const int tid = threadIdx.x, b = blockIdx.x;
    for (int i = tid; i < 784; i += 256) X[i] = x[b*784 + i];
    __syncthreads();
    for (int pos = tid; pos < 676; pos += 256){
        int y = pos / 26, xx = pos - y*26;
        float v[9];
#pragma unroll
        for (int r = 0; r < 3; r++)
#pragma unroll
            for (int s = 0; s < 3; s++)
                v[r*3+s] = X[(y+r)*28 + xx + s];
#pragma unroll
        for (int g = 0; g < 8; g++){
            float a0 = c0b[g*4+0], a1 = c0b[g*4+1], a2 = c0b[g*4+2], a3 = c0b[g*4+3];
#pragma unroll
            for (int k = 0; k < 9; k++){
                a0 += v[k] * c0w[(g*4+0)*9 + k];
                a1 += v[k] * c0w[(g*4+1)*9 + k];
                a2 += v[k] * c0w[(g*4+2)*9 + k];
                a3 += v[k] * c0w[(g*4+3)*9 + k];
            }
            ushort4 o;
            o.x = f2b(fast_tanh(a0)); o.y = f2b(fast_tanh(a1));
            o.z = f2b(fast_tanh(a2)); o.w = f2b(fast_tanh(a3));
            *(ushort4*)(H0 + pos*32 + g*4) = o;
        }
    }
    __syncthreads();
    conv_gemm<24, 26, 24, 0>(wc1, c1b, H0, H1, tid);
    __syncthreads();
    conv_gemm<22, 24, 22, 0>(wc2, c2b, H1, H2, tid);
    __syncthreads();
    {
        int fg = tid >> 4, l = tid & 15;
        float a = 0.f;
        for (int ci = 0; ci < 32; ci++)
            for (int pos = fg; pos < 484; pos += 16)
                a += b2f(H2[pos*32 + ci]) * elw[(ci*484 + pos)*16 + l];
        red[fg*17 + l] = a;
        __syncthreads();
        if (tid < 16){
            float s = elb[tid];
#pragma unroll
            for (int g = 0; g < 16; g++) s += red[g*17 + tid];
            z1[b*16 + tid] = s;
        }
    }
}

__global__ void __launch_bounds__(256)
k_dec_f(const float* __restrict__ z1,
        const float* __restrict__ dlw, const float* __restrict__ dlb,
        const unsigned short* __restrict__ wt0, const float* __restrict__ t0b,
        const unsigned short* __restrict__ wt1, const float* __restrict__ t1b,
        const float* __restrict__ t2w, const float* __restrict__ t2b,
        float* __restrict__ out){
    __shared__ __align__(16) unsigned short D0[21632];
    __shared__ __align__(16) unsigned short D1[25088];
    __shared__ __align__(16) unsigned short D2[28800];
    const int tid = threadIdx.x, b = blockIdx.x;
    {
        uint4 zq = {0,0,0,0};
        for (int i = tid; i < 2704; i += 256) ((uint4*)D0)[i] = zq;
        for (int i = tid; i < 3136; i += 256) ((uint4*)D1)[i] = zq;
        for (int i = tid; i < 3600; i += 256) ((uint4*)D2)[i] = zq;
    }
    float zz[16];
#pragma unroll
    for (int l = 0; l < 16; l++) zz[l] = z1[b*16 + l];
    __syncthreads();
    for (int f = tid; f < 15488; f += 256){
        float a = dlb[f];
#pragma unroll
        for (int l = 0; l < 16; l++) a += zz[l] * dlw[l*15488 + f];
        int ci = f / 484, pos = f - ci*484;
        int y = pos / 22, xx = pos - y*22;
        D0[((y+2)*26 + xx + 2)*32 + ci] = f2b(fast_tanh(a));
    }
    __syncthreads();
    conv_gemm<24, 26, 28, 58>(wt0, t0b, D0, D1, tid);
    __syncthreads();
    conv_gemm<26, 28, 30, 62>(wt1, t1b, D1, D2, tid);
    __syncthreads();
    for (int o = tid; o < 784; o += 256){
        int y = o / 28, xx = o - y*28;
        float a = t2b[0];
#pragma unroll
        for (int r = 0; r < 3; r++)
#pragma unroll
            for (int s = 0; s < 3; s++){
                const unsigned short* pp = D2 + ((y+r)*30 + xx + s)*32;
                int wi = (2-r)*3 + (2-s);
#pragma unroll
                for (int g = 0; g < 4; g++){
                    bf16x8 h = *(const bf16x8*)(pp + g*8);
#pragma unroll
                    for (int j = 0; j < 8; j++)
                        a += b2f((unsigned short)h[j]) * t2w[(g*8+j)*9 + wi];
                }
            }
        out[(size_t)b*784 + o] = a;
    }
}

// ===== hypernetwork + CNF + final (unchanged, proven) ======================
__global__ void k_hyper(const float* __restrict__ h1w, const float* __restrict__ h1b,
                        const float* __restrict__ h2w, const float* __restrict__ h2b,
                        const float* __restrict__ h3w, const float* __restrict__ h3b,
                        float* __restrict__ hyp){
    int sidx = blockIdx.x;
    int i  = sidx >> 2, st = sidx & 3;
    float t = 10.0f - 0.5f * (float)i;
    if (st == 1 || st == 2) t -= 0.25f;
    else if (st == 3)       t -= 0.5f;
    __shared__ float p1[64], p2[64];
    __shared__ float p3[3136];
    int tid = threadIdx.x;
    if (tid < 64) p1[tid] = fast_tanh(t * h1w[tid] + h1b[tid]);
    __syncthreads();
    if (tid < 64){
        float a = h2b[tid];
#pragma unroll
        for (int k = 0; k < 64; k++) a += p1[k] * h2w[k*64 + tid];
        p2[tid] = fast_tanh(a);
    }
    __syncthreads();
    for (int m = tid; m < 3136; m += 256){
        float a = h3b[m];
#pragma unroll
        for (int k = 0; k < 64; k++) a += p2[k] * h3w[k*3136 + m];
        p3[m] = a;
    }
    __syncthreads();
    float* g = hyp + sidx * 2176;
    for (int m = tid; m < 1024; m += 256){
        g[m] = p3[m];
        float u = p3[1024 + m] * fast_sigmoid(p3[2048 + m]);
        g[1024 + (m & 15)*64 + (m >> 4)] = u;
        p3[1024 + m] = u;
    }
    if (tid < 64) g[2048 + tid] = p3[3072 + tid];
    __syncthreads();
    if (tid < 64){
        float s = 0.f;
#pragma unroll
        for (int d = 0; d < 16; d++) s += p3[tid*16 + d] * p3[1024 + tid*16 + d];
        g[2112 + tid] = s;
    }
}

__global__ void __launch_bounds__(128)
k_cnf(const float* __restrict__ z1, const float* __restrict__ hyp,
      float* __restrict__ part){
    __shared__ float Wl[64*17];
    __shared__ __align__(16) float Utl[16*68];
    __shared__ __align__(16) float hhl[8*68];
    __shared__ float zsl[8*17];
    __shared__ float Bbl[64];
    __shared__ __align__(16) float sl[64];
    __shared__ float red[8];
    int tid  = threadIdx.x;
    int bloc = tid >> 4, d = tid & 15;
    int bglob = blockIdx.x * 8 + bloc;
    const float dt = -0.5f;
    float z  = z1[bglob*16 + d];
    float zs = z;
    float lp = 0.f;
    for (int step = 0; step < 20; step++){
        float zacc = 0.f, lacc = 0.f;
#pragma unroll 1
        for (int st = 0; st < 4; st++){
            __syncthreads();
            const float* g = hyp + (size_t)(step*4 + st) * 2176;
            for (int k = tid; k < 2176; k += 128){
                float v = g[k];
                if (k < 1024)       Wl[(k >> 4)*17 + (k & 15)] = v;
                else if (k < 2048){ int k2 = k - 1024; Utl[(k2 >> 6)*68 + (k2 & 63)] = v; }
                else if (k < 2112)  Bbl[k - 2048] = v;
                else                sl[k - 2112] = v;
            }
            zsl[bloc*17 + d] = zs;
            __syncthreads();
#pragma unroll
            for (int r = 0; r < 4; r++){
                int task = tid + r*128;
                int pb = task >> 6, pw = task & 63;
                float a = Bbl[pw];
#pragma unroll
                for (int dd = 0; dd < 16; dd++)
                    a += zsl[pb*17 + dd] * Wl[pw*17 + dd];
                hhl[pb*68 + pw] = fast_tanh(a);
            }
            __syncthreads();
            float dz = 0.f;
            const float4* h4p = (const float4*)(hhl + bloc*68);
            const float4* u4p = (const float4*)(Utl + d*68);
#pragma unroll
            for (int w4 = 0; w4 < 16; w4++){
                float4 h = h4p[w4], u = u4p[w4];
                dz += h.x*u.x + h.y*u.y + h.z*u.z + h.w*u.w;
            }
            float4 hh4 = h4p[d];
            float4 s4  = ((const float4*)sl)[d];
            float tr = (1.f - hh4.x*hh4.x)*s4.x + (1.f - hh4.y*hh4.y)*s4.y
                     + (1.f - hh4.z*hh4.z)*s4.z + (1.f - hh4.w*hh4.w)*s4.w;
#pragma unroll
            for (int off = 1; off < 16; off <<= 1)
                tr += __shfl_xor(tr, off, 16);
            dz *= (1.f/64.f);
            float dl = -tr * (1.f/64.f);
            float wgt = (st == 0 || st == 3) ? 1.f : 2.f;
            zacc += wgt * dz;
            lacc += wgt * dl;
            if (st < 3){
                float a = (st == 2) ? 1.0f : 0.5f;
                zs = z + a * dt * dz;
            }
        }
        z  += (dt/6.f) * zacc;
        lp += (dt/6.f) * lacc;
        zs = z;
    }
    float sq = z * z;
#pragma unroll
    for (int off = 1; off < 16; off <<= 1) sq += __shfl_xor(sq, off, 16);
    float logp = -0.5f * (16.f*1.8378770664093453f + 16.f*(-2.302585092994046f) + sq*10.f);
    float contrib = logp - lp;
    if (d == 0) red[bloc] = contrib;
    __syncthreads();
    if (tid == 0){
        float p = 0.f;
#pragma unroll
        for (int j = 0; j < 8; j++) p += red[j];
        part[blockIdx.x] = p;
    }
}

__global__ void k_final(const float* __restrict__ part, float* __restrict__ out){
    __shared__ float red[256];
    int tid = threadIdx.x;
    red[tid] = part[tid];
    __syncthreads();
    for (int s = 128; s > 0; s >>= 1){
        if (tid < s) red[tid] += red[tid + s];
        __syncthreads();
    }
    if (tid == 0) out[1605632] = red[0] * (1.f/2048.f);
}

extern "C" void kernel_launch(void* const* d_in, const int* in_sizes, int n_in,
                              void* d_out, int out_size, void* d_ws, size_t ws_size,
                              hipStream_t stream){
    const float* x   = (const float*)d_in[0];
    const float* c0w = (const float*)d_in[1];
    const float* c0b = (const float*)d_in[2];
    const float* c1w = (const float*)d_in[3];
    const float* c1b = (const float*)d_in[4];
    const float* c2w = (const float*)d_in[5];
    const float* c2b = (const float*)d_in[6];
    const float* elw = (const float*)d_in[7];
    const float* elb = (const float*)d_in[8];
    const float* dlw = (const float*)d_in[9];
    const float* dlb = (const float*)d_in[10];
    const float* t0w = (const float*)d_in[11];
    const float* t0b = (const float*)d_in[12];
    const float* t1w = (const float*)d_in[13];
    const float* t1b = (const float*)d_in[14];
    const float* t2w = (const float*)d_in[15];
    const float* t2b = (const float*)d_in[16];
    const float* h1w = (const float*)d_in[17];
    const float* h1b = (const float*)d_in[18];
    const float* h2w = (const float*)d_in[19];
    const float* h2b = (const float*)d_in[20];
    const float* h3w = (const float*)d_in[21];
    const float* h3b = (const float*)d_in[22];

    float* ws   = (float*)d_ws;
    float* z1   = ws;                          // 32768 f
    float* hyp  = z1 + 32768;                  // 174080 f
    float* part = hyp + 174080;                // 256 f
    unsigned short* wc1  = (unsigned short*)(part + 256);   // 9216 each
    unsigned short* wc2  = wc1 + 9216;
    unsigned short* wt0  = wc2 + 9216;
    unsigned short* wt1  = wt0 + 9216;
    unsigned short* elwT = wt1 + 9216;         // 247808
    unsigned short* dlwT = elwT + 247808;      // 247808
    unsigned short* act  = dlwT + 247808;      // byte offset 1,893,376 (16B aligned)
    float* rec  = (float*)d_out;

    // pick chunk size from ws_size (constant per process -> graph-safe)
    const size_t MISC = 1893376;
    int CH = 0;
    const int cands[6] = {2048, 1024, 512, 256, 128, 64};
    for (int c = 0; c < 6; c++){
        size_t need = MISC + (size_t)cands[c] * 111104;
        if (need <= ws_size){ CH = cands[c]; break; }
    }

    k_hyper<<<80, 256, 0, stream>>>(h1w, h1b, h2w, h2b, h3w, h3b, hyp);

    if (CH == 0){
        // fused fallback (~902 KB ws) — proven round-3 path
        k_prep <<<64,   256, 0, stream>>>(c1w, c2w, t0w, t1w, elw, dlw,
                                          wc1, wc2, wt0, wt1, wt1, wt1, 0);
        k_enc_f<<<2048, 256, 0, stream>>>(x, c0w, c0b, wc1, c1b, wc2, c2b, elw, elb, z1);
        k_cnf  <<<256,  128, 0, stream>>>(z1, hyp, part);
        k_dec_f<<<2048, 256, 0, stream>>>(z1, dlw, dlb, wt0, t0b, wt1, t1b, t2w, t2b, rec);
        k_final<<<1,    256, 0, stream>>>(part, rec);
        return;
    }

    k_prep<<<64, 256, 0, stream>>>(c1w, c2w, t0w, t1w, elw, dlw,
                                   wc1, wc2, wt0, wt1, elwT, dlwT, 1);

    unsigned short* R0 = act;                          // A0 / D0 / D2 : CH*21632
    unsigned short* R1 = R0 + (size_t)CH*21632;        // A1 ; D1 head : CH*18432
    unsigned short* R2 = R1 + (size_t)CH*18432;        // A2 ; D1 tail : CH*15488
    unsigned short* D1 = R1;                           // CH*25088 <= CH*33920

    for (int cb = 0; cb < Bsz; cb += CH){
        k_conv0<<<(CH*676 + 255)/256, 256, 0, stream>>>(x, c0w, c0b, R0, cb, CH);
        k_convM<26,24,24, 0, 21632, 18432><<<CH, 256, 0, stream>>>(R0, wc1, c1b, R1);
        k_convM<24,22,22, 0, 18432, 15488><<<CH, 256, 0, stream>>>(R1, wc2, c2b, R2);
        k_encg<<<(CH + 63)/64, 256, 0, stream>>>(R2, elwT, elb, z1, cb, CH);
        k_halo<<<(CH*1460 + 255)/256, 256, 0, stream>>>(R0, D1, CH);
        k_decg<<<dim3(61, CH/16), 256, 0, stream>>>(z1, dlwT, dlb, R0, cb, CH);
        k_convM<26,24,28,58, 21632, 25088><<<CH, 256, 0, stream>>>(R0, wt0, t0b, D1);
        k_convM<28,26,26, 0, 25088, 21632><<<CH, 256, 0, stream>>>(D1, wt1, t1b, R0);
        k_convT2<<<(CH*784 + 255)/256, 256, 0, stream>>>(R0, t2w, t2b, rec, cb, CH);
    }
    k_cnf  <<<256, 128, 0, stream>>>(z1, hyp, part);
    k_final<<<1,   256, 0, stream>>>(part, rec);
}

// Round 5
// 834.741 us; speedup vs baseline: 7.1378x; 1.5082x over previous
//
#include <hip/hip_runtime.h>
#include <math.h>

#define Bsz 2048

using bf16x8 = __attribute__((ext_vector_type(8))) short;
using f32x4  = __attribute__((ext_vector_type(4))) float;

__device__ __forceinline__ float fast_tanh(float x){
    float e = __expf(2.0f * x);
    return 1.0f - 2.0f / (e + 1.0f);
}
__device__ __forceinline__ float fast_sigmoid(float x){
    return 1.0f / (1.0f + __expf(-x));
}
__device__ __forceinline__ unsigned short f2b(float f){
    union { float f; unsigned u; } v; v.f = f;
    unsigned r = v.u + 0x7FFFu + ((v.u >> 16) & 1u);
    return (unsigned short)(r >> 16);
}
__device__ __forceinline__ float b2f(unsigned short s){
    union { unsigned u; float f; } v; v.u = ((unsigned)s) << 16;
    return v.f;
}

// ===== weight prep ==========================================================
__global__ void k_prep(const float* __restrict__ c1w, const float* __restrict__ c2w,
                       const float* __restrict__ t0w, const float* __restrict__ t1w,
                       const float* __restrict__ elw, const float* __restrict__ dlw,
                       unsigned short* __restrict__ wc1, unsigned short* __restrict__ wc2,
                       unsigned short* __restrict__ wt0, unsigned short* __restrict__ wt1,
                       unsigned short* __restrict__ elwT, unsigned short* __restrict__ dlwT,
                       int full){
    int gsz = gridDim.x * 256;
    for (int i = blockIdx.x*256 + threadIdx.x; i < 9216; i += gsz){
        int ci = i & 31, co = (i >> 5) & 31, s = i >> 10;
        wc1[i] = f2b(c1w[(co*32 + ci)*9 + s]);
        wc2[i] = f2b(c2w[(co*32 + ci)*9 + s]);
        wt0[i] = f2b(t0w[(ci*32 + co)*9 + (8 - s)]);
        wt1[i] = f2b(t1w[(ci*32 + co)*9 + (8 - s)]);
    }
    if (!full) return;
    for (int i = blockIdx.x*256 + threadIdx.x; i < 247808; i += gsz){
        int l = i / 15488, f2 = i - l*15488;
        int pos = f2 >> 5, ci = f2 & 31;
        elwT[i] = f2b(elw[(ci*484 + pos)*16 + l]);
    }
    for (int i = blockIdx.x*256 + threadIdx.x; i < 247808; i += gsz){
        int f2 = i >> 4, l = i & 15;
        int pos = f2 >> 5, ci = f2 & 31;
        dlwT[i] = f2b(dlw[l*15488 + ci*484 + pos]);
    }
}

// ===== conv0: 1->32, VALU ==================================================
__global__ void __launch_bounds__(256)
k_conv0(const float* __restrict__ x, const float* __restrict__ c0w,
        const float* __restrict__ c0b, unsigned short* __restrict__ A0,
        int cb, int CH){
    int gid = blockIdx.x*256 + threadIdx.x;
    if (gid >= CH*676) return;
    int b = gid / 676, pos = gid - b*676;
    int y = pos / 26, xx = pos - y*26;
    const float* xin = x + (size_t)(cb + b)*784;
    float v[9];
#pragma unroll
    for (int r = 0; r < 3; r++)
#pragma unroll
        for (int s = 0; s < 3; s++)
            v[r*3+s] = xin[(y+r)*28 + xx + s];
    unsigned short* ob = A0 + (size_t)b*21632 + pos*32;
#pragma unroll
    for (int g = 0; g < 8; g++){
        float a0 = c0b[g*4+0], a1 = c0b[g*4+1], a2 = c0b[g*4+2], a3 = c0b[g*4+3];
#pragma unroll
        for (int k = 0; k < 9; k++){
            a0 += v[k] * c0w[(g*4+0)*9 + k];
            a1 += v[k] * c0w[(g*4+1)*9 + k];
            a2 += v[k] * c0w[(g*4+2)*9 + k];
            a3 += v[k] * c0w[(g*4+3)*9 + k];
        }
        ushort4 o;
        o.x = f2b(fast_tanh(a0)); o.y = f2b(fast_tanh(a1));
        o.z = f2b(fast_tanh(a2)); o.w = f2b(fast_tanh(a3));
        *(ushort4*)(ob + g*4) = o;
    }
}

// ===== MFMA conv layer, tile-parallel across all images ====================
template<int IL, int OL, int OW, int OOFF, int INS, int OUTS>
__global__ void __launch_bounds__(256)
k_convM(const unsigned short* __restrict__ in, const unsigned short* __restrict__ wg,
        const float* __restrict__ bias, unsigned short* __restrict__ out, int CH){
    constexpr int N  = OL * OL;
    constexpr int NT = (N + 15) / 16;
    const int tid = threadIdx.x;
    const int wave = tid >> 6, lane = tid & 63;
    const int q = lane >> 4, nn = lane & 15;
    const int nw = gridDim.x * 4;

    bf16x8 af[2][9];
#pragma unroll
    for (int mt = 0; mt < 2; mt++)
#pragma unroll
        for (int s = 0; s < 9; s++)
            af[mt][s] = *(const bf16x8*)(wg + s*1024 + (mt*16 + nn)*32 + q*8);
    float4 bc0 = *(const float4*)(bias + q*4);
    float4 bc1 = *(const float4*)(bias + 16 + q*4);

    for (int t = blockIdx.x*4 + wave; t < CH*NT; t += nw){
        int img = t / NT, tt = t - img*NT;
        const unsigned short* inb = in + (size_t)img * INS;
        unsigned short* outb = out + (size_t)img * OUTS;
        int pos = tt*16 + nn;
        int pc  = pos < N ? pos : N - 1;
        int oy = pc / OL, ox = pc - oy*OL;
        const unsigned short* ib = inb + (oy*IL + ox)*32 + q*8;
        f32x4 acc0 = {0.f,0.f,0.f,0.f}, acc1 = {0.f,0.f,0.f,0.f};
#pragma unroll
        for (int r = 0; r < 3; r++){
            bf16x8 b0 = *(const bf16x8*)(ib + (r*IL + 0)*32);
            bf16x8 b1 = *(const bf16x8*)(ib + (r*IL + 1)*32);
            bf16x8 b2 = *(const bf16x8*)(ib + (r*IL + 2)*32);
            acc0 = __builtin_amdgcn_mfma_f32_16x16x32_bf16(af[0][r*3+0], b0, acc0, 0,0,0);
            acc1 = __builtin_amdgcn_mfma_f32_16x16x32_bf16(af[1][r*3+0], b0, acc1, 0,0,0);
            acc0 = __builtin_amdgcn_mfma_f32_16x16x32_bf16(af[0][r*3+1], b1, acc0, 0,0,0);
            acc1 = __builtin_amdgcn_mfma_f32_16x16x32_bf16(af[1][r*3+1], b1, acc1, 0,0,0);
            acc0 = __builtin_amdgcn_mfma_f32_16x16x32_bf16(af[0][r*3+2], b2, acc0, 0,0,0);
            acc1 = __builtin_amdgcn_mfma_f32_16x16x32_bf16(af[1][r*3+2], b2, acc1, 0,0,0);
        }
        if (pos < N){
            int opix = oy*OW + ox + OOFF;
            ushort4 o0, o1;
            o0.x = f2b(fast_tanh(acc0[0] + bc0.x)); o0.y = f2b(fast_tanh(acc0[1] + bc0.y));
            o0.z = f2b(fast_tanh(acc0[2] + bc0.z)); o0.w = f2b(fast_tanh(acc0[3] + bc0.w));
            o1.x = f2b(fast_tanh(acc1[0] + bc1.x)); o1.y = f2b(fast_tanh(acc1[1] + bc1.y));
            o1.z = f2b(fast_tanh(acc1[2] + bc1.z)); o1.w = f2b(fast_tanh(acc1[3] + bc1.w));
            *(ushort4*)(outb + opix*32 + q*4)      = o0;
            *(ushort4*)(outb + opix*32 + 16 + q*4) = o1;
        }
    }
}

// ===== encoder GEMM, K split across 4 waves ================================
__global__ void __launch_bounds__(256)
k_encg(const unsigned short* __restrict__ A2, const unsigned short* __restrict__ elwT,
       const float* __restrict__ elb, float* __restrict__ z1, int cb, int CH){
    __shared__ float red[4][64][4];
    int wave = threadIdx.x >> 6, lane = threadIdx.x & 63;
    int q = lane >> 4, nn = lane & 15;
    int imgb = blockIdx.x*16;
    const unsigned short* ap = A2 + (size_t)(imgb + nn)*15488 + wave*3872 + q*8;
    const unsigned short* bp = elwT + (size_t)nn*15488 + wave*3872 + q*8;
    f32x4 acc = {0.f,0.f,0.f,0.f};
#pragma unroll 4
    for (int kk = 0; kk < 121; kk++){
        bf16x8 a = *(const bf16x8*)(ap + kk*32);
        bf16x8 b = *(const bf16x8*)(bp + kk*32);
        acc = __builtin_amdgcn_mfma_f32_16x16x32_bf16(a, b, acc, 0,0,0);
    }
#pragma unroll
    for (int i = 0; i < 4; i++) red[wave][lane][i] = acc[i];
    __syncthreads();
    if (wave == 0){
        float eb = elb[nn];
#pragma unroll
        for (int i = 0; i < 4; i++){
            float s = red[0][lane][i] + red[1][lane][i] + red[2][lane][i] + red[3][lane][i];
            z1[(size_t)(cb + imgb + q*4 + i)*16 + nn] = s + eb;
        }
    }
}

// ===== halo zero ===========================================================
__global__ void __launch_bounds__(256)
k_halo(unsigned short* __restrict__ D0, unsigned short* __restrict__ D1, int CH){
    int gid = blockIdx.x*256 + threadIdx.x;
    uint4 zq = {0,0,0,0};
    if (gid < CH*676){
        int img = gid / 676, px = gid - img*676;
        int y = px / 26, x = px - y*26;
        if (y < 2 || y >= 24 || x < 2 || x >= 24){
            uint4* p = (uint4*)(D0 + (size_t)img*21632 + px*32);
            p[0] = zq; p[1] = zq; p[2] = zq; p[3] = zq;
        }
    } else {
        int g2 = gid - CH*676;
        if (g2 >= CH*784) return;
        int img = g2 / 784, px = g2 - img*784;
        int y = px / 28, x = px - y*28;
        if (y < 2 || y >= 26 || x < 2 || x >= 26){
            uint4* p = (uint4*)(D1 + (size_t)img*25088 + px*32);
            p[0] = zq; p[1] = zq; p[2] = zq; p[3] = zq;
        }
    }
}

// ===== decoder GEMV ========================================================
__global__ void __launch_bounds__(256)
k_decg(const float* __restrict__ z1, const unsigned short* __restrict__ dlwT,
       const float* __restrict__ dlb, unsigned short* __restrict__ D0,
       int cb, int CH){
    __shared__ float zl[256];
    int tid = threadIdx.x, ib = blockIdx.y;
    zl[tid] = z1[(size_t)(cb + ib*16 + (tid >> 4))*16 + (tid & 15)];
    __syncthreads();
    int ci = tid & 31, po = tid >> 5;
    int pos = blockIdx.x*8 + po;
    if (pos >= 484) return;
    int y = pos / 22, xx = pos - y*22;
    float bias = dlb[ci*484 + pos];
    const unsigned short* w = dlwT + (size_t)(pos*32 + ci)*16;
    bf16x8 w0 = *(const bf16x8*)(w);
    bf16x8 w1 = *(const bf16x8*)(w + 8);
    float wf[16];
#pragma unroll
    for (int j = 0; j < 8; j++){
        wf[j]   = b2f((unsigned short)w0[j]);
        wf[8+j] = b2f((unsigned short)w1[j]);
    }
    int opix = ((y+2)*26 + xx + 2)*32 + ci;
#pragma unroll 1
    for (int i = 0; i < 16; i++){
        float a = bias;
#pragma unroll
        for (int l = 0; l < 16; l++) a += zl[i*16 + l] * wf[l];
        D0[(size_t)(ib*16 + i)*21632 + opix] = f2b(fast_tanh(a));
    }
}

// ===== convT2: 32->1 =======================================================
__global__ void __launch_bounds__(256)
k_convT2(const unsigned short* __restrict__ D2, const float* __restrict__ t2w,
         const float* __restrict__ t2b, float* __restrict__ out, int cb, int CH){
    int gid = blockIdx.x*256 + threadIdx.x;
    if (gid >= CH*784) return;
    int b = gid / 784, o = gid - b*784;
    int y = o / 28, xx = o - y*28;
    const unsigned short* db = D2 + (size_t)b*21632;
    float a = t2b[0];
#pragma unroll
    for (int r = 0; r < 3; r++){
        int iy = y + r - 2;
        if ((unsigned)iy >= 26u) continue;
#pragma unroll
        for (int s = 0; s < 3; s++){
            int ix = xx + s - 2;
            if ((unsigned)ix >= 26u) continue;
            const unsigned short* pp = db + (iy*26 + ix)*32;
            int wi = (2-r)*3 + (2-s);
#pragma unroll
            for (int g = 0; g < 4; g++){
                bf16x8 h = *(const bf16x8*)(pp + g*8);
#pragma unroll
                for (int j = 0; j < 8; j++)
                    a += b2f((unsigned short)h[j]) * t2w[(g*8+j)*9 + wi];
            }
        }
    }
    out[(size_t)(cb + b)*784 + o] = a;
}

// ===== FUSED FALLBACK (round-3, proven) ====================================
template<int LOUT, int INW, int OUTW, int OUTOFF>
__device__ __forceinline__ void conv_gemm(const unsigned short* __restrict__ Wg,
                                          const float* __restrict__ bias,
                                          const unsigned short* inL,
                                          unsigned short* outL, int tid){
    constexpr int N  = LOUT * LOUT;
    constexpr int NT = (N + 15) / 16;
    const int lane  = tid & 63;
    const int wave  = tid >> 6;
    const int mtile = wave & 1;
    const int quad  = lane >> 4;
    const int nn    = lane & 15;
    bf16x8 afr[9];
    const unsigned short* wp = Wg + (mtile*16 + nn)*32 + quad*8;
#pragma unroll
    for (int s = 0; s < 9; s++)
        afr[s] = *(const bf16x8*)(wp + s*1024);
    float4 bco = *(const float4*)(bias + mtile*16 + quad*4);
    for (int t = (wave >> 1); t < NT; t += 2){
        int pos = t*16 + nn;
        int pc  = pos < N ? pos : N - 1;
        int y = pc / LOUT, x = pc - y*LOUT;
        const unsigned short* ib = inL + (y*INW + x)*32 + quad*8;
        f32x4 acc = {0.f, 0.f, 0.f, 0.f};
#pragma unroll
        for (int r = 0; r < 3; r++)
#pragma unroll
            for (int s = 0; s < 3; s++)
                acc = __builtin_amdgcn_mfma_f32_16x16x32_bf16(
                        afr[r*3+s], *(const bf16x8*)(ib + (r*INW + s)*32), acc, 0, 0, 0);
        if (pos < N){
            ushort4 o;
            o.x = f2b(fast_tanh(acc[0] + bco.x));
            o.y = f2b(fast_tanh(acc[1] + bco.y));
            o.z = f2b(fast_tanh(acc[2] + bco.z));
            o.w = f2b(fast_tanh(acc[3] + bco.w));
            int opix = y*OUTW + x + OUTOFF;
            *(ushort4*)(outL + opix*32 + mtile*16 + quad*4) = o;
        }
    }
}

__global__ void __launch_bounds__(256)
k_enc_f(const float* __restrict__ x,
        const float* __restrict__ c0w, const float* __restrict__ c0b,
        const unsigned short* __restrict__ wc1, const float* __restrict__ c1b,
        const unsigned short* __restrict__ wc2, const float* __restrict__ c2b,
        const float* __restrict__ elw, const float* __restrict__ elb,
        float* __restrict__ z1){
    __shared__ float X[784];
    __shared__ __align__(16) unsigned short H0[21632];
    __shared__ __align__(16) unsigned short H1[18432];
    __shared__ __align__(16) unsigned short H2[15488];
    __shared__ float red[16*17];
    const int tid = threadIdx.x, b = blockIdx.x;
    for (int i = tid; i < 784; i += 256) X[i] = x[b*784 + i];
    __syncthreads();
    for (int pos = tid; pos < 676; pos += 256){
        int y = pos / 26, xx = pos - y*26;
        float v[9];
#pragma unroll
        for (int r = 0; r < 3; r++)
#pragma unroll
            for (int s = 0; s < 3; s++)
                v[r*3+s] = X[(y+r)*28 + xx + s];
#pragma unroll
        for (int g = 0; g < 8; g++){
            float a0 = c0b[g*4+0], a1 = c0b[g*4+1], a2 = c0b[g*4+2], a3 = c0b[g*4+3];
#pragma unroll
            for (int k = 0; k < 9; k++){
                a0 += v[k] * c0w[(g*4+0)*9 + k];
                a1 += v[k] * c0w[(g*4+1)*9 + k];
                a2 += v[k] * c0w[(g*4+2)*9 + k];
                a3 += v[k] * c0w[(g*4+3)*9 + k];
            }
            ushort4 o;
            o.x = f2b(fast_tanh(a0)); o.y = f2b(fast_tanh(a1));
            o.z = f2b(fast_tanh(a2)); o.w = f2b(fast_tanh(a3));
            *(ushort4*)(H0 + pos*32 + g*4) = o;
        }
    }
    __syncthreads();
    conv_gemm<24, 26, 24, 0>(wc1, c1b, H0, H1, tid);
    __syncthreads();
    conv_gemm<22, 24, 22, 0>(wc2, c2b, H1, H2, tid);
    __syncthreads();
    {
        int fg = tid >> 4, l = tid & 15;
        float a = 0.f;
        for (int ci = 0; ci < 32; ci++)
            for (int pos = fg; pos < 484; pos += 16)
                a += b2f(H2[pos*32 + ci]) * elw[(ci*484 + pos)*16 + l];
        red[fg*17 + l] = a;
        __syncthreads();
        if (tid < 16){
            float s = elb[tid];
#pragma unroll
            for (int g = 0; g < 16; g++) s += red[g*17 + tid];
            z1[b*16 + tid] = s;
        }
    }
}

__global__ void __launch_bounds__(256)
k_dec_f(const float* __restrict__ z1,
        const float* __restrict__ dlw, const float* __restrict__ dlb,
        const unsigned short* __restrict__ wt0, const float* __restrict__ t0b,
        const unsigned short* __restrict__ wt1, const float* __restrict__ t1b,
        const float* __restrict__ t2w, const float* __restrict__ t2b,
        float* __restrict__ out){
    __shared__ __align__(16) unsigned short D0[21632];
    __shared__ __align__(16) unsigned short D1[25088];
    __shared__ __align__(16) unsigned short D2[28800];
    const int tid = threadIdx.x, b = blockIdx.x;
    {
        uint4 zq = {0,0,0,0};
        for (int i = tid; i < 2704; i += 256) ((uint4*)D0)[i] = zq;
        for (int i = tid; i < 3136; i += 256) ((uint4*)D1)[i] = zq;
        for (int i = tid; i < 3600; i += 256) ((uint4*)D2)[i] = zq;
    }
    float zz[16];
#pragma unroll
    for (int l = 0; l < 16; l++) zz[l] = z1[b*16 + l];
    __syncthreads();
    for (int f = tid; f < 15488; f += 256){
        float a = dlb[f];
#pragma unroll
        for (int l = 0; l < 16; l++) a += zz[l] * dlw[l*15488 + f];
        int ci = f / 484, pos = f - ci*484;
        int y = pos / 22, xx = pos - y*22;
        D0[((y+2)*26 + xx + 2)*32 + ci] = f2b(fast_tanh(a));
    }
    __syncthreads();
    conv_gemm<24, 26, 28, 58>(wt0, t0b, D0, D1, tid);
    __syncthreads();
    conv_gemm<26, 28, 30, 62>(wt1, t1b, D1, D2, tid);
    __syncthreads();
    for (int o = tid; o < 784; o += 256){
        int y = o / 28, xx = o - y*28;
        float a = t2b[0];
#pragma unroll
        for (int r = 0; r < 3; r++)
#pragma unroll
            for (int s = 0; s < 3; s++){
                const unsigned short* pp = D2 + ((y+r)*30 + xx + s)*32;
                int wi = (2-r)*3 + (2-s);
#pragma unroll
                for (int g = 0; g < 4; g++){
                    bf16x8 h = *(const bf16x8*)(pp + g*8);
#pragma unroll
                    for (int j = 0; j < 8; j++)
                        a += b2f((unsigned short)h[j]) * t2w[(g*8+j)*9 + wi];
                }
            }
        out[(size_t)b*784 + o] = a;
    }
}

// ===== hypernetwork: stage stride 2304 =====================================
__global__ void k_hyper(const float* __restrict__ h1w, const float* __restrict__ h1b,
                        const float* __restrict__ h2w, const float* __restrict__ h2b,
                        const float* __restrict__ h3w, const float* __restrict__ h3b,
                        float* __restrict__ hyp){
    int sidx = blockIdx.x;
    int i  = sidx >> 2, st = sidx & 3;
    float t = 10.0f - 0.5f * (float)i;
    if (st == 1 || st == 2) t -= 0.25f;
    else if (st == 3)       t -= 0.5f;
    __shared__ float p1[64], p2[64];
    __shared__ float p3[3136];
    int tid = threadIdx.x;
    if (tid < 64) p1[tid] = fast_tanh(t * h1w[tid] + h1b[tid]);
    __syncthreads();
    if (tid < 64){
        float a = h2b[tid];
#pragma unroll
        for (int k = 0; k < 64; k++) a += p1[k] * h2w[k*64 + tid];
        p2[tid] = fast_tanh(a);
    }
    __syncthreads();
    for (int m = tid; m < 3136; m += 256){
        float a = h3b[m];
#pragma unroll
        for (int k = 0; k < 64; k++) a += p2[k] * h3w[k*3136 + m];
        p3[m] = a;
    }
    __syncthreads();
    float* g = hyp + (size_t)sidx * 2304;
    for (int m = tid; m < 1024; m += 256){
        g[m] = p3[m];                                   // W[w*16+d]
        float u = p3[1024 + m] * fast_sigmoid(p3[2048 + m]);
        g[1024 + (m & 15)*64 + (m >> 4)] = u;           // Ut[d*64+w]
        p3[1024 + m] = u;
    }
    if (tid < 64) g[2048 + tid] = p3[3072 + tid];       // Bb
    __syncthreads();
    if (tid < 64){
        float s = 0.f;
#pragma unroll
        for (int d = 0; d < 16; d++) s += p3[tid*16 + d] * p3[1024 + tid*16 + d];
        g[2112 + tid] = s;                              // strace
    }
}

// ===== CNF RK4: single-wave blocks, 4 rows/wave, prefetched params =========
struct PF { float4 Wr[4]; float4 Ur[4]; float Bb, st; };

__device__ __forceinline__ void load_pf(const float* __restrict__ g, int lane, PF& p){
    const float4* w4 = (const float4*)(g + lane*16);
    p.Wr[0] = w4[0]; p.Wr[1] = w4[1]; p.Wr[2] = w4[2]; p.Wr[3] = w4[3];
    const float4* u4 = (const float4*)(g + 1024 + lane*16);
    p.Ur[0] = u4[0]; p.Ur[1] = u4[1]; p.Ur[2] = u4[2]; p.Ur[3] = u4[3];
    p.Bb = g[2048 + lane];
    p.st = g[2112 + lane];
}

__global__ void __launch_bounds__(64)
k_cnf(const float* __restrict__ z1, const float* __restrict__ hyp,
      float* __restrict__ part){
    __shared__ __align__(16) float Utl[16*68];   // Ut[d][w] at d*68+w
    __shared__ __align__(16) float hhl[4*68];    // hh[b][w]
    __shared__ __align__(16) float zsl[64];      // zs[b*16+d]
    __shared__ __align__(16) float sl[64];       // strace[w]
    __shared__ float red2[4];

    const int lane = threadIdx.x;
    const int bloc = lane >> 4, d = lane & 15;
    const int du = lane >> 2, wb = (lane & 3) * 16;
    const float dt = -0.5f;

    float z  = z1[(size_t)(blockIdx.x*4 + bloc)*16 + d];
    float zs = z;
    float lp = 0.f;
    float zacc = 0.f, lacc = 0.f;

    PF cur, nxt;
    load_pf(hyp, lane, cur);

    for (int sidx = 0; sidx < 80; sidx++){
        // stage-in: params to LDS / registers stay
        *(float4*)(Utl + du*68 + wb)      = cur.Ur[0];
        *(float4*)(Utl + du*68 + wb + 4)  = cur.Ur[1];
        *(float4*)(Utl + du*68 + wb + 8)  = cur.Ur[2];
        *(float4*)(Utl + du*68 + wb + 12) = cur.Ur[3];
        sl[lane]  = cur.st;
        zsl[lane] = zs;
        __syncthreads();
        if (sidx < 79) load_pf(hyp + (size_t)(sidx + 1)*2304, lane, nxt);

        // phase 1: lane = w; hh[b][w] = tanh(Bb[w] + zs[b]·W[w])
        float hhv[4];
#pragma unroll
        for (int b = 0; b < 4; b++){
            const float4* zp = (const float4*)(zsl + b*16);
            float4 z0 = zp[0], z1v = zp[1], z2 = zp[2], z3 = zp[3];
            float a = cur.Bb;
            a += z0.x*cur.Wr[0].x + z0.y*cur.Wr[0].y + z0.z*cur.Wr[0].z + z0.w*cur.Wr[0].w;
            a += z1v.x*cur.Wr[1].x + z1v.y*cur.Wr[1].y + z1v.z*cur.Wr[1].z + z1v.w*cur.Wr[1].w;
            a += z2.x*cur.Wr[2].x + z2.y*cur.Wr[2].y + z2.z*cur.Wr[2].z + z2.w*cur.Wr[2].w;
            a += z3.x*cur.Wr[3].x + z3.y*cur.Wr[3].y + z3.z*cur.Wr[3].z + z3.w*cur.Wr[3].w;
            hhv[b] = fast_tanh(a);
        }
#pragma unroll
        for (int b = 0; b < 4; b++) hhl[b*68 + lane] = hhv[b];
        __syncthreads();

        // phase 2: lane = (bloc, d)
        float dz = 0.f;
        const float4* h4p = (const float4*)(hhl + bloc*68);
        const float4* u4p = (const float4*)(Utl + d*68);
#pragma unroll
        for (int w4 = 0; w4 < 16; w4++){
            float4 h = h4p[w4], u = u4p[w4];
            dz += h.x*u.x + h.y*u.y + h.z*u.z + h.w*u.w;
        }
        float4 hh4 = h4p[d];
        float4 s4  = ((const float4*)sl)[d];
        float tr = (1.f - hh4.x*hh4.x)*s4.x + (1.f - hh4.y*hh4.y)*s4.y
                 + (1.f - hh4.z*hh4.z)*s4.z + (1.f - hh4.w*hh4.w)*s4.w;
#pragma unroll
        for (int off = 1; off < 16; off <<= 1)
            tr += __shfl_xor(tr, off, 16);
        dz *= (1.f/64.f);
        float dl = -tr * (1.f/64.f);

        int st = sidx & 3;
        float wgt = (st == 0 || st == 3) ? 1.f : 2.f;
        zacc += wgt * dz;
        lacc += wgt * dl;
        if (st < 3){
            float a = (st == 2) ? 1.0f : 0.5f;
            zs = z + a * dt * dz;
        } else {
            z  += (dt/6.f) * zacc;
            lp += (dt/6.f) * lacc;
            zs = z;
            zacc = 0.f; lacc = 0.f;
        }
        cur = nxt;
    }

    float sq = z * z;
#pragma unroll
    for (int off = 1; off < 16; off <<= 1) sq += __shfl_xor(sq, off, 16);
    float logp = -0.5f * (16.f*1.8378770664093453f + 16.f*(-2.302585092994046f) + sq*10.f);
    float contrib = logp - lp;
    if (d == 0) red2[bloc] = contrib;
    __syncthreads();
    if (lane == 0)
        part[blockIdx.x] = red2[0] + red2[1] + red2[2] + red2[3];
}

__global__ void k_final(const float* __restrict__ part, float* __restrict__ out){
    __shared__ float red[256];
    int tid = threadIdx.x;
    red[tid] = part[tid] + part[tid + 256];
    __syncthreads();
    for (int s = 128; s > 0; s >>= 1){
        if (tid < s) red[tid] += red[tid + s];
        __syncthreads();
    }
    if (tid == 0) out[1605632] = red[0] * (1.f/2048.f);
}

extern "C" void kernel_launch(void* const* d_in, const int* in_sizes, int n_in,
                              void* d_out, int out_size, void* d_ws, size_t ws_size,
                              hipStream_t stream){
    const float* x   = (const float*)d_in[0];
    const float* c0w = (const float*)d_in[1];
    const float* c0b = (const float*)d_in[2];
    const float* c1w = (const float*)d_in[3];
    const float* c1b = (const float*)d_in[4];
    const float* c2w = (const float*)d_in[5];
    const float* c2b = (const float*)d_in[6];
    const float* elw = (const float*)d_in[7];
    const float* elb = (const float*)d_in[8];
    const float* dlw = (const float*)d_in[9];
    const float* dlb = (const float*)d_in[10];
    const float* t0w = (const float*)d_in[11];
    const float* t0b = (const float*)d_in[12];
    const float* t1w = (const float*)d_in[13];
    const float* t1b = (const float*)d_in[14];
    const float* t2w = (const float*)d_in[15];
    const float* t2b = (const float*)d_in[16];
    const float* h1w = (const float*)d_in[17];
    const float* h1b = (const float*)d_in[18];
    const float* h2w = (const float*)d_in[19];
    const float* h2b = (const float*)d_in[20];
    const float* h3w = (const float*)d_in[21];
    const float* h3b = (const float*)d_in[22];

    float* ws   = (float*)d_ws;
    float* z1   = ws;                          // 32768 f
    float* hyp  = z1 + 32768;                  // 184320 f (80*2304)
    float* part = hyp + 184320;                // 512 f
    unsigned short* wc1  = (unsigned short*)(part + 512);   // 9216 each
    unsigned short* wc2  = wc1 + 9216;
    unsigned short* wt0  = wc2 + 9216;
    unsigned short* wt1  = wt0 + 9216;
    unsigned short* elwT = wt1 + 9216;         // 247808
    unsigned short* dlwT = elwT + 247808;      // 247808
    unsigned short* act  = dlwT + 247808;      // byte offset 1,935,360 (16B aligned)
    float* rec  = (float*)d_out;

    const size_t MISC = 1935360;
    int CH = 0;
    const int cands[6] = {2048, 1024, 512, 256, 128, 64};
    for (int c = 0; c < 6; c++){
        size_t need = MISC + (size_t)cands[c] * 111104;
        if (need <= ws_size){ CH = cands[c]; break; }
    }

    k_hyper<<<80, 256, 0, stream>>>(h1w, h1b, h2w, h2b, h3w, h3b, hyp);

    if (CH == 0){
        k_prep <<<64,   256, 0, stream>>>(c1w, c2w, t0w, t1w, elw, dlw,
                                          wc1, wc2, wt0, wt1, wt1, wt1, 0);
        k_enc_f<<<2048, 256, 0, stream>>>(x, c0w, c0b, wc1, c1b, wc2, c2b, elw, elb, z1);
        k_cnf  <<<512,   64, 0, stream>>>(z1, hyp, part);
        k_dec_f<<<2048, 256, 0, stream>>>(z1, dlw, dlb, wt0, t0b, wt1, t1b, t2w, t2b, rec);
        k_final<<<1,    256, 0, stream>>>(part, rec);
        return;
    }

    k_prep<<<64, 256, 0, stream>>>(c1w, c2w, t0w, t1w, elw, dlw,
                                   wc1, wc2, wt0, wt1, elwT, dlwT, 1);

    unsigned short* R0 = act;                          // A0 / D0 / D2 : CH*21632
    unsigned short* R1 = R0 + (size_t)CH*21632;        // A1 ; D1 head : CH*18432
    unsigned short* R2 = R1 + (size_t)CH*18432;        // A2 ; D1 tail : CH*15488
    unsigned short* D1 = R1;                           // CH*25088 <= CH*33920

    for (int cb = 0; cb < Bsz; cb += CH){
        k_conv0<<<(CH*676 + 255)/256, 256, 0, stream>>>(x, c0w, c0b, R0, cb, CH);
        k_convM<26,24,24, 0, 21632, 18432><<<(CH*36 + 15)/16, 256, 0, stream>>>(R0, wc1, c1b, R1, CH);
        k_convM<24,22,22, 0, 18432, 15488><<<(CH*31 + 15)/16, 256, 0, stream>>>(R1, wc2, c2b, R2, CH);
        k_encg<<<CH/16, 256, 0, stream>>>(R2, elwT, elb, z1, cb, CH);
        k_halo<<<(CH*1460 + 255)/256, 256, 0, stream>>>(R0, D1, CH);
        k_decg<<<dim3(61, CH/16), 256, 0, stream>>>(z1, dlwT, dlb, R0, cb, CH);
        k_convM<26,24,28,58, 21632, 25088><<<(CH*36 + 15)/16, 256, 0, stream>>>(R0, wt0, t0b, D1, CH);
        k_convM<28,26,26, 0, 25088, 21632><<<(CH*43 + 15)/16, 256, 0, stream>>>(D1, wt1, t1b, R0, CH);
        k_convT2<<<(CH*784 + 255)/256, 256, 0, stream>>>(R0, t2w, t2b, rec, cb, CH);
    }
    k_cnf  <<<512,  64, 0, stream>>>(z1, hyp, part);
    k_final<<<1,   256, 0, stream>>>(part, rec);
}

// Round 6
// 666.202 us; speedup vs baseline: 8.9436x; 1.2530x over previous
//
#include <hip/hip_runtime.h>
#include <math.h>

#define Bsz 2048

using bf16x8 = __attribute__((ext_vector_type(8))) short;
using f32x4  = __attribute__((ext_vector_type(4))) float;

__device__ __forceinline__ float fast_tanh(float x){
    float e = __expf(2.0f * x);
    return 1.0f - 2.0f / (e + 1.0f);
}
__device__ __forceinline__ float fast_sigmoid(float x){
    return 1.0f / (1.0f + __expf(-x));
}
__device__ __forceinline__ unsigned short f2b(float f){
    union { float f; unsigned u; } v; v.f = f;
    unsigned r = v.u + 0x7FFFu + ((v.u >> 16) & 1u);
    return (unsigned short)(r >> 16);
}
__device__ __forceinline__ float b2f(unsigned short s){
    union { unsigned u; float f; } v; v.u = ((unsigned)s) << 16;
    return v.f;
}

__device__ __forceinline__ float stage_t(int sidx){
    int i  = sidx >> 2, st = sidx & 3;
    float t = 10.0f - 0.5f * (float)i;
    if (st == 1 || st == 2) t -= 0.25f;
    else if (st == 3)       t -= 0.5f;
    return t;
}

// ===== weight prep ==========================================================
__global__ void k_prep(const float* __restrict__ c1w, const float* __restrict__ c2w,
                       const float* __restrict__ t0w, const float* __restrict__ t1w,
                       const float* __restrict__ elw, const float* __restrict__ dlw,
                       unsigned short* __restrict__ wc1, unsigned short* __restrict__ wc2,
                       unsigned short* __restrict__ wt0, unsigned short* __restrict__ wt1,
                       unsigned short* __restrict__ elwT, unsigned short* __restrict__ dlwT,
                       int full){
    int gsz = gridDim.x * 256;
    for (int i = blockIdx.x*256 + threadIdx.x; i < 9216; i += gsz){
        int ci = i & 31, co = (i >> 5) & 31, s = i >> 10;
        wc1[i] = f2b(c1w[(co*32 + ci)*9 + s]);
        wc2[i] = f2b(c2w[(co*32 + ci)*9 + s]);
        wt0[i] = f2b(t0w[(ci*32 + co)*9 + (8 - s)]);
        wt1[i] = f2b(t1w[(ci*32 + co)*9 + (8 - s)]);
    }
    if (!full) return;
    for (int i = blockIdx.x*256 + threadIdx.x; i < 247808; i += gsz){
        int l = i / 15488, f2 = i - l*15488;
        int pos = f2 >> 5, ci = f2 & 31;
        elwT[i] = f2b(elw[(ci*484 + pos)*16 + l]);
    }
    for (int i = blockIdx.x*256 + threadIdx.x; i < 247808; i += gsz){
        int f2 = i >> 4, l = i & 15;
        int pos = f2 >> 5, ci = f2 & 31;
        dlwT[i] = f2b(dlw[l*15488 + ci*484 + pos]);
    }
}

// ===== conv0: 1->32, VALU ==================================================
__global__ void __launch_bounds__(256)
k_conv0(const float* __restrict__ x, const float* __restrict__ c0w,
        const float* __restrict__ c0b, unsigned short* __restrict__ A0,
        int cb, int CH){
    int gid = blockIdx.x*256 + threadIdx.x;
    if (gid >= CH*676) return;
    int b = gid / 676, pos = gid - b*676;
    int y = pos / 26, xx = pos - y*26;
    const float* xin = x + (size_t)(cb + b)*784;
    float v[9];
#pragma unroll
    for (int r = 0; r < 3; r++)
#pragma unroll
        for (int s = 0; s < 3; s++)
            v[r*3+s] = xin[(y+r)*28 + xx + s];
    unsigned short* ob = A0 + (size_t)b*21632 + pos*32;
#pragma unroll
    for (int g = 0; g < 8; g++){
        float a0 = c0b[g*4+0], a1 = c0b[g*4+1], a2 = c0b[g*4+2], a3 = c0b[g*4+3];
#pragma unroll
        for (int k = 0; k < 9; k++){
            a0 += v[k] * c0w[(g*4+0)*9 + k];
            a1 += v[k] * c0w[(g*4+1)*9 + k];
            a2 += v[k] * c0w[(g*4+2)*9 + k];
            a3 += v[k] * c0w[(g*4+3)*9 + k];
        }
        ushort4 o;
        o.x = f2b(fast_tanh(a0)); o.y = f2b(fast_tanh(a1));
        o.z = f2b(fast_tanh(a2)); o.w = f2b(fast_tanh(a3));
        *(ushort4*)(ob + g*4) = o;
    }
}

// ===== MFMA conv layer, tile-parallel across all images ====================
template<int IL, int OL, int OW, int OOFF, int INS, int OUTS>
__global__ void __launch_bounds__(256)
k_convM(const unsigned short* __restrict__ in, const unsigned short* __restrict__ wg,
        const float* __restrict__ bias, unsigned short* __restrict__ out, int CH){
    constexpr int N  = OL * OL;
    constexpr int NT = (N + 15) / 16;
    const int tid = threadIdx.x;
    const int wave = tid >> 6, lane = tid & 63;
    const int q = lane >> 4, nn = lane & 15;
    const int nw = gridDim.x * 4;

    bf16x8 af[2][9];
#pragma unroll
    for (int mt = 0; mt < 2; mt++)
#pragma unroll
        for (int s = 0; s < 9; s++)
            af[mt][s] = *(const bf16x8*)(wg + s*1024 + (mt*16 + nn)*32 + q*8);
    float4 bc0 = *(const float4*)(bias + q*4);
    float4 bc1 = *(const float4*)(bias + 16 + q*4);

    for (int t = blockIdx.x*4 + wave; t < CH*NT; t += nw){
        int img = t / NT, tt = t - img*NT;
        const unsigned short* inb = in + (size_t)img * INS;
        unsigned short* outb = out + (size_t)img * OUTS;
        int pos = tt*16 + nn;
        int pc  = pos < N ? pos : N - 1;
        int oy = pc / OL, ox = pc - oy*OL;
        const unsigned short* ib = inb + (oy*IL + ox)*32 + q*8;
        f32x4 acc0 = {0.f,0.f,0.f,0.f}, acc1 = {0.f,0.f,0.f,0.f};
#pragma unroll
        for (int r = 0; r < 3; r++){
            bf16x8 b0 = *(const bf16x8*)(ib + (r*IL + 0)*32);
            bf16x8 b1 = *(const bf16x8*)(ib + (r*IL + 1)*32);
            bf16x8 b2 = *(const bf16x8*)(ib + (r*IL + 2)*32);
            acc0 = __builtin_amdgcn_mfma_f32_16x16x32_bf16(af[0][r*3+0], b0, acc0, 0,0,0);
            acc1 = __builtin_amdgcn_mfma_f32_16x16x32_bf16(af[1][r*3+0], b0, acc1, 0,0,0);
            acc0 = __builtin_amdgcn_mfma_f32_16x16x32_bf16(af[0][r*3+1], b1, acc0, 0,0,0);
            acc1 = __builtin_amdgcn_mfma_f32_16x16x32_bf16(af[1][r*3+1], b1, acc1, 0,0,0);
            acc0 = __builtin_amdgcn_mfma_f32_16x16x32_bf16(af[0][r*3+2], b2, acc0, 0,0,0);
            acc1 = __builtin_amdgcn_mfma_f32_16x16x32_bf16(af[1][r*3+2], b2, acc1, 0,0,0);
        }
        if (pos < N){
            int opix = oy*OW + ox + OOFF;
            ushort4 o0, o1;
            o0.x = f2b(fast_tanh(acc0[0] + bc0.x)); o0.y = f2b(fast_tanh(acc0[1] + bc0.y));
            o0.z = f2b(fast_tanh(acc0[2] + bc0.z)); o0.w = f2b(fast_tanh(acc0[3] + bc0.w));
            o1.x = f2b(fast_tanh(acc1[0] + bc1.x)); o1.y = f2b(fast_tanh(acc1[1] + bc1.y));
            o1.z = f2b(fast_tanh(acc1[2] + bc1.z)); o1.w = f2b(fast_tanh(acc1[3] + bc1.w));
            *(ushort4*)(outb + opix*32 + q*4)      = o0;
            *(ushort4*)(outb + opix*32 + 16 + q*4) = o1;
        }
    }
}

// ===== encoder GEMM, K split across 4 waves ================================
__global__ void __launch_bounds__(256)
k_encg(const unsigned short* __restrict__ A2, const unsigned short* __restrict__ elwT,
       const float* __restrict__ elb, float* __restrict__ z1, int cb, int CH){
    __shared__ float red[4][64][4];
    int wave = threadIdx.x >> 6, lane = threadIdx.x & 63;
    int q = lane >> 4, nn = lane & 15;
    int imgb = blockIdx.x*16;
    const unsigned short* ap = A2 + (size_t)(imgb + nn)*15488 + wave*3872 + q*8;
    const unsigned short* bp = elwT + (size_t)nn*15488 + wave*3872 + q*8;
    f32x4 acc = {0.f,0.f,0.f,0.f};
#pragma unroll 4
    for (int kk = 0; kk < 121; kk++){
        bf16x8 a = *(const bf16x8*)(ap + kk*32);
        bf16x8 b = *(const bf16x8*)(bp + kk*32);
        acc = __builtin_amdgcn_mfma_f32_16x16x32_bf16(a, b, acc, 0,0,0);
    }
#pragma unroll
    for (int i = 0; i < 4; i++) red[wave][lane][i] = acc[i];
    __syncthreads();
    if (wave == 0){
        float eb = elb[nn];
#pragma unroll
        for (int i = 0; i < 4; i++){
            float s = red[0][lane][i] + red[1][lane][i] + red[2][lane][i] + red[3][lane][i];
            z1[(size_t)(cb + imgb + q*4 + i)*16 + nn] = s + eb;
        }
    }
}

// ===== halo zero ===========================================================
__global__ void __launch_bounds__(256)
k_halo(unsigned short* __restrict__ D0, unsigned short* __restrict__ D1, int CH){
    int gid = blockIdx.x*256 + threadIdx.x;
    uint4 zq = {0,0,0,0};
    if (gid < CH*676){
        int img = gid / 676, px = gid - img*676;
        int y = px / 26, x = px - y*26;
        if (y < 2 || y >= 24 || x < 2 || x >= 24){
            uint4* p = (uint4*)(D0 + (size_t)img*21632 + px*32);
            p[0] = zq; p[1] = zq; p[2] = zq; p[3] = zq;
        }
    } else {
        int g2 = gid - CH*676;
        if (g2 >= CH*784) return;
        int img = g2 / 784, px = g2 - img*784;
        int y = px / 28, x = px - y*28;
        if (y < 2 || y >= 26 || x < 2 || x >= 26){
            uint4* p = (uint4*)(D1 + (size_t)img*25088 + px*32);
            p[0] = zq; p[1] = zq; p[2] = zq; p[3] = zq;
        }
    }
}

// ===== decoder GEMV ========================================================
__global__ void __launch_bounds__(256)
k_decg(const float* __restrict__ z1, const unsigned short* __restrict__ dlwT,
       const float* __restrict__ dlb, unsigned short* __restrict__ D0,
       int cb, int CH){
    __shared__ float zl[256];
    int tid = threadIdx.x, ib = blockIdx.y;
    zl[tid] = z1[(size_t)(cb + ib*16 + (tid >> 4))*16 + (tid & 15)];
    __syncthreads();
    int ci = tid & 31, po = tid >> 5;
    int pos = blockIdx.x*8 + po;
    if (pos >= 484) return;
    int y = pos / 22, xx = pos - y*22;
    float bias = dlb[ci*484 + pos];
    const unsigned short* w = dlwT + (size_t)(pos*32 + ci)*16;
    bf16x8 w0 = *(const bf16x8*)(w);
    bf16x8 w1 = *(const bf16x8*)(w + 8);
    float wf[16];
#pragma unroll
    for (int j = 0; j < 8; j++){
        wf[j]   = b2f((unsigned short)w0[j]);
        wf[8+j] = b2f((unsigned short)w1[j]);
    }
    int opix = ((y+2)*26 + xx + 2)*32 + ci;
#pragma unroll 1
    for (int i = 0; i < 16; i++){
        float a = bias;
#pragma unroll
        for (int l = 0; l < 16; l++) a += zl[i*16 + l] * wf[l];
        D0[(size_t)(ib*16 + i)*21632 + opix] = f2b(fast_tanh(a));
    }
}

// ===== convT2: 32->1 =======================================================
__global__ void __launch_bounds__(256)
k_convT2(const unsigned short* __restrict__ D2, const float* __restrict__ t2w,
         const float* __restrict__ t2b, float* __restrict__ out, int cb, int CH){
    int gid = blockIdx.x*256 + threadIdx.x;
    if (gid >= CH*784) return;
    int b = gid / 784, o = gid - b*784;
    int y = o / 28, xx = o - y*28;
    const unsigned short* db = D2 + (size_t)b*21632;
    float a = t2b[0];
#pragma unroll
    for (int r = 0; r < 3; r++){
        int iy = y + r - 2;
        if ((unsigned)iy >= 26u) continue;
#pragma unroll
        for (int s = 0; s < 3; s++){
            int ix = xx + s - 2;
            if ((unsigned)ix >= 26u) continue;
            const unsigned short* pp = db + (iy*26 + ix)*32;
            int wi = (2-r)*3 + (2-s);
#pragma unroll
            for (int g = 0; g < 4; g++){
                bf16x8 h = *(const bf16x8*)(pp + g*8);
#pragma unroll
                for (int j = 0; j < 8; j++)
                    a += b2f((unsigned short)h[j]) * t2w[(g*8+j)*9 + wi];
            }
        }
    }
    out[(size_t)(cb + b)*784 + o] = a;
}

// ===== FUSED FALLBACK (round-3, proven) ====================================
template<int LOUT, int INW, int OUTW, int OUTOFF>
__device__ __forceinline__ void conv_gemm(const unsigned short* __restrict__ Wg,
                                          const float* __restrict__ bias,
                                          const unsigned short* inL,
                                          unsigned short* outL, int tid){
    constexpr int N  = LOUT * LOUT;
    constexpr int NT = (N + 15) / 16;
    const int lane  = tid & 63;
    const int wave  = tid >> 6;
    const int mtile = wave & 1;
    const int quad  = lane >> 4;
    const int nn    = lane & 15;
    bf16x8 afr[9];
    const unsigned short* wp = Wg + (mtile*16 + nn)*32 + quad*8;
#pragma unroll
    for (int s = 0; s < 9; s++)
        afr[s] = *(const bf16x8*)(wp + s*1024);
    float4 bco = *(const float4*)(bias + mtile*16 + quad*4);
    for (int t = (wave >> 1); t < NT; t += 2){
        int pos = t*16 + nn;
        int pc  = pos < N ? pos : N - 1;
        int y = pc / LOUT, x = pc - y*LOUT;
        const unsigned short* ib = inL + (y*INW + x)*32 + quad*8;
        f32x4 acc = {0.f, 0.f, 0.f, 0.f};
#pragma unroll
        for (int r = 0; r < 3; r++)
#pragma unroll
            for (int s = 0; s < 3; s++)
                acc = __builtin_amdgcn_mfma_f32_16x16x32_bf16(
                        afr[r*3+s], *(const bf16x8*)(ib + (r*INW + s)*32), acc, 0, 0, 0);
        if (pos < N){
            ushort4 o;
            o.x = f2b(fast_tanh(acc[0] + bco.x));
            o.y = f2b(fast_tanh(acc[1] + bco.y));
            o.z = f2b(fast_tanh(acc[2] + bco.z));
            o.w = f2b(fast_tanh(acc[3] + bco.w));
            int opix = y*OUTW + x + OUTOFF;
            *(ushort4*)(outL + opix*32 + mtile*16 + quad*4) = o;
        }
    }
}

__global__ void __launch_bounds__(256)
k_enc_f(const float* __restrict__ x,
        const float* __restrict__ c0w, const float* __restrict__ c0b,
        const unsigned short* __restrict__ wc1, const float* __restrict__ c1b,
        const unsigned short* __restrict__ wc2, const float* __restrict__ c2b,
        const float* __restrict__ elw, const float* __restrict__ elb,
        float* __restrict__ z1){
    __shared__ float X[784];
    __shared__ __align__(16) unsigned short H0[21632];
    __shared__ __align__(16) unsigned short H1[18432];
    __shared__ __align__(16) unsigned short H2[15488];
    __shared__ float red[16*17];
    const int tid = threadIdx.x, b = blockIdx.x;
    for (int i = tid; i < 784; i += 256) X[i] = x[b*784 + i];
    __syncthreads();
    for (int pos = tid; pos < 676; pos += 256){
        int y = pos / 26, xx = pos - y*26;
        float v[9];
#pragma unroll
        for (int r = 0; r < 3; r++)
#pragma unroll
            for (int s = 0; s < 3; s++)
                v[r*3+s] = X[(y+r)*28 + xx + s];
#pragma unroll
        for (int g = 0; g < 8; g++){
            float a0 = c0b[g*4+0], a1 = c0b[g*4+1], a2 = c0b[g*4+2], a3 = c0b[g*4+3];
#pragma unroll
            for (int k = 0; k < 9; k++){
                a0 += v[k] * c0w[(g*4+0)*9 + k];
                a1 += v[k] * c0w[(g*4+1)*9 + k];
                a2 += v[k] * c0w[(g*4+2)*9 + k];
                a3 += v[k] * c0w[(g*4+3)*9 + k];
            }
            ushort4 o;
            o.x = f2b(fast_tanh(a0)); o.y = f2b(fast_tanh(a1));
            o.z = f2b(fast_tanh(a2)); o.w = f2b(fast_tanh(a3));
            *(ushort4*)(H0 + pos*32 + g*4) = o;
        }
    }
    __syncthreads();
    conv_gemm<24, 26, 24, 0>(wc1, c1b, H0, H1, tid);
    __syncthreads();
    conv_gemm<22, 24, 22, 0>(wc2, c2b, H1, H2, tid);
    __syncthreads();
    {
        int fg = tid >> 4, l = tid & 15;
        float a = 0.f;
        for (int ci = 0; ci < 32; ci++)
            for (int pos = fg; pos < 484; pos += 16)
                a += b2f(H2[pos*32 + ci]) * elw[(ci*484 + pos)*16 + l];
        red[fg*17 + l] = a;
        __syncthreads();
        if (tid < 16){
            float s = elb[tid];
#pragma unroll
            for (int g = 0; g < 16; g++) s += red[g*17 + tid];
            z1[b*16 + tid] = s;
        }
    }
}

__global__ void __launch_bounds__(256)
k_dec_f(const float* __restrict__ z1,
        const float* __restrict__ dlw, const float* __restrict__ dlb,
        const unsigned short* __restrict__ wt0, const float* __restrict__ t0b,
        const unsigned short* __restrict__ wt1, const float* __restrict__ t1b,
        const float* __restrict__ t2w, const float* __restrict__ t2b,
        float* __restrict__ out){
    __shared__ __align__(16) unsigned short D0[21632];
    __shared__ __align__(16) unsigned short D1[25088];
    __shared__ __align__(16) unsigned short D2[28800];
    const int tid = threadIdx.x, b = blockIdx.x;
    {
        uint4 zq = {0,0,0,0};
        for (int i = tid; i < 2704; i += 256) ((uint4*)D0)[i] = zq;
        for (int i = tid; i < 3136; i += 256) ((uint4*)D1)[i] = zq;
        for (int i = tid; i < 3600; i += 256) ((uint4*)D2)[i] = zq;
    }
    float zz[16];
#pragma unroll
    for (int l = 0; l < 16; l++) zz[l] = z1[b*16 + l];
    __syncthreads();
    for (int f = tid; f < 15488; f += 256){
        float a = dlb[f];
#pragma unroll
        for (int l = 0; l < 16; l++) a += zz[l] * dlw[l*15488 + f];
        int ci = f / 484, pos = f - ci*484;
        int y = pos / 22, xx = pos - y*22;
        D0[((y+2)*26 + xx + 2)*32 + ci] = f2b(fast_tanh(a));
    }
    __syncthreads();
    conv_gemm<24, 26, 28, 58>(wt0, t0b, D0, D1, tid);
    __syncthreads();
    conv_gemm<26, 28, 30, 62>(wt1, t1b, D1, D2, tid);
    __syncthreads();
    for (int o = tid; o < 784; o += 256){
        int y = o / 28, xx = o - y*28;
        float a = t2b[0];
#pragma unroll
        for (int r = 0; r < 3; r++)
#pragma unroll
            for (int s = 0; s < 3; s++){
                const unsigned short* pp = D2 + ((y+r)*30 + xx + s)*32;
                int wi = (2-r)*3 + (2-s);
#pragma unroll
                for (int g = 0; g < 4; g++){
                    bf16x8 h = *(const bf16x8*)(pp + g*8);
#pragma unroll
                    for (int j = 0; j < 8; j++)
                        a += b2f((unsigned short)h[j]) * t2w[(g*8+j)*9 + wi];
                }
            }
        out[(size_t)b*784 + o] = a;
    }
}

// ===== hypernetwork, parallel 3-kernel path ================================
// k_hyp1: p2[stage][64] for all 80 stages
__global__ void __launch_bounds__(64)
k_hyp1(const float* __restrict__ h1w, const float* __restrict__ h1b,
       const float* __restrict__ h2w, const float* __restrict__ h2b,
       float* __restrict__ p2ws){
    __shared__ float p1l[64];
    int sidx = blockIdx.x, tid = threadIdx.x;
    float t = stage_t(sidx);
    p1l[tid] = fast_tanh(t * h1w[tid] + h1b[tid]);
    __syncthreads();
    float a0 = h2b[tid], a1 = 0.f, a2 = 0.f, a3 = 0.f;
#pragma unroll
    for (int k = 0; k < 64; k += 4){
        a0 += p1l[k]   * h2w[(k)*64   + tid];
        a1 += p1l[k+1] * h2w[(k+1)*64 + tid];
        a2 += p1l[k+2] * h2w[(k+2)*64 + tid];
        a3 += p1l[k+3] * h2w[(k+3)*64 + tid];
    }
    p2ws[sidx*64 + tid] = fast_tanh((a0 + a1) + (a2 + a3));
}

// k_hyp2: p3[stage][m] = h3b[m] + sum_k p2[k]*h3w[k*3136+m]; grid (13, 80)
__global__ void __launch_bounds__(256)
k_hyp2(const float* __restrict__ p2ws, const float* __restrict__ h3w,
       const float* __restrict__ h3b, float* __restrict__ p3ws){
    __shared__ float p2l[64];
    int sidx = blockIdx.y, tid = threadIdx.x;
    if (tid < 64) p2l[tid] = p2ws[sidx*64 + tid];
    __syncthreads();
    int m = blockIdx.x*256 + tid;
    if (m >= 3136) return;
    const float* hp = h3w + m;
    float a0 = h3b[m], a1 = 0.f, a2 = 0.f, a3 = 0.f;
#pragma unroll
    for (int k = 0; k < 64; k += 4){
        a0 += p2l[k]   * hp[(size_t)(k)*3136];
        a1 += p2l[k+1] * hp[(size_t)(k+1)*3136];
        a2 += p2l[k+2] * hp[(size_t)(k+2)*3136];
        a3 += p2l[k+3] * hp[(size_t)(k+3)*3136];
    }
    p3ws[(size_t)sidx*3200 + m] = (a0 + a1) + (a2 + a3);
}

// k_hyp3: epilogue -> hyp stage layout (stride 2304):
// [0,1024)=W[w*16+d], [1024,2048)=Ut[d*64+w], [2048,2112)=Bb, [2112,2176)=strace
__global__ void __launch_bounds__(256)
k_hyp3(const float* __restrict__ p3ws, float* __restrict__ hyp){
    __shared__ float partial[256];
    int sidx = blockIdx.x, tid = threadIdx.x;
    const float* p3 = p3ws + (size_t)sidx*3200;
    float* g = hyp + (size_t)sidx*2304;
    int m0 = tid*4;
    float4 w4 = *(const float4*)(p3 + m0);
    float4 a4 = *(const float4*)(p3 + 1024 + m0);
    float4 s4 = *(const float4*)(p3 + 2048 + m0);
    float4 u4;
    u4.x = a4.x * fast_sigmoid(s4.x);
    u4.y = a4.y * fast_sigmoid(s4.y);
    u4.z = a4.z * fast_sigmoid(s4.z);
    u4.w = a4.w * fast_sigmoid(s4.w);
    *(float4*)(g + m0) = w4;                            // W
    g[1024 + ((m0+0) & 15)*64 + ((m0+0) >> 4)] = u4.x;  // Ut scatter
    g[1024 + ((m0+1) & 15)*64 + ((m0+1) >> 4)] = u4.y;
    g[1024 + ((m0+2) & 15)*64 + ((m0+2) >> 4)] = u4.z;
    g[1024 + ((m0+3) & 15)*64 + ((m0+3) >> 4)] = u4.w;
    partial[tid] = w4.x*u4.x + w4.y*u4.y + w4.z*u4.z + w4.w*u4.w;
    __syncthreads();
    if (tid < 64){
        g[2048 + tid] = p3[3072 + tid];                 // Bb
        g[2112 + tid] = partial[tid*4] + partial[tid*4+1]
                      + partial[tid*4+2] + partial[tid*4+3];  // strace
    }
}

// ===== single-block hyper (fallback only) ==================================
__global__ void k_hyper(const float* __restrict__ h1w, const float* __restrict__ h1b,
                        const float* __restrict__ h2w, const float* __restrict__ h2b,
                        const float* __restrict__ h3w, const float* __restrict__ h3b,
                        float* __restrict__ hyp){
    int sidx = blockIdx.x;
    float t = stage_t(sidx);
    __shared__ float p1[64], p2[64];
    __shared__ float p3[3136];
    int tid = threadIdx.x;
    if (tid < 64) p1[tid] = fast_tanh(t * h1w[tid] + h1b[tid]);
    __syncthreads();
    if (tid < 64){
        float a = h2b[tid];
#pragma unroll
        for (int k = 0; k < 64; k++) a += p1[k] * h2w[k*64 + tid];
        p2[tid] = fast_tanh(a);
    }
    __syncthreads();
    for (int m = tid; m < 3136; m += 256){
        float a = h3b[m];
#pragma unroll
        for (int k = 0; k < 64; k++) a += p2[k] * h3w[k*3136 + m];
        p3[m] = a;
    }
    __syncthreads();
    float* g = hyp + (size_t)sidx * 2304;
    for (int m = tid; m < 1024; m += 256){
        g[m] = p3[m];
        float u = p3[1024 + m] * fast_sigmoid(p3[2048 + m]);
        g[1024 + (m & 15)*64 + (m >> 4)] = u;
        p3[1024 + m] = u;
    }
    if (tid < 64) g[2048 + tid] = p3[3072 + tid];
    __syncthreads();
    if (tid < 64){
        float s = 0.f;
#pragma unroll
        for (int d = 0; d < 16; d++) s += p3[tid*16 + d] * p3[1024 + tid*16 + d];
        g[2112 + tid] = s;
    }
}

// ===== CNF RK4: single-wave blocks, 4 rows/wave, prefetched params =========
struct PF { float4 Wr[4]; float4 Ur[4]; float Bb, st; };

__device__ __forceinline__ void load_pf(const float* __restrict__ g, int lane, PF& p){
    const float4* w4 = (const float4*)(g + lane*16);
    p.Wr[0] = w4[0]; p.Wr[1] = w4[1]; p.Wr[2] = w4[2]; p.Wr[3] = w4[3];
    const float4* u4 = (const float4*)(g + 1024 + lane*16);
    p.Ur[0] = u4[0]; p.Ur[1] = u4[1]; p.Ur[2] = u4[2]; p.Ur[3] = u4[3];
    p.Bb = g[2048 + lane];
    p.st = g[2112 + lane];
}

__global__ void __launch_bounds__(64)
k_cnf(const float* __restrict__ z1, const float* __restrict__ hyp,
      float* __restrict__ part){
    __shared__ __align__(16) float Utl[16*68];
    __shared__ __align__(16) float hhl[4*68];
    __shared__ __align__(16) float zsl[64];
    __shared__ __align__(16) float sl[64];
    __shared__ float red2[4];

    const int lane = threadIdx.x;
    const int bloc = lane >> 4, d = lane & 15;
    const int du = lane >> 2, wb = (lane & 3) * 16;
    const float dt = -0.5f;

    float z  = z1[(size_t)(blockIdx.x*4 + bloc)*16 + d];
    float zs = z;
    float lp = 0.f;
    float zacc = 0.f, lacc = 0.f;

    PF cur, nxt;
    load_pf(hyp, lane, cur);

    for (int sidx = 0; sidx < 80; sidx++){
        *(float4*)(Utl + du*68 + wb)      = cur.Ur[0];
        *(float4*)(Utl + du*68 + wb + 4)  = cur.Ur[1];
        *(float4*)(Utl + du*68 + wb + 8)  = cur.Ur[2];
        *(float4*)(Utl + du*68 + wb + 12) = cur.Ur[3];
        sl[lane]  = cur.st;
        zsl[lane] = zs;
        __syncthreads();
        if (sidx < 79) load_pf(hyp + (size_t)(sidx + 1)*2304, lane, nxt);

        float hhv[4];
#pragma unroll
        for (int b = 0; b < 4; b++){
            const float4* zp = (const float4*)(zsl + b*16);
            float4 z0 = zp[0], z1v = zp[1], z2 = zp[2], z3 = zp[3];
            float a = cur.Bb;
            a += z0.x*cur.Wr[0].x + z0.y*cur.Wr[0].y + z0.z*cur.Wr[0].z + z0.w*cur.Wr[0].w;
            a += z1v.x*cur.Wr[1].x + z1v.y*cur.Wr[1].y + z1v.z*cur.Wr[1].z + z1v.w*cur.Wr[1].w;
            a += z2.x*cur.Wr[2].x + z2.y*cur.Wr[2].y + z2.z*cur.Wr[2].z + z2.w*cur.Wr[2].w;
            a += z3.x*cur.Wr[3].x + z3.y*cur.Wr[3].y + z3.z*cur.Wr[3].z + z3.w*cur.Wr[3].w;
            hhv[b] = fast_tanh(a);
        }
#pragma unroll
        for (int b = 0; b < 4; b++) hhl[b*68 + lane] = hhv[b];
        __syncthreads();

        float dz = 0.f;
        const float4* h4p = (const float4*)(hhl + bloc*68);
        const float4* u4p = (const float4*)(Utl + d*68);
#pragma unroll
        for (int w4 = 0; w4 < 16; w4++){
            float4 h = h4p[w4], u = u4p[w4];
            dz += h.x*u.x + h.y*u.y + h.z*u.z + h.w*u.w;
        }
        float4 hh4 = h4p[d];
        float4 s4  = ((const float4*)sl)[d];
        float tr = (1.f - hh4.x*hh4.x)*s4.x + (1.f - hh4.y*hh4.y)*s4.y
                 + (1.f - hh4.z*hh4.z)*s4.z + (1.f - hh4.w*hh4.w)*s4.w;
#pragma unroll
        for (int off = 1; off < 16; off <<= 1)
            tr += __shfl_xor(tr, off, 16);
        dz *= (1.f/64.f);
        float dl = -tr * (1.f/64.f);

        int st = sidx & 3;
        float wgt = (st == 0 || st == 3) ? 1.f : 2.f;
        zacc += wgt * dz;
        lacc += wgt * dl;
        if (st < 3){
            float a = (st == 2) ? 1.0f : 0.5f;
            zs = z + a * dt * dz;
        } else {
            z  += (dt/6.f) * zacc;
            lp += (dt/6.f) * lacc;
            zs = z;
            zacc = 0.f; lacc = 0.f;
        }
        cur = nxt;
    }

    float sq = z * z;
#pragma unroll
    for (int off = 1; off < 16; off <<= 1) sq += __shfl_xor(sq, off, 16);
    float logp = -0.5f * (16.f*1.8378770664093453f + 16.f*(-2.302585092994046f) + sq*10.f);
    float contrib = logp - lp;
    if (d == 0) red2[bloc] = contrib;
    __syncthreads();
    if (lane == 0)
        part[blockIdx.x] = red2[0] + red2[1] + red2[2] + red2[3];
}

__global__ void k_final(const float* __restrict__ part, float* __restrict__ out){
    __shared__ float red[256];
    int tid = threadIdx.x;
    red[tid] = part[tid] + part[tid + 256];
    __syncthreads();
    for (int s = 128; s > 0; s >>= 1){
        if (tid < s) red[tid] += red[tid + s];
        __syncthreads();
    }
    if (tid == 0) out[1605632] = red[0] * (1.f/2048.f);
}

extern "C" void kernel_launch(void* const* d_in, const int* in_sizes, int n_in,
                              void* d_out, int out_size, void* d_ws, size_t ws_size,
                              hipStream_t stream){
    const float* x   = (const float*)d_in[0];
    const float* c0w = (const float*)d_in[1];
    const float* c0b = (const float*)d_in[2];
    const float* c1w = (const float*)d_in[3];
    const float* c1b = (const float*)d_in[4];
    const float* c2w = (const float*)d_in[5];
    const float* c2b = (const float*)d_in[6];
    const float* elw = (const float*)d_in[7];
    const float* elb = (const float*)d_in[8];
    const float* dlw = (const float*)d_in[9];
    const float* dlb = (const float*)d_in[10];
    const float* t0w = (const float*)d_in[11];
    const float* t0b = (const float*)d_in[12];
    const float* t1w = (const float*)d_in[13];
    const float* t1b = (const float*)d_in[14];
    const float* t2w = (const float*)d_in[15];
    const float* t2b = (const float*)d_in[16];
    const float* h1w = (const float*)d_in[17];
    const float* h1b = (const float*)d_in[18];
    const float* h2w = (const float*)d_in[19];
    const float* h2b = (const float*)d_in[20];
    const float* h3w = (const float*)d_in[21];
    const float* h3b = (const float*)d_in[22];

    float* ws   = (float*)d_ws;
    float* z1   = ws;                          // 32768 f
    float* hyp  = z1 + 32768;                  // 184320 f (80*2304)
    float* part = hyp + 184320;                // 512 f
    float* p2ws = part + 512;                  // 5120 f
    float* p3ws = p2ws + 5120;                 // 256000 f (80*3200)
    unsigned short* wc1  = (unsigned short*)(p3ws + 256000);  // 9216 each
    unsigned short* wc2  = wc1 + 9216;
    unsigned short* wt0  = wc2 + 9216;
    unsigned short* wt1  = wt0 + 9216;
    unsigned short* elwT = wt1 + 9216;         // 247808
    unsigned short* dlwT = elwT + 247808;      // 247808
    unsigned short* act  = dlwT + 247808;
    float* rec  = (float*)d_out;

    const size_t MISC = 2979840;               // bytes up to `act`
    int CH = 0;
    const int cands[6] = {2048, 1024, 512, 256, 128, 64};
    for (int c = 0; c < 6; c++){
        size_t need = MISC + (size_t)cands[c] * 111104;
        if (need <= ws_size){ CH = cands[c]; break; }
    }

    if (CH == 0){
        // tiny-ws fallback: single-block hyper (no p3ws staging)
        k_hyper<<<80, 256, 0, stream>>>(h1w, h1b, h2w, h2b, h3w, h3b, hyp);
        k_prep <<<64,   256, 0, stream>>>(c1w, c2w, t0w, t1w, elw, dlw,
                                          wc1, wc2, wt0, wt1, wt1, wt1, 0);
        k_enc_f<<<2048, 256, 0, stream>>>(x, c0w, c0b, wc1, c1b, wc2, c2b, elw, elb, z1);
        k_cnf  <<<512,   64, 0, stream>>>(z1, hyp, part);
        k_dec_f<<<2048, 256, 0, stream>>>(z1, dlw, dlb, wt0, t0b, wt1, t1b, t2w, t2b, rec);
        k_final<<<1,    256, 0, stream>>>(part, rec);
        return;
    }

    k_hyp1<<<80,           64, 0, stream>>>(h1w, h1b, h2w, h2b, p2ws);
    k_hyp2<<<dim3(13,80), 256, 0, stream>>>(p2ws, h3w, h3b, p3ws);
    k_hyp3<<<80,          256, 0, stream>>>(p3ws, hyp);

    k_prep<<<64, 256, 0, stream>>>(c1w, c2w, t0w, t1w, elw, dlw,
                                   wc1, wc2, wt0, wt1, elwT, dlwT, 1);

    unsigned short* R0 = act;                          // A0 / D0 / D2 : CH*21632
    unsigned short* R1 = R0 + (size_t)CH*21632;        // A1 ; D1 head : CH*18432
    unsigned short* R2 = R1 + (size_t)CH*18432;        // A2 ; D1 tail : CH*15488
    unsigned short* D1 = R1;                           // CH*25088 <= CH*33920

    for (int cb = 0; cb < Bsz; cb += CH){
        k_conv0<<<(CH*676 + 255)/256, 256, 0, stream>>>(x, c0w, c0b, R0, cb, CH);
        k_convM<26,24,24, 0, 21632, 18432><<<(CH*36 + 15)/16, 256, 0, stream>>>(R0, wc1, c1b, R1, CH);
        k_convM<24,22,22, 0, 18432, 15488><<<(CH*31 + 15)/16, 256, 0, stream>>>(R1, wc2, c2b, R2, CH);
        k_encg<<<CH/16, 256, 0, stream>>>(R2, elwT, elb, z1, cb, CH);
        k_halo<<<(CH*1460 + 255)/256, 256, 0, stream>>>(R0, D1, CH);
        k_decg<<<dim3(61, CH/16), 256, 0, stream>>>(z1, dlwT, dlb, R0, cb, CH);
        k_convM<26,24,28,58, 21632, 25088><<<(CH*36 + 15)/16, 256, 0, stream>>>(R0, wt0, t0b, D1, CH);
        k_convM<28,26,26, 0, 25088, 21632><<<(CH*43 + 15)/16, 256, 0, stream>>>(D1, wt1, t1b, R0, CH);
        k_convT2<<<(CH*784 + 255)/256, 256, 0, stream>>>(R0, t2w, t2b, rec, cb, CH);
    }
    k_cnf  <<<512,  64, 0, stream>>>(z1, hyp, part);
    k_final<<<1,   256, 0, stream>>>(part, rec);
}

// Round 7
// 662.624 us; speedup vs baseline: 8.9919x; 1.0054x over previous
//
#include <hip/hip_runtime.h>
#include <math.h>

#define Bsz 2048

using bf16x8 = __attribute__((ext_vector_type(8))) short;
using f32x4  = __attribute__((ext_vector_type(4))) float;

__device__ __forceinline__ float fast_tanh(float x){
    float e = __expf(2.0f * x);
    return 1.0f - 2.0f / (e + 1.0f);
}
__device__ __forceinline__ float fast_sigmoid(float x){
    return 1.0f / (1.0f + __expf(-x));
}
__device__ __forceinline__ unsigned short f2b(float f){
    union { float f; unsigned u; } v; v.f = f;
    unsigned r = v.u + 0x7FFFu + ((v.u >> 16) & 1u);
    return (unsigned short)(r >> 16);
}
__device__ __forceinline__ float b2f(unsigned short s){
    union { unsigned u; float f; } v; v.u = ((unsigned)s) << 16;
    return v.f;
}

__device__ __forceinline__ float stage_t(int sidx){
    int i  = sidx >> 2, st = sidx & 3;
    float t = 10.0f - 0.5f * (float)i;
    if (st == 1 || st == 2) t -= 0.25f;
    else if (st == 3)       t -= 0.5f;
    return t;
}

// ===== weight prep (+ z1 bias init for atomic encoder) ======================
__global__ void k_prep(const float* __restrict__ c1w, const float* __restrict__ c2w,
                       const float* __restrict__ t0w, const float* __restrict__ t1w,
                       const float* __restrict__ elw, const float* __restrict__ dlw,
                       const float* __restrict__ elb,
                       unsigned short* __restrict__ wc1, unsigned short* __restrict__ wc2,
                       unsigned short* __restrict__ wt0, unsigned short* __restrict__ wt1,
                       unsigned short* __restrict__ elwT, unsigned short* __restrict__ dlwT,
                       float* __restrict__ z1, int full){
    int gsz = gridDim.x * 256;
    for (int i = blockIdx.x*256 + threadIdx.x; i < 9216; i += gsz){
        int ci = i & 31, co = (i >> 5) & 31, s = i >> 10;
        wc1[i] = f2b(c1w[(co*32 + ci)*9 + s]);
        wc2[i] = f2b(c2w[(co*32 + ci)*9 + s]);
        wt0[i] = f2b(t0w[(ci*32 + co)*9 + (8 - s)]);
        wt1[i] = f2b(t1w[(ci*32 + co)*9 + (8 - s)]);
    }
    if (!full) return;
    for (int i = blockIdx.x*256 + threadIdx.x; i < 32768; i += gsz)
        z1[i] = elb[i & 15];
    for (int i = blockIdx.x*256 + threadIdx.x; i < 247808; i += gsz){
        int l = i / 15488, f2 = i - l*15488;
        int pos = f2 >> 5, ci = f2 & 31;
        elwT[i] = f2b(elw[(ci*484 + pos)*16 + l]);
    }
    for (int i = blockIdx.x*256 + threadIdx.x; i < 247808; i += gsz){
        int f2 = i >> 4, l = i & 15;
        int pos = f2 >> 5, ci = f2 & 31;
        dlwT[i] = f2b(dlw[l*15488 + ci*484 + pos]);
    }
}

// ===== conv0: 1->32, VALU ==================================================
__global__ void __launch_bounds__(256)
k_conv0(const float* __restrict__ x, const float* __restrict__ c0w,
        const float* __restrict__ c0b, unsigned short* __restrict__ A0,
        int cb, int CH){
    int gid = blockIdx.x*256 + threadIdx.x;
    if (gid >= CH*676) return;
    int b = gid / 676, pos = gid - b*676;
    int y = pos / 26, xx = pos - y*26;
    const float* xin = x + (size_t)(cb + b)*784;
    float v[9];
#pragma unroll
    for (int r = 0; r < 3; r++)
#pragma unroll
        for (int s = 0; s < 3; s++)
            v[r*3+s] = xin[(y+r)*28 + xx + s];
    unsigned short* ob = A0 + (size_t)b*21632 + pos*32;
#pragma unroll
    for (int g = 0; g < 8; g++){
        float a0 = c0b[g*4+0], a1 = c0b[g*4+1], a2 = c0b[g*4+2], a3 = c0b[g*4+3];
#pragma unroll
        for (int k = 0; k < 9; k++){
            a0 += v[k] * c0w[(g*4+0)*9 + k];
            a1 += v[k] * c0w[(g*4+1)*9 + k];
            a2 += v[k] * c0w[(g*4+2)*9 + k];
            a3 += v[k] * c0w[(g*4+3)*9 + k];
        }
        ushort4 o;
        o.x = f2b(fast_tanh(a0)); o.y = f2b(fast_tanh(a1));
        o.z = f2b(fast_tanh(a2)); o.w = f2b(fast_tanh(a3));
        *(ushort4*)(ob + g*4) = o;
    }
}

// ===== MFMA conv layer, tile-parallel across all images ====================
template<int IL, int OL, int OW, int OOFF, int INS, int OUTS>
__global__ void __launch_bounds__(256)
k_convM(const unsigned short* __restrict__ in, const unsigned short* __restrict__ wg,
        const float* __restrict__ bias, unsigned short* __restrict__ out, int CH){
    constexpr int N  = OL * OL;
    constexpr int NT = (N + 15) / 16;
    const int tid = threadIdx.x;
    const int wave = tid >> 6, lane = tid & 63;
    const int q = lane >> 4, nn = lane & 15;
    const int nw = gridDim.x * 4;

    bf16x8 af[2][9];
#pragma unroll
    for (int mt = 0; mt < 2; mt++)
#pragma unroll
        for (int s = 0; s < 9; s++)
            af[mt][s] = *(const bf16x8*)(wg + s*1024 + (mt*16 + nn)*32 + q*8);
    float4 bc0 = *(const float4*)(bias + q*4);
    float4 bc1 = *(const float4*)(bias + 16 + q*4);

    for (int t = blockIdx.x*4 + wave; t < CH*NT; t += nw){
        int img = t / NT, tt = t - img*NT;
        const unsigned short* inb = in + (size_t)img * INS;
        unsigned short* outb = out + (size_t)img * OUTS;
        int pos = tt*16 + nn;
        int pc  = pos < N ? pos : N - 1;
        int oy = pc / OL, ox = pc - oy*OL;
        const unsigned short* ib = inb + (oy*IL + ox)*32 + q*8;
        f32x4 acc0 = {0.f,0.f,0.f,0.f}, acc1 = {0.f,0.f,0.f,0.f};
#pragma unroll
        for (int r = 0; r < 3; r++){
            bf16x8 b0 = *(const bf16x8*)(ib + (r*IL + 0)*32);
            bf16x8 b1 = *(const bf16x8*)(ib + (r*IL + 1)*32);
            bf16x8 b2 = *(const bf16x8*)(ib + (r*IL + 2)*32);
            acc0 = __builtin_amdgcn_mfma_f32_16x16x32_bf16(af[0][r*3+0], b0, acc0, 0,0,0);
            acc1 = __builtin_amdgcn_mfma_f32_16x16x32_bf16(af[1][r*3+0], b0, acc1, 0,0,0);
            acc0 = __builtin_amdgcn_mfma_f32_16x16x32_bf16(af[0][r*3+1], b1, acc0, 0,0,0);
            acc1 = __builtin_amdgcn_mfma_f32_16x16x32_bf16(af[1][r*3+1], b1, acc1, 0,0,0);
            acc0 = __builtin_amdgcn_mfma_f32_16x16x32_bf16(af[0][r*3+2], b2, acc0, 0,0,0);
            acc1 = __builtin_amdgcn_mfma_f32_16x16x32_bf16(af[1][r*3+2], b2, acc1, 0,0,0);
        }
        if (pos < N){
            int opix = oy*OW + ox + OOFF;
            ushort4 o0, o1;
            o0.x = f2b(fast_tanh(acc0[0] + bc0.x)); o0.y = f2b(fast_tanh(acc0[1] + bc0.y));
            o0.z = f2b(fast_tanh(acc0[2] + bc0.z)); o0.w = f2b(fast_tanh(acc0[3] + bc0.w));
            o1.x = f2b(fast_tanh(acc1[0] + bc1.x)); o1.y = f2b(fast_tanh(acc1[1] + bc1.y));
            o1.z = f2b(fast_tanh(acc1[2] + bc1.z)); o1.w = f2b(fast_tanh(acc1[3] + bc1.w));
            *(ushort4*)(outb + opix*32 + q*4)      = o0;
            *(ushort4*)(outb + opix*32 + 16 + q*4) = o1;
        }
    }
}

// ===== encoder GEMM, K split across 4 blocks + 4 waves, atomic combine =====
__global__ void __launch_bounds__(256)
k_encg(const unsigned short* __restrict__ A2, const unsigned short* __restrict__ elwT,
       float* __restrict__ z1, int cb, int CH){
    int wave = threadIdx.x >> 6, lane = threadIdx.x & 63;
    int q = lane >> 4, nn = lane & 15;
    int imgb = blockIdx.x*16;
    const unsigned short* ap = A2 + (size_t)(imgb + nn)*15488 + q*8;
    const unsigned short* bp = elwT + (size_t)nn*15488 + q*8;
    f32x4 acc = {0.f,0.f,0.f,0.f};
    int s0 = blockIdx.y*121;
#pragma unroll 2
    for (int s = s0 + wave; s < s0 + 121; s += 4){
        bf16x8 a = *(const bf16x8*)(ap + s*32);
        bf16x8 b = *(const bf16x8*)(bp + s*32);
        acc = __builtin_amdgcn_mfma_f32_16x16x32_bf16(a, b, acc, 0,0,0);
    }
    float* zp = z1 + (size_t)(cb + imgb)*16;
#pragma unroll
    for (int i = 0; i < 4; i++)
        atomicAdd(zp + (q*4 + i)*16 + nn, acc[i]);
}

// ===== halo zero ===========================================================
__global__ void __launch_bounds__(256)
k_halo(unsigned short* __restrict__ D0, unsigned short* __restrict__ D1, int CH){
    int gid = blockIdx.x*256 + threadIdx.x;
    uint4 zq = {0,0,0,0};
    if (gid < CH*676){
        int img = gid / 676, px = gid - img*676;
        int y = px / 26, x = px - y*26;
        if (y < 2 || y >= 24 || x < 2 || x >= 24){
            uint4* p = (uint4*)(D0 + (size_t)img*21632 + px*32);
            p[0] = zq; p[1] = zq; p[2] = zq; p[3] = zq;
        }
    } else {
        int g2 = gid - CH*676;
        if (g2 >= CH*784) return;
        int img = g2 / 784, px = g2 - img*784;
        int y = px / 28, x = px - y*28;
        if (y < 2 || y >= 26 || x < 2 || x >= 26){
            uint4* p = (uint4*)(D1 + (size_t)img*25088 + px*32);
            p[0] = zq; p[1] = zq; p[2] = zq; p[3] = zq;
        }
    }
}

// ===== decoder GEMV ========================================================
__global__ void __launch_bounds__(256)
k_decg(const float* __restrict__ z1, const unsigned short* __restrict__ dlwT,
       const float* __restrict__ dlb, unsigned short* __restrict__ D0,
       int cb, int CH){
    __shared__ float zl[256];
    int tid = threadIdx.x, ib = blockIdx.y;
    zl[tid] = z1[(size_t)(cb + ib*16 + (tid >> 4))*16 + (tid & 15)];
    __syncthreads();
    int ci = tid & 31, po = tid >> 5;
    int pos = blockIdx.x*8 + po;
    if (pos >= 484) return;
    int y = pos / 22, xx = pos - y*22;
    float bias = dlb[ci*484 + pos];
    const unsigned short* w = dlwT + (size_t)(pos*32 + ci)*16;
    bf16x8 w0 = *(const bf16x8*)(w);
    bf16x8 w1 = *(const bf16x8*)(w + 8);
    float wf[16];
#pragma unroll
    for (int j = 0; j < 8; j++){
        wf[j]   = b2f((unsigned short)w0[j]);
        wf[8+j] = b2f((unsigned short)w1[j]);
    }
    int opix = ((y+2)*26 + xx + 2)*32 + ci;
#pragma unroll 1
    for (int i = 0; i < 16; i++){
        float a = bias;
#pragma unroll
        for (int l = 0; l < 16; l++) a += zl[i*16 + l] * wf[l];
        D0[(size_t)(ib*16 + i)*21632 + opix] = f2b(fast_tanh(a));
    }
}

// ===== convT2: 32->1 =======================================================
__global__ void __launch_bounds__(256)
k_convT2(const unsigned short* __restrict__ D2, const float* __restrict__ t2w,
         const float* __restrict__ t2b, float* __restrict__ out, int cb, int CH){
    int gid = blockIdx.x*256 + threadIdx.x;
    if (gid >= CH*784) return;
    int b = gid / 784, o = gid - b*784;
    int y = o / 28, xx = o - y*28;
    const unsigned short* db = D2 + (size_t)b*21632;
    float a = t2b[0];
#pragma unroll
    for (int r = 0; r < 3; r++){
        int iy = y + r - 2;
        if ((unsigned)iy >= 26u) continue;
#pragma unroll
        for (int s = 0; s < 3; s++){
            int ix = xx + s - 2;
            if ((unsigned)ix >= 26u) continue;
            const unsigned short* pp = db + (iy*26 + ix)*32;
            int wi = (2-r)*3 + (2-s);
#pragma unroll
            for (int g = 0; g < 4; g++){
                bf16x8 h = *(const bf16x8*)(pp + g*8);
#pragma unroll
                for (int j = 0; j < 8; j++)
                    a += b2f((unsigned short)h[j]) * t2w[(g*8+j)*9 + wi];
            }
        }
    }
    out[(size_t)(cb + b)*784 + o] = a;
}

// ===== FUSED FALLBACK (round-3, proven) ====================================
template<int LOUT, int INW, int OUTW, int OUTOFF>
__device__ __forceinline__ void conv_gemm(const unsigned short* __restrict__ Wg,
                                          const float* __restrict__ bias,
                                          const unsigned short* inL,
                                          unsigned short* outL, int tid){
    constexpr int N  = LOUT * LOUT;
    constexpr int NT = (N + 15) / 16;
    const int lane  = tid & 63;
    const int wave  = tid >> 6;
    const int mtile = wave & 1;
    const int quad  = lane >> 4;
    const int nn    = lane & 15;
    bf16x8 afr[9];
    const unsigned short* wp = Wg + (mtile*16 + nn)*32 + quad*8;
#pragma unroll
    for (int s = 0; s < 9; s++)
        afr[s] = *(const bf16x8*)(wp + s*1024);
    float4 bco = *(const float4*)(bias + mtile*16 + quad*4);
    for (int t = (wave >> 1); t < NT; t += 2){
        int pos = t*16 + nn;
        int pc  = pos < N ? pos : N - 1;
        int y = pc / LOUT, x = pc - y*LOUT;
        const unsigned short* ib = inL + (y*INW + x)*32 + quad*8;
        f32x4 acc = {0.f, 0.f, 0.f, 0.f};
#pragma unroll
        for (int r = 0; r < 3; r++)
#pragma unroll
            for (int s = 0; s < 3; s++)
                acc = __builtin_amdgcn_mfma_f32_16x16x32_bf16(
                        afr[r*3+s], *(const bf16x8*)(ib + (r*INW + s)*32), acc, 0, 0, 0);
        if (pos < N){
            ushort4 o;
            o.x = f2b(fast_tanh(acc[0] + bco.x));
            o.y = f2b(fast_tanh(acc[1] + bco.y));
            o.z = f2b(fast_tanh(acc[2] + bco.z));
            o.w = f2b(fast_tanh(acc[3] + bco.w));
            int opix = y*OUTW + x + OUTOFF;
            *(ushort4*)(outL + opix*32 + mtile*16 + quad*4) = o;
        }
    }
}

__global__ void __launch_bounds__(256)
k_enc_f(const float* __restrict__ x,
        const float* __restrict__ c0w, const float* __restrict__ c0b,
        const unsigned short* __restrict__ wc1, const float* __restrict__ c1b,
        const unsigned short* __restrict__ wc2, const float* __restrict__ c2b,
        const float* __restrict__ elw, const float* __restrict__ elb,
        float* __restrict__ z1){
    __shared__ float X[784];
    __shared__ __align__(16) unsigned short H0[21632];
    __shared__ __align__(16) unsigned short H1[18432];
    __shared__ __align__(16) unsigned short H2[15488];
    __shared__ float red[16*17];
    const int tid = threadIdx.x, b = blockIdx.x;
    for (int i = tid; i < 784; i += 256) X[i] = x[b*784 + i];
    __syncthreads();
    for (int pos = tid; pos < 676; pos += 256){
        int y = pos / 26, xx = pos - y*26;
        float v[9];
#pragma unroll
        for (int r = 0; r < 3; r++)
#pragma unroll
            for (int s = 0; s < 3; s++)
                v[r*3+s] = X[(y+r)*28 + xx + s];
#pragma unroll
        for (int g = 0; g < 8; g++){
            float a0 = c0b[g*4+0], a1 = c0b[g*4+1], a2 = c0b[g*4+2], a3 = c0b[g*4+3];
#pragma unroll
            for (int k = 0; k < 9; k++){
                a0 += v[k] * c0w[(g*4+0)*9 + k];
                a1 += v[k] * c0w[(g*4+1)*9 + k];
                a2 += v[k] * c0w[(g*4+2)*9 + k];
                a3 += v[k] * c0w[(g*4+3)*9 + k];
            }
            ushort4 o;
            o.x = f2b(fast_tanh(a0)); o.y = f2b(fast_tanh(a1));
            o.z = f2b(fast_tanh(a2)); o.w = f2b(fast_tanh(a3));
            *(ushort4*)(H0 + pos*32 + g*4) = o;
        }
    }
    __syncthreads();
    conv_gemm<24, 26, 24, 0>(wc1, c1b, H0, H1, tid);
    __syncthreads();
    conv_gemm<22, 24, 22, 0>(wc2, c2b, H1, H2, tid);
    __syncthreads();
    {
        int fg = tid >> 4, l = tid & 15;
        float a = 0.f;
        for (int ci = 0; ci < 32; ci++)
            for (int pos = fg; pos < 484; pos += 16)
                a += b2f(H2[pos*32 + ci]) * elw[(ci*484 + pos)*16 + l];
        red[fg*17 + l] = a;
        __syncthreads();
        if (tid < 16){
            float s = elb[tid];
#pragma unroll
            for (int g = 0; g < 16; g++) s += red[g*17 + tid];
            z1[b*16 + tid] = s;
        }
    }
}

__global__ void __launch_bounds__(256)
k_dec_f(const float* __restrict__ z1,
        const float* __restrict__ dlw, const float* __restrict__ dlb,
        const unsigned short* __restrict__ wt0, const float* __restrict__ t0b,
        const unsigned short* __restrict__ wt1, const float* __restrict__ t1b,
        const float* __restrict__ t2w, const float* __restrict__ t2b,
        float* __restrict__ out){
    __shared__ __align__(16) unsigned short D0[21632];
    __shared__ __align__(16) unsigned short D1[25088];
    __shared__ __align__(16) unsigned short D2[28800];
    const int tid = threadIdx.x, b = blockIdx.x;
    {
        uint4 zq = {0,0,0,0};
        for (int i = tid; i < 2704; i += 256) ((uint4*)D0)[i] = zq;
        for (int i = tid; i < 3136; i += 256) ((uint4*)D1)[i] = zq;
        for (int i = tid; i < 3600; i += 256) ((uint4*)D2)[i] = zq;
    }
    float zz[16];
#pragma unroll
    for (int l = 0; l < 16; l++) zz[l] = z1[b*16 + l];
    __syncthreads();
    for (int f = tid; f < 15488; f += 256){
        float a = dlb[f];
#pragma unroll
        for (int l = 0; l < 16; l++) a += zz[l] * dlw[l*15488 + f];
        int ci = f / 484, pos = f - ci*484;
        int y = pos / 22, xx = pos - y*22;
        D0[((y+2)*26 + xx + 2)*32 + ci] = f2b(fast_tanh(a));
    }
    __syncthreads();
    conv_gemm<24, 26, 28, 58>(wt0, t0b, D0, D1, tid);
    __syncthreads();
    conv_gemm<26, 28, 30, 62>(wt1, t1b, D1, D2, tid);
    __syncthreads();
    for (int o = tid; o < 784; o += 256){
        int y = o / 28, xx = o - y*28;
        float a = t2b[0];
#pragma unroll
        for (int r = 0; r < 3; r++)
#pragma unroll
            for (int s = 0; s < 3; s++){
                const unsigned short* pp = D2 + ((y+r)*30 + xx + s)*32;
                int wi = (2-r)*3 + (2-s);
#pragma unroll
                for (int g = 0; g < 4; g++){
                    bf16x8 h = *(const bf16x8*)(pp + g*8);
#pragma unroll
                    for (int j = 0; j < 8; j++)
                        a += b2f((unsigned short)h[j]) * t2w[(g*8+j)*9 + wi];
                }
            }
        out[(size_t)b*784 + o] = a;
    }
}

// ===== hypernetwork, parallel 3-kernel path ================================
__global__ void __launch_bounds__(64)
k_hyp1(const float* __restrict__ h1w, const float* __restrict__ h1b,
       const float* __restrict__ h2w, const float* __restrict__ h2b,
       float* __restrict__ p2ws){
    __shared__ float p1l[64];
    int sidx = blockIdx.x, tid = threadIdx.x;
    float t = stage_t(sidx);
    p1l[tid] = fast_tanh(t * h1w[tid] + h1b[tid]);
    __syncthreads();
    float a0 = h2b[tid], a1 = 0.f, a2 = 0.f, a3 = 0.f;
#pragma unroll
    for (int k = 0; k < 64; k += 4){
        a0 += p1l[k]   * h2w[(k)*64   + tid];
        a1 += p1l[k+1] * h2w[(k+1)*64 + tid];
        a2 += p1l[k+2] * h2w[(k+2)*64 + tid];
        a3 += p1l[k+3] * h2w[(k+3)*64 + tid];
    }
    p2ws[sidx*64 + tid] = fast_tanh((a0 + a1) + (a2 + a3));
}

__global__ void __launch_bounds__(256)
k_hyp2(const float* __restrict__ p2ws, const float* __restrict__ h3w,
       const float* __restrict__ h3b, float* __restrict__ p3ws){
    __shared__ float p2l[64];
    int sidx = blockIdx.y, tid = threadIdx.x;
    if (tid < 64) p2l[tid] = p2ws[sidx*64 + tid];
    __syncthreads();
    int m = blockIdx.x*256 + tid;
    if (m >= 3136) return;
    const float* hp = h3w + m;
    float a0 = h3b[m], a1 = 0.f, a2 = 0.f, a3 = 0.f;
#pragma unroll
    for (int k = 0; k < 64; k += 4){
        a0 += p2l[k]   * hp[(size_t)(k)*3136];
        a1 += p2l[k+1] * hp[(size_t)(k+1)*3136];
        a2 += p2l[k+2] * hp[(size_t)(k+2)*3136];
        a3 += p2l[k+3] * hp[(size_t)(k+3)*3136];
    }
    p3ws[(size_t)sidx*3200 + m] = (a0 + a1) + (a2 + a3);
}

__global__ void __launch_bounds__(256)
k_hyp3(const float* __restrict__ p3ws, float* __restrict__ hyp){
    __shared__ float partial[256];
    int sidx = blockIdx.x, tid = threadIdx.x;
    const float* p3 = p3ws + (size_t)sidx*3200;
    float* g = hyp + (size_t)sidx*2304;
    int m0 = tid*4;
    float4 w4 = *(const float4*)(p3 + m0);
    float4 a4 = *(const float4*)(p3 + 1024 + m0);
    float4 s4 = *(const float4*)(p3 + 2048 + m0);
    float4 u4;
    u4.x = a4.x * fast_sigmoid(s4.x);
    u4.y = a4.y * fast_sigmoid(s4.y);
    u4.z = a4.z * fast_sigmoid(s4.z);
    u4.w = a4.w * fast_sigmoid(s4.w);
    *(float4*)(g + m0) = w4;                            // W
    g[1024 + ((m0+0) & 15)*64 + ((m0+0) >> 4)] = u4.x;  // Ut scatter
    g[1024 + ((m0+1) & 15)*64 + ((m0+1) >> 4)] = u4.y;
    g[1024 + ((m0+2) & 15)*64 + ((m0+2) >> 4)] = u4.z;
    g[1024 + ((m0+3) & 15)*64 + ((m0+3) >> 4)] = u4.w;
    partial[tid] = w4.x*u4.x + w4.y*u4.y + w4.z*u4.z + w4.w*u4.w;
    __syncthreads();
    if (tid < 64){
        g[2048 + tid] = p3[3072 + tid];                 // Bb
        g[2112 + tid] = partial[tid*4] + partial[tid*4+1]
                      + partial[tid*4+2] + partial[tid*4+3];  // strace
    }
}

// ===== single-block hyper (fallback only) ==================================
__global__ void k_hyper(const float* __restrict__ h1w, const float* __restrict__ h1b,
                        const float* __restrict__ h2w, const float* __restrict__ h2b,
                        const float* __restrict__ h3w, const float* __restrict__ h3b,
                        float* __restrict__ hyp){
    int sidx = blockIdx.x;
    float t = stage_t(sidx);
    __shared__ float p1[64], p2[64];
    __shared__ float p3[3136];
    int tid = threadIdx.x;
    if (tid < 64) p1[tid] = fast_tanh(t * h1w[tid] + h1b[tid]);
    __syncthreads();
    if (tid < 64){
        float a = h2b[tid];
#pragma unroll
        for (int k = 0; k < 64; k++) a += p1[k] * h2w[k*64 + tid];
        p2[tid] = fast_tanh(a);
    }
    __syncthreads();
    for (int m = tid; m < 3136; m += 256){
        float a = h3b[m];
#pragma unroll
        for (int k = 0; k < 64; k++) a += p2[k] * h3w[k*3136 + m];
        p3[m] = a;
    }
    __syncthreads();
    float* g = hyp + (size_t)sidx * 2304;
    for (int m = tid; m < 1024; m += 256){
        g[m] = p3[m];
        float u = p3[1024 + m] * fast_sigmoid(p3[2048 + m]);
        g[1024 + (m & 15)*64 + (m >> 4)] = u;
        p3[1024 + m] = u;
    }
    if (tid < 64) g[2048 + tid] = p3[3072 + tid];
    __syncthreads();
    if (tid < 64){
        float s = 0.f;
#pragma unroll
        for (int d = 0; d < 16; d++) s += p3[tid*16 + d] * p3[1024 + tid*16 + d];
        g[2112 + tid] = s;
    }
}

// ===== CNF RK4: 1 batch row per wave, 2048 single-wave blocks ==============
// lane roles: phase1 lane=w (0..63); phase2 lane=(q,d), q=lane>>4, d=lane&15
struct PF { float4 Wr[4]; float4 Ur[4]; float Bb, sw; };

__device__ __forceinline__ void load_pf(const float* __restrict__ g,
                                        int lane, int q, int d, PF& p){
    const float4* w4 = (const float4*)(g + lane*16);
    p.Wr[0] = w4[0]; p.Wr[1] = w4[1]; p.Wr[2] = w4[2]; p.Wr[3] = w4[3];
    const float4* u4 = (const float4*)(g + 1024 + d*64 + q*16);
    p.Ur[0] = u4[0]; p.Ur[1] = u4[1]; p.Ur[2] = u4[2]; p.Ur[3] = u4[3];
    p.Bb = g[2048 + lane];
    p.sw = g[2112 + lane];
}

__global__ void __launch_bounds__(64)
k_cnf(const float* __restrict__ z1, const float* __restrict__ hyp,
      float* __restrict__ part){
    __shared__ __align__(16) float zsl[16];
    __shared__ __align__(16) float hhl[64];
    const int lane = threadIdx.x;
    const int q = lane >> 4, d = lane & 15;
    const float dt = -0.5f;

    float z  = z1[(size_t)blockIdx.x*16 + d];   // replicated across q
    float zs = z;
    float lp = 0.f, zacc = 0.f, lacc = 0.f;
    if (lane < 16) zsl[lane] = zs;

    PF cur, nxt;
    load_pf(hyp, lane, q, d, cur);

    for (int sidx = 0; sidx < 80; sidx++){
        __syncthreads();                         // zsl ready
        if (sidx < 79) load_pf(hyp + (size_t)(sidx + 1)*2304, lane, q, d, nxt);

        // phase1: lane = w
        const float4* zp = (const float4*)zsl;
        float4 z0 = zp[0], z1v = zp[1], z2 = zp[2], z3 = zp[3];
        float a = cur.Bb;
        a += z0.x*cur.Wr[0].x + z0.y*cur.Wr[0].y + z0.z*cur.Wr[0].z + z0.w*cur.Wr[0].w;
        a += z1v.x*cur.Wr[1].x + z1v.y*cur.Wr[1].y + z1v.z*cur.Wr[1].z + z1v.w*cur.Wr[1].w;
        a += z2.x*cur.Wr[2].x + z2.y*cur.Wr[2].y + z2.z*cur.Wr[2].z + z2.w*cur.Wr[2].w;
        a += z3.x*cur.Wr[3].x + z3.y*cur.Wr[3].y + z3.z*cur.Wr[3].z + z3.w*cur.Wr[3].w;
        float hh = fast_tanh(a);
        float e = (1.f - hh*hh) * cur.sw;
#pragma unroll
        for (int off = 1; off < 64; off <<= 1)   // tr = sum_w e_w, replicated
            e += __shfl_xor(e, off);
        hhl[lane] = hh;
        __syncthreads();                         // hhl ready

        // phase2: lane = (q,d); quarter-dot over w-chunk q, reduce over q
        const float4* hp = (const float4*)(hhl + q*16);
        float4 h0 = hp[0], h1 = hp[1], h2 = hp[2], h3 = hp[3];
        float dzp = 0.f;
        dzp += h0.x*cur.Ur[0].x + h0.y*cur.Ur[0].y + h0.z*cur.Ur[0].z + h0.w*cur.Ur[0].w;
        dzp += h1.x*cur.Ur[1].x + h1.y*cur.Ur[1].y + h1.z*cur.Ur[1].z + h1.w*cur.Ur[1].w;
        dzp += h2.x*cur.Ur[2].x + h2.y*cur.Ur[2].y + h2.z*cur.Ur[2].z + h2.w*cur.Ur[2].w;
        dzp += h3.x*cur.Ur[3].x + h3.y*cur.Ur[3].y + h3.z*cur.Ur[3].z + h3.w*cur.Ur[3].w;
        dzp += __shfl_xor(dzp, 16);
        dzp += __shfl_xor(dzp, 32);
        float dz = dzp * (1.f/64.f);
        float dl = -e  * (1.f/64.f);

        int st = sidx & 3;
        float wgt = (st == 0 || st == 3) ? 1.f : 2.f;
        zacc += wgt * dz;
        lacc += wgt * dl;
        if (st < 3){
            float aa = (st == 2) ? 1.0f : 0.5f;
            zs = z + aa * dt * dz;
        } else {
            z  += (dt/6.f) * zacc;
            lp += (dt/6.f) * lacc;
            zs = z;
            zacc = 0.f; lacc = 0.f;
        }
        if (lane < 16) zsl[lane] = zs;           // safe: same wave, program order
        cur = nxt;
    }

    float sq = z * z;
#pragma unroll
    for (int off = 1; off < 16; off <<= 1) sq += __shfl_xor(sq, off, 16);
    float logp = -0.5f * (16.f*1.8378770664093453f + 16.f*(-2.302585092994046f) + sq*10.f);
    if (lane == 0) part[blockIdx.x] = logp - lp;
}

__global__ void k_final(const float* __restrict__ part, float* __restrict__ out){
    __shared__ float red[256];
    int tid = threadIdx.x;
    float s = 0.f;
#pragma unroll
    for (int k = 0; k < 8; k++) s += part[tid + k*256];
    red[tid] = s;
    __syncthreads();
    for (int st = 128; st > 0; st >>= 1){
        if (tid < st) red[tid] += red[tid + st];
        __syncthreads();
    }
    if (tid == 0) out[1605632] = red[0] * (1.f/2048.f);
}

extern "C" void kernel_launch(void* const* d_in, const int* in_sizes, int n_in,
                              void* d_out, int out_size, void* d_ws, size_t ws_size,
                              hipStream_t stream){
    const float* x   = (const float*)d_in[0];
    const float* c0w = (const float*)d_in[1];
    const float* c0b = (const float*)d_in[2];
    const float* c1w = (const float*)d_in[3];
    const float* c1b = (const float*)d_in[4];
    const float* c2w = (const float*)d_in[5];
    const float* c2b = (const float*)d_in[6];
    const float* elw = (const float*)d_in[7];
    const float* elb = (const float*)d_in[8];
    const float* dlw = (const float*)d_in[9];
    const float* dlb = (const float*)d_in[10];
    const float* t0w = (const float*)d_in[11];
    const float* t0b = (const float*)d_in[12];
    const float* t1w = (const float*)d_in[13];
    const float* t1b = (const float*)d_in[14];
    const float* t2w = (const float*)d_in[15];
    const float* t2b = (const float*)d_in[16];
    const float* h1w = (const float*)d_in[17];
    const float* h1b = (const float*)d_in[18];
    const float* h2w = (const float*)d_in[19];
    const float* h2b = (const float*)d_in[20];
    const float* h3w = (const float*)d_in[21];
    const float* h3b = (const float*)d_in[22];

    float* ws   = (float*)d_ws;
    float* z1   = ws;                          // 32768 f
    float* hyp  = z1 + 32768;                  // 184320 f (80*2304)
    float* part = hyp + 184320;                // 2048 f
    float* p2ws = part + 2048;                 // 5120 f
    float* p3ws = p2ws + 5120;                 // 256000 f (80*3200)
    unsigned short* wc1  = (unsigned short*)(p3ws + 256000);  // 9216 each
    unsigned short* wc2  = wc1 + 9216;
    unsigned short* wt0  = wc2 + 9216;
    unsigned short* wt1  = wt0 + 9216;
    unsigned short* elwT = wt1 + 9216;         // 247808
    unsigned short* dlwT = elwT + 247808;      // 247808
    unsigned short* act  = dlwT + 247808;      // byte offset 2,985,984 (16B aligned)
    float* rec  = (float*)d_out;

    const size_t MISC = 2985984;
    int CH = 0;
    const int cands[6] = {2048, 1024, 512, 256, 128, 64};
    for (int c = 0; c < 6; c++){
        size_t need = MISC + (size_t)cands[c] * 111104;
        if (need <= ws_size){ CH = cands[c]; break; }
    }

    if (CH == 0){
        // tiny-ws fallback
        k_hyper<<<80, 256, 0, stream>>>(h1w, h1b, h2w, h2b, h3w, h3b, hyp);
        k_prep <<<64,   256, 0, stream>>>(c1w, c2w, t0w, t1w, elw, dlw, elb,
                                          wc1, wc2, wt0, wt1, wt1, wt1, z1, 0);
        k_enc_f<<<2048, 256, 0, stream>>>(x, c0w, c0b, wc1, c1b, wc2, c2b, elw, elb, z1);
        k_cnf  <<<2048,  64, 0, stream>>>(z1, hyp, part);
        k_dec_f<<<2048, 256, 0, stream>>>(z1, dlw, dlb, wt0, t0b, wt1, t1b, t2w, t2b, rec);
        k_final<<<1,    256, 0, stream>>>(part, rec);
        return;
    }

    k_hyp1<<<80,           64, 0, stream>>>(h1w, h1b, h2w, h2b, p2ws);
    k_hyp2<<<dim3(13,80), 256, 0, stream>>>(p2ws, h3w, h3b, p3ws);
    k_hyp3<<<80,          256, 0, stream>>>(p3ws, hyp);

    k_prep<<<64, 256, 0, stream>>>(c1w, c2w, t0w, t1w, elw, dlw, elb,
                                   wc1, wc2, wt0, wt1, elwT, dlwT, z1, 1);

    unsigned short* R0 = act;                          // A0 / D0 / D2 : CH*21632
    unsigned short* R1 = R0 + (size_t)CH*21632;        // A1 ; D1 head : CH*18432
    unsigned short* R2 = R1 + (size_t)CH*18432;        // A2 ; D1 tail : CH*15488
    unsigned short* D1 = R1;                           // CH*25088 <= CH*33920

    for (int cb = 0; cb < Bsz; cb += CH){
        k_conv0<<<(CH*676 + 255)/256, 256, 0, stream>>>(x, c0w, c0b, R0, cb, CH);
        k_convM<26,24,24, 0, 21632, 18432><<<(CH*36 + 15)/16, 256, 0, stream>>>(R0, wc1, c1b, R1, CH);
        k_convM<24,22,22, 0, 18432, 15488><<<(CH*31 + 15)/16, 256, 0, stream>>>(R1, wc2, c2b, R2, CH);
        k_encg<<<dim3(CH/16, 4), 256, 0, stream>>>(R2, elwT, z1, cb, CH);
        k_halo<<<(CH*1460 + 255)/256, 256, 0, stream>>>(R0, D1, CH);
        k_decg<<<dim3(61, CH/16), 256, 0, stream>>>(z1, dlwT, dlb, R0, cb, CH);
        k_convM<26,24,28,58, 21632, 25088><<<(CH*36 + 15)/16, 256, 0, stream>>>(R0, wt0, t0b, D1, CH);
        k_convM<28,26,26, 0, 25088, 21632><<<(CH*43 + 15)/16, 256, 0, stream>>>(D1, wt1, t1b, R0, CH);
        k_convT2<<<(CH*784 + 255)/256, 256, 0, stream>>>(R0, t2w, t2b, rec, cb, CH);
    }
    k_cnf  <<<2048,  64, 0, stream>>>(z1, hyp, part);
    k_final<<<1,    256, 0, stream>>>(part, rec);
}

// Round 8
// 652.184 us; speedup vs baseline: 9.1358x; 1.0160x over previous
//
#include <hip/hip_runtime.h>
#include <math.h>

#define Bsz 2048

using bf16x8 = __attribute__((ext_vector_type(8))) short;
using f32x4  = __attribute__((ext_vector_type(4))) float;

__device__ __forceinline__ float fast_tanh(float x){
    float e = __expf(2.0f * x);
    return 1.0f - 2.0f / (e + 1.0f);
}
__device__ __forceinline__ float fast_sigmoid(float x){
    return 1.0f / (1.0f + __expf(-x));
}
__device__ __forceinline__ unsigned short f2b(float f){
    union { float f; unsigned u; } v; v.f = f;
    unsigned r = v.u + 0x7FFFu + ((v.u >> 16) & 1u);
    return (unsigned short)(r >> 16);
}
__device__ __forceinline__ float b2f(unsigned short s){
    union { unsigned u; float f; } v; v.u = ((unsigned)s) << 16;
    return v.f;
}

__device__ __forceinline__ float stage_t(int sidx){
    int i  = sidx >> 2, st = sidx & 3;
    float t = 10.0f - 0.5f * (float)i;
    if (st == 1 || st == 2) t -= 0.25f;
    else if (st == 3)       t -= 0.5f;
    return t;
}

// ===== weight prep (+ z1 bias init for atomic encoder) ======================
__global__ void k_prep(const float* __restrict__ c1w, const float* __restrict__ c2w,
                       const float* __restrict__ t0w, const float* __restrict__ t1w,
                       const float* __restrict__ elw, const float* __restrict__ dlw,
                       const float* __restrict__ elb,
                       unsigned short* __restrict__ wc1, unsigned short* __restrict__ wc2,
                       unsigned short* __restrict__ wt0, unsigned short* __restrict__ wt1,
                       unsigned short* __restrict__ elwT, unsigned short* __restrict__ dlwT,
                       float* __restrict__ z1, int full){
    int gsz = gridDim.x * 256;
    for (int i = blockIdx.x*256 + threadIdx.x; i < 9216; i += gsz){
        int ci = i & 31, co = (i >> 5) & 31, s = i >> 10;
        wc1[i] = f2b(c1w[(co*32 + ci)*9 + s]);
        wc2[i] = f2b(c2w[(co*32 + ci)*9 + s]);
        wt0[i] = f2b(t0w[(ci*32 + co)*9 + (8 - s)]);
        wt1[i] = f2b(t1w[(ci*32 + co)*9 + (8 - s)]);
    }
    if (!full) return;
    for (int i = blockIdx.x*256 + threadIdx.x; i < 32768; i += gsz)
        z1[i] = elb[i & 15];
    for (int i = blockIdx.x*256 + threadIdx.x; i < 247808; i += gsz){
        int l = i / 15488, f2 = i - l*15488;
        int pos = f2 >> 5, ci = f2 & 31;
        elwT[i] = f2b(elw[(ci*484 + pos)*16 + l]);
    }
    for (int i = blockIdx.x*256 + threadIdx.x; i < 247808; i += gsz){
        int f2 = i >> 4, l = i & 15;
        int pos = f2 >> 5, ci = f2 & 31;
        dlwT[i] = f2b(dlw[l*15488 + ci*484 + pos]);
    }
}

// ===== conv0: 1->32, VALU ==================================================
__global__ void __launch_bounds__(256)
k_conv0(const float* __restrict__ x, const float* __restrict__ c0w,
        const float* __restrict__ c0b, unsigned short* __restrict__ A0,
        int cb, int CH){
    int gid = blockIdx.x*256 + threadIdx.x;
    if (gid >= CH*676) return;
    int b = gid / 676, pos = gid - b*676;
    int y = pos / 26, xx = pos - y*26;
    const float* xin = x + (size_t)(cb + b)*784;
    float v[9];
#pragma unroll
    for (int r = 0; r < 3; r++)
#pragma unroll
        for (int s = 0; s < 3; s++)
            v[r*3+s] = xin[(y+r)*28 + xx + s];
    unsigned short* ob = A0 + (size_t)b*21632 + pos*32;
#pragma unroll
    for (int g = 0; g < 8; g++){
        float a0 = c0b[g*4+0], a1 = c0b[g*4+1], a2 = c0b[g*4+2], a3 = c0b[g*4+3];
#pragma unroll
        for (int k = 0; k < 9; k++){
            a0 += v[k] * c0w[(g*4+0)*9 + k];
            a1 += v[k] * c0w[(g*4+1)*9 + k];
            a2 += v[k] * c0w[(g*4+2)*9 + k];
            a3 += v[k] * c0w[(g*4+3)*9 + k];
        }
        ushort4 o;
        o.x = f2b(fast_tanh(a0)); o.y = f2b(fast_tanh(a1));
        o.z = f2b(fast_tanh(a2)); o.w = f2b(fast_tanh(a3));
        *(ushort4*)(ob + g*4) = o;
    }
}

// ===== MFMA conv layer, tile-parallel across all images ====================
template<int IL, int OL, int OW, int OOFF, int INS, int OUTS>
__global__ void __launch_bounds__(256)
k_convM(const unsigned short* __restrict__ in, const unsigned short* __restrict__ wg,
        const float* __restrict__ bias, unsigned short* __restrict__ out, int CH){
    constexpr int N  = OL * OL;
    constexpr int NT = (N + 15) / 16;
    const int tid = threadIdx.x;
    const int wave = tid >> 6, lane = tid & 63;
    const int q = lane >> 4, nn = lane & 15;
    const int nw = gridDim.x * 4;

    bf16x8 af[2][9];
#pragma unroll
    for (int mt = 0; mt < 2; mt++)
#pragma unroll
        for (int s = 0; s < 9; s++)
            af[mt][s] = *(const bf16x8*)(wg + s*1024 + (mt*16 + nn)*32 + q*8);
    float4 bc0 = *(const float4*)(bias + q*4);
    float4 bc1 = *(const float4*)(bias + 16 + q*4);

    for (int t = blockIdx.x*4 + wave; t < CH*NT; t += nw){
        int img = t / NT, tt = t - img*NT;
        const unsigned short* inb = in + (size_t)img * INS;
        unsigned short* outb = out + (size_t)img * OUTS;
        int pos = tt*16 + nn;
        int pc  = pos < N ? pos : N - 1;
        int oy = pc / OL, ox = pc - oy*OL;
        const unsigned short* ib = inb + (oy*IL + ox)*32 + q*8;
        f32x4 acc0 = {0.f,0.f,0.f,0.f}, acc1 = {0.f,0.f,0.f,0.f};
#pragma unroll
        for (int r = 0; r < 3; r++){
            bf16x8 b0 = *(const bf16x8*)(ib + (r*IL + 0)*32);
            bf16x8 b1 = *(const bf16x8*)(ib + (r*IL + 1)*32);
            bf16x8 b2 = *(const bf16x8*)(ib + (r*IL + 2)*32);
            acc0 = __builtin_amdgcn_mfma_f32_16x16x32_bf16(af[0][r*3+0], b0, acc0, 0,0,0);
            acc1 = __builtin_amdgcn_mfma_f32_16x16x32_bf16(af[1][r*3+0], b0, acc1, 0,0,0);
            acc0 = __builtin_amdgcn_mfma_f32_16x16x32_bf16(af[0][r*3+1], b1, acc0, 0,0,0);
            acc1 = __builtin_amdgcn_mfma_f32_16x16x32_bf16(af[1][r*3+1], b1, acc1, 0,0,0);
            acc0 = __builtin_amdgcn_mfma_f32_16x16x32_bf16(af[0][r*3+2], b2, acc0, 0,0,0);
            acc1 = __builtin_amdgcn_mfma_f32_16x16x32_bf16(af[1][r*3+2], b2, acc1, 0,0,0);
        }
        if (pos < N){
            int opix = oy*OW + ox + OOFF;
            ushort4 o0, o1;
            o0.x = f2b(fast_tanh(acc0[0] + bc0.x)); o0.y = f2b(fast_tanh(acc0[1] + bc0.y));
            o0.z = f2b(fast_tanh(acc0[2] + bc0.z)); o0.w = f2b(fast_tanh(acc0[3] + bc0.w));
            o1.x = f2b(fast_tanh(acc1[0] + bc1.x)); o1.y = f2b(fast_tanh(acc1[1] + bc1.y));
            o1.z = f2b(fast_tanh(acc1[2] + bc1.z)); o1.w = f2b(fast_tanh(acc1[3] + bc1.w));
            *(ushort4*)(outb + opix*32 + q*4)      = o0;
            *(ushort4*)(outb + opix*32 + 16 + q*4) = o1;
        }
    }
}

// ===== encoder GEMM, K split across 4 blocks + 4 waves, atomic combine =====
__global__ void __launch_bounds__(256)
k_encg(const unsigned short* __restrict__ A2, const unsigned short* __restrict__ elwT,
       float* __restrict__ z1, int cb, int CH){
    int wave = threadIdx.x >> 6, lane = threadIdx.x & 63;
    int q = lane >> 4, nn = lane & 15;
    int imgb = blockIdx.x*16;
    const unsigned short* ap = A2 + (size_t)(imgb + nn)*15488 + q*8;
    const unsigned short* bp = elwT + (size_t)nn*15488 + q*8;
    f32x4 acc = {0.f,0.f,0.f,0.f};
    int s0 = blockIdx.y*121;
#pragma unroll 2
    for (int s = s0 + wave; s < s0 + 121; s += 4){
        bf16x8 a = *(const bf16x8*)(ap + s*32);
        bf16x8 b = *(const bf16x8*)(bp + s*32);
        acc = __builtin_amdgcn_mfma_f32_16x16x32_bf16(a, b, acc, 0,0,0);
    }
    float* zp = z1 + (size_t)(cb + imgb)*16;
#pragma unroll
    for (int i = 0; i < 4; i++)
        atomicAdd(zp + (q*4 + i)*16 + nn, acc[i]);
}

// ===== halo zero ===========================================================
__global__ void __launch_bounds__(256)
k_halo(unsigned short* __restrict__ D0, unsigned short* __restrict__ D1, int CH){
    int gid = blockIdx.x*256 + threadIdx.x;
    uint4 zq = {0,0,0,0};
    if (gid < CH*676){
        int img = gid / 676, px = gid - img*676;
        int y = px / 26, x = px - y*26;
        if (y < 2 || y >= 24 || x < 2 || x >= 24){
            uint4* p = (uint4*)(D0 + (size_t)img*21632 + px*32);
            p[0] = zq; p[1] = zq; p[2] = zq; p[3] = zq;
        }
    } else {
        int g2 = gid - CH*676;
        if (g2 >= CH*784) return;
        int img = g2 / 784, px = g2 - img*784;
        int y = px / 28, x = px - y*28;
        if (y < 2 || y >= 26 || x < 2 || x >= 26){
            uint4* p = (uint4*)(D1 + (size_t)img*25088 + px*32);
            p[0] = zq; p[1] = zq; p[2] = zq; p[3] = zq;
        }
    }
}

// ===== decoder GEMV ========================================================
__global__ void __launch_bounds__(256)
k_decg(const float* __restrict__ z1, const unsigned short* __restrict__ dlwT,
       const float* __restrict__ dlb, unsigned short* __restrict__ D0,
       int cb, int CH){
    __shared__ float zl[256];
    int tid = threadIdx.x, ib = blockIdx.y;
    zl[tid] = z1[(size_t)(cb + ib*16 + (tid >> 4))*16 + (tid & 15)];
    __syncthreads();
    int ci = tid & 31, po = tid >> 5;
    int pos = blockIdx.x*8 + po;
    if (pos >= 484) return;
    int y = pos / 22, xx = pos - y*22;
    float bias = dlb[ci*484 + pos];
    const unsigned short* w = dlwT + (size_t)(pos*32 + ci)*16;
    bf16x8 w0 = *(const bf16x8*)(w);
    bf16x8 w1 = *(const bf16x8*)(w + 8);
    float wf[16];
#pragma unroll
    for (int j = 0; j < 8; j++){
        wf[j]   = b2f((unsigned short)w0[j]);
        wf[8+j] = b2f((unsigned short)w1[j]);
    }
    int opix = ((y+2)*26 + xx + 2)*32 + ci;
#pragma unroll 1
    for (int i = 0; i < 16; i++){
        float a = bias;
#pragma unroll
        for (int l = 0; l < 16; l++) a += zl[i*16 + l] * wf[l];
        D0[(size_t)(ib*16 + i)*21632 + opix] = f2b(fast_tanh(a));
    }
}

// ===== convT2: 32->1 =======================================================
__global__ void __launch_bounds__(256)
k_convT2(const unsigned short* __restrict__ D2, const float* __restrict__ t2w,
         const float* __restrict__ t2b, float* __restrict__ out, int cb, int CH){
    int gid = blockIdx.x*256 + threadIdx.x;
    if (gid >= CH*784) return;
    int b = gid / 784, o = gid - b*784;
    int y = o / 28, xx = o - y*28;
    const unsigned short* db = D2 + (size_t)b*21632;
    float a = t2b[0];
#pragma unroll
    for (int r = 0; r < 3; r++){
        int iy = y + r - 2;
        if ((unsigned)iy >= 26u) continue;
#pragma unroll
        for (int s = 0; s < 3; s++){
            int ix = xx + s - 2;
            if ((unsigned)ix >= 26u) continue;
            const unsigned short* pp = db + (iy*26 + ix)*32;
            int wi = (2-r)*3 + (2-s);
#pragma unroll
            for (int g = 0; g < 4; g++){
                bf16x8 h = *(const bf16x8*)(pp + g*8);
#pragma unroll
                for (int j = 0; j < 8; j++)
                    a += b2f((unsigned short)h[j]) * t2w[(g*8+j)*9 + wi];
            }
        }
    }
    out[(size_t)(cb + b)*784 + o] = a;
}

// ===== FUSED FALLBACK (round-3, proven) ====================================
template<int LOUT, int INW, int OUTW, int OUTOFF>
__device__ __forceinline__ void conv_gemm(const unsigned short* __restrict__ Wg,
                                          const float* __restrict__ bias,
                                          const unsigned short* inL,
                                          unsigned short* outL, int tid){
    constexpr int N  = LOUT * LOUT;
    constexpr int NT = (N + 15) / 16;
    const int lane  = tid & 63;
    const int wave  = tid >> 6;
    const int mtile = wave & 1;
    const int quad  = lane >> 4;
    const int nn    = lane & 15;
    bf16x8 afr[9];
    const unsigned short* wp = Wg + (mtile*16 + nn)*32 + quad*8;
#pragma unroll
    for (int s = 0; s < 9; s++)
        afr[s] = *(const bf16x8*)(wp + s*1024);
    float4 bco = *(const float4*)(bias + mtile*16 + quad*4);
    for (int t = (wave >> 1); t < NT; t += 2){
        int pos = t*16 + nn;
        int pc  = pos < N ? pos : N - 1;
        int y = pc / LOUT, x = pc - y*LOUT;
        const unsigned short* ib = inL + (y*INW + x)*32 + quad*8;
        f32x4 acc = {0.f, 0.f, 0.f, 0.f};
#pragma unroll
        for (int r = 0; r < 3; r++)
#pragma unroll
            for (int s = 0; s < 3; s++)
                acc = __builtin_amdgcn_mfma_f32_16x16x32_bf16(
                        afr[r*3+s], *(const bf16x8*)(ib + (r*INW + s)*32), acc, 0, 0, 0);
        if (pos < N){
            ushort4 o;
            o.x = f2b(fast_tanh(acc[0] + bco.x));
            o.y = f2b(fast_tanh(acc[1] + bco.y));
            o.z = f2b(fast_tanh(acc[2] + bco.z));
            o.w = f2b(fast_tanh(acc[3] + bco.w));
            int opix = y*OUTW + x + OUTOFF;
            *(ushort4*)(outL + opix*32 + mtile*16 + quad*4) = o;
        }
    }
}

__global__ void __launch_bounds__(256)
k_enc_f(const float* __restrict__ x,
        const float* __restrict__ c0w, const float* __restrict__ c0b,
        const unsigned short* __restrict__ wc1, const float* __restrict__ c1b,
        const unsigned short* __restrict__ wc2, const float* __restrict__ c2b,
        const float* __restrict__ elw, const float* __restrict__ elb,
        float* __restrict__ z1){
    __shared__ float X[784];
    __shared__ __align__(16) unsigned short H0[21632];
    __shared__ __align__(16) unsigned short H1[18432];
    __shared__ __align__(16) unsigned short H2[15488];
    __shared__ float red[16*17];
    const int tid = threadIdx.x, b = blockIdx.x;
    for (int i = tid; i < 784; i += 256) X[i] = x[b*784 + i];
    __syncthreads();
    for (int pos = tid; pos < 676; pos += 256){
        int y = pos / 26, xx = pos - y*26;
        float v[9];
#pragma unroll
        for (int r = 0; r < 3; r++)
#pragma unroll
            for (int s = 0; s < 3; s++)
                v[r*3+s] = X[(y+r)*28 + xx + s];
#pragma unroll
        for (int g = 0; g < 8; g++){
            float a0 = c0b[g*4+0], a1 = c0b[g*4+1], a2 = c0b[g*4+2], a3 = c0b[g*4+3];
#pragma unroll
            for (int k = 0; k < 9; k++){
                a0 += v[k] * c0w[(g*4+0)*9 + k];
                a1 += v[k] * c0w[(g*4+1)*9 + k];
                a2 += v[k] * c0w[(g*4+2)*9 + k];
                a3 += v[k] * c0w[(g*4+3)*9 + k];
            }
            ushort4 o;
            o.x = f2b(fast_tanh(a0)); o.y = f2b(fast_tanh(a1));
            o.z = f2b(fast_tanh(a2)); o.w = f2b(fast_tanh(a3));
            *(ushort4*)(H0 + pos*32 + g*4) = o;
        }
    }
    __syncthreads();
    conv_gemm<24, 26, 24, 0>(wc1, c1b, H0, H1, tid);
    __syncthreads();
    conv_gemm<22, 24, 22, 0>(wc2, c2b, H1, H2, tid);
    __syncthreads();
    {
        int fg = tid >> 4, l = tid & 15;
        float a = 0.f;
        for (int ci = 0; ci < 32; ci++)
            for (int pos = fg; pos < 484; pos += 16)
                a += b2f(H2[pos*32 + ci]) * elw[(ci*484 + pos)*16 + l];
        red[fg*17 + l] = a;
        __syncthreads();
        if (tid < 16){
            float s = elb[tid];
#pragma unroll
            for (int g = 0; g < 16; g++) s += red[g*17 + tid];
            z1[b*16 + tid] = s;
        }
    }
}

__global__ void __launch_bounds__(256)
k_dec_f(const float* __restrict__ z1,
        const float* __restrict__ dlw, const float* __restrict__ dlb,
        const unsigned short* __restrict__ wt0, const float* __restrict__ t0b,
        const unsigned short* __restrict__ wt1, const float* __restrict__ t1b,
        const float* __restrict__ t2w, const float* __restrict__ t2b,
        float* __restrict__ out){
    __shared__ __align__(16) unsigned short D0[21632];
    __shared__ __align__(16) unsigned short D1[25088];
    __shared__ __align__(16) unsigned short D2[28800];
    const int tid = threadIdx.x, b = blockIdx.x;
    {
        uint4 zq = {0,0,0,0};
        for (int i = tid; i < 2704; i += 256) ((uint4*)D0)[i] = zq;
        for (int i = tid; i < 3136; i += 256) ((uint4*)D1)[i] = zq;
        for (int i = tid; i < 3600; i += 256) ((uint4*)D2)[i] = zq;
    }
    float zz[16];
#pragma unroll
    for (int l = 0; l < 16; l++) zz[l] = z1[b*16 + l];
    __syncthreads();
    for (int f = tid; f < 15488; f += 256){
        float a = dlb[f];
#pragma unroll
        for (int l = 0; l < 16; l++) a += zz[l] * dlw[l*15488 + f];
        int ci = f / 484, pos = f - ci*484;
        int y = pos / 22, xx = pos - y*22;
        D0[((y+2)*26 + xx + 2)*32 + ci] = f2b(fast_tanh(a));
    }
    __syncthreads();
    conv_gemm<24, 26, 28, 58>(wt0, t0b, D0, D1, tid);
    __syncthreads();
    conv_gemm<26, 28, 30, 62>(wt1, t1b, D1, D2, tid);
    __syncthreads();
    for (int o = tid; o < 784; o += 256){
        int y = o / 28, xx = o - y*28;
        float a = t2b[0];
#pragma unroll
        for (int r = 0; r < 3; r++)
#pragma unroll
            for (int s = 0; s < 3; s++){
                const unsigned short* pp = D2 + ((y+r)*30 + xx + s)*32;
                int wi = (2-r)*3 + (2-s);
#pragma unroll
                for (int g = 0; g < 4; g++){
                    bf16x8 h = *(const bf16x8*)(pp + g*8);
#pragma unroll
                    for (int j = 0; j < 8; j++)
                        a += b2f((unsigned short)h[j]) * t2w[(g*8+j)*9 + wi];
                }
            }
        out[(size_t)b*784 + o] = a;
    }
}

// ===== hypernetwork, parallel 3-kernel path ================================
__global__ void __launch_bounds__(64)
k_hyp1(const float* __restrict__ h1w, const float* __restrict__ h1b,
       const float* __restrict__ h2w, const float* __restrict__ h2b,
       float* __restrict__ p2ws){
    __shared__ float p1l[64];
    int sidx = blockIdx.x, tid = threadIdx.x;
    float t = stage_t(sidx);
    p1l[tid] = fast_tanh(t * h1w[tid] + h1b[tid]);
    __syncthreads();
    float a0 = h2b[tid], a1 = 0.f, a2 = 0.f, a3 = 0.f;
#pragma unroll
    for (int k = 0; k < 64; k += 4){
        a0 += p1l[k]   * h2w[(k)*64   + tid];
        a1 += p1l[k+1] * h2w[(k+1)*64 + tid];
        a2 += p1l[k+2] * h2w[(k+2)*64 + tid];
        a3 += p1l[k+3] * h2w[(k+3)*64 + tid];
    }
    p2ws[sidx*64 + tid] = fast_tanh((a0 + a1) + (a2 + a3));
}

__global__ void __launch_bounds__(256)
k_hyp2(const float* __restrict__ p2ws, const float* __restrict__ h3w,
       const float* __restrict__ h3b, float* __restrict__ p3ws){
    __shared__ float p2l[64];
    int sidx = blockIdx.y, tid = threadIdx.x;
    if (tid < 64) p2l[tid] = p2ws[sidx*64 + tid];
    __syncthreads();
    int m = blockIdx.x*256 + tid;
    if (m >= 3136) return;
    const float* hp = h3w + m;
    float a0 = h3b[m], a1 = 0.f, a2 = 0.f, a3 = 0.f;
#pragma unroll
    for (int k = 0; k < 64; k += 4){
        a0 += p2l[k]   * hp[(size_t)(k)*3136];
        a1 += p2l[k+1] * hp[(size_t)(k+1)*3136];
        a2 += p2l[k+2] * hp[(size_t)(k+2)*3136];
        a3 += p2l[k+3] * hp[(size_t)(k+3)*3136];
    }
    p3ws[(size_t)sidx*3200 + m] = (a0 + a1) + (a2 + a3);
}

// k_hyp3: emit per-lane pre-swizzled MFMA param fragments, stage stride 2048 f
// [0,1024)f  = Wpk bf16: entry (c*64+lane)*8 shorts; A1[m=lane&15][k=q*8+j],
//              W chunk c: value = (q<2) ? W[c*16+m][q*8+j] : 0
// [1024,1536)f = Upk bf16: entry (kb*64+lane)*8 shorts; B2[k=kb*32+q*8+j][n=lane&15]
// [1536,1600)f = Bb[64]; [1600,1664)f = s[64]; [1664]f = stot
__global__ void __launch_bounds__(256)
k_hyp3(const float* __restrict__ p3ws, float* __restrict__ hyp){
    __shared__ float sred[64];
    int sidx = blockIdx.x, tid = threadIdx.x;
    const float* p3 = p3ws + (size_t)sidx*3200;
    float* g = hyp + (size_t)sidx*2048;
    unsigned short* gW = (unsigned short*)g;
    unsigned short* gU = (unsigned short*)(g + 1024);

    {   // Wpk: tid = c*64 + lane
        int lane = tid & 63, c = tid >> 6;
        int q = lane >> 4, m = lane & 15;
        ushort4 o0 = {0,0,0,0}, o1 = {0,0,0,0};
        if (q < 2){
            const float* wp = p3 + (c*16 + m)*16 + q*8;
            o0.x = f2b(wp[0]); o0.y = f2b(wp[1]); o0.z = f2b(wp[2]); o0.w = f2b(wp[3]);
            o1.x = f2b(wp[4]); o1.y = f2b(wp[5]); o1.z = f2b(wp[6]); o1.w = f2b(wp[7]);
        }
        *(ushort4*)(gW + tid*8)     = o0;
        *(ushort4*)(gW + tid*8 + 4) = o1;
    }
    if (tid < 128){  // Upk: tid = kb*64 + lane
        int lane = tid & 63, kb = tid >> 6;
        int q = lane >> 4, d = lane & 15;
        unsigned short uo[8];
#pragma unroll
        for (int j = 0; j < 8; j++){
            int w = kb*32 + q*8 + j;
            float u = p3[1024 + w*16 + d] * fast_sigmoid(p3[2048 + w*16 + d]);
            uo[j] = f2b(u);
        }
        *(ushort4*)(gU + tid*8)     = *(ushort4*)&uo[0];
        *(ushort4*)(gU + tid*8 + 4) = *(ushort4*)&uo[4];
    } else if (tid < 192){  // Bb
        int w = tid - 128;
        g[1536 + w] = p3[3072 + w];
    } else {                // s[w]
        int w = tid - 192;
        float s = 0.f;
#pragma unroll
        for (int d = 0; d < 16; d++){
            float u = p3[1024 + w*16 + d] * fast_sigmoid(p3[2048 + w*16 + d]);
            s += p3[w*16 + d] * u;
        }
        g[1600 + w] = s;
        sred[w] = s;
    }
    __syncthreads();
    if (tid == 0){
        float st = 0.f;
#pragma unroll
        for (int w = 0; w < 64; w++) st += sred[w];
        g[1664] = st;
    }
}

// ===== single-block hyper (fallback only, OLD layout stride 2304) ==========
__global__ void k_hyper(const float* __restrict__ h1w, const float* __restrict__ h1b,
                        const float* __restrict__ h2w, const float* __restrict__ h2b,
                        const float* __restrict__ h3w, const float* __restrict__ h3b,
                        float* __restrict__ hyp){
    int sidx = blockIdx.x;
    float t = stage_t(sidx);
    __shared__ float p1[64], p2[64];
    __shared__ float p3[3136];
    int tid = threadIdx.x;
    if (tid < 64) p1[tid] = fast_tanh(t * h1w[tid] + h1b[tid]);
    __syncthreads();
    if (tid < 64){
        float a = h2b[tid];
#pragma unroll
        for (int k = 0; k < 64; k++) a += p1[k] * h2w[k*64 + tid];
        p2[tid] = fast_tanh(a);
    }
    __syncthreads();
    for (int m = tid; m < 3136; m += 256){
        float a = h3b[m];
#pragma unroll
        for (int k = 0; k < 64; k++) a += p2[k] * h3w[k*3136 + m];
        p3[m] = a;
    }
    __syncthreads();
    float* g = hyp + (size_t)sidx * 2304;
    for (int m = tid; m < 1024; m += 256){
        g[m] = p3[m];
        float u = p3[1024 + m] * fast_sigmoid(p3[2048 + m]);
        g[1024 + (m & 15)*64 + (m >> 4)] = u;
        p3[1024 + m] = u;
    }
    if (tid < 64) g[2048 + tid] = p3[3072 + tid];
    __syncthreads();
    if (tid < 64){
        float s = 0.f;
#pragma unroll
        for (int d = 0; d < 16; d++) s += p3[tid*16 + d] * p3[1024 + tid*16 + d];
        g[2112 + tid] = s;
    }
}

// ===== CNF RK4 (MFMA): 16 rows/wave, 128 single-wave blocks ================
struct PM {
    bf16x8 Wf[4];     // A1 frags, chunks of 16 w
    bf16x8 Uf[2];     // B2 frags, k-blocks of 32 w
    float4 Bbf[4];    // Bb[c*16+q*4 ..+3]
    float4 sf[4];     // s [c*16+q*4 ..+3]
    float stot;
};
__device__ __forceinline__ void loadPM(const float* __restrict__ g, int lane, int q, PM& p){
    const unsigned short* gW = (const unsigned short*)g;
    const unsigned short* gU = (const unsigned short*)(g + 1024);
#pragma unroll
    for (int c = 0; c < 4; c++)
        p.Wf[c] = *(const bf16x8*)(gW + (c*64 + lane)*8);
#pragma unroll
    for (int kb = 0; kb < 2; kb++)
        p.Uf[kb] = *(const bf16x8*)(gU + (kb*64 + lane)*8);
#pragma unroll
    for (int c = 0; c < 4; c++){
        p.Bbf[c] = *(const float4*)(g + 1536 + c*16 + q*4);
        p.sf[c]  = *(const float4*)(g + 1600 + c*16 + q*4);
    }
    p.stot = g[1664];
}

__global__ void __launch_bounds__(64)
k_cnfM(const float* __restrict__ z1, const float* __restrict__ hyp,
       float* __restrict__ part){
    __shared__ __align__(16) float zsf[384];             // [r][d] stride 20
    __shared__ __align__(16) unsigned short hhT[16*72];  // [r][w] stride 72 sh
    __shared__ float trl[16];
    const int lane = threadIdx.x;
    const int q = lane >> 4, d = lane & 15;      // d doubles as r16 for A-frags
    const float dt = -0.5f;

    float z[4], zacc[4], lacc[4], lp[4];
#pragma unroll
    for (int i = 0; i < 4; i++){
        z[i] = z1[(size_t)(blockIdx.x*16 + q*4 + i)*16 + d];
        zacc[i] = 0.f; lacc[i] = 0.f; lp[i] = 0.f;
        zsf[(q*4 + i)*20 + d] = z[i];
    }
    PM cur, nxt;
    loadPM(hyp, lane, q, cur);

    for (int sidx = 0; sidx < 80; sidx++){
        // build z B1-frag (k<16 real; q>=2 contributes 0 via zeroed Wpk)
        bf16x8 zb;
        if (q < 2){
            float4 za = *(const float4*)(zsf + d*20 + q*8);
            float4 zc = *(const float4*)(zsf + d*20 + q*8 + 4);
            zb[0]=(short)f2b(za.x); zb[1]=(short)f2b(za.y);
            zb[2]=(short)f2b(za.z); zb[3]=(short)f2b(za.w);
            zb[4]=(short)f2b(zc.x); zb[5]=(short)f2b(zc.y);
            zb[6]=(short)f2b(zc.z); zb[7]=(short)f2b(zc.w);
        } else {
            bf16x8 zz2 = {0,0,0,0,0,0,0,0}; zb = zz2;
        }
        // phase1: HH[w][r], 4 chunks
        f32x4 h0 = {0,0,0,0}, h1 = {0,0,0,0}, h2 = {0,0,0,0}, h3 = {0,0,0,0};
        h0 = __builtin_amdgcn_mfma_f32_16x16x32_bf16(cur.Wf[0], zb, h0, 0,0,0);
        h1 = __builtin_amdgcn_mfma_f32_16x16x32_bf16(cur.Wf[1], zb, h1, 0,0,0);
        h2 = __builtin_amdgcn_mfma_f32_16x16x32_bf16(cur.Wf[2], zb, h2, 0,0,0);
        h3 = __builtin_amdgcn_mfma_f32_16x16x32_bf16(cur.Wf[3], zb, h3, 0,0,0);
        if (sidx < 79) loadPM(hyp + (size_t)(sidx + 1)*2048, lane, q, nxt);

        // tanh + trace partial + hhT write (rows r = d = lane&15)
        float partial = 0.f;
        f32x4 hc[4] = {h0, h1, h2, h3};
#pragma unroll
        for (int c = 0; c < 4; c++){
            ushort4 o;
            float t0 = fast_tanh(hc[c][0] + cur.Bbf[c].x);
            float t1 = fast_tanh(hc[c][1] + cur.Bbf[c].y);
            float t2 = fast_tanh(hc[c][2] + cur.Bbf[c].z);
            float t3 = fast_tanh(hc[c][3] + cur.Bbf[c].w);
            partial += t0*t0*cur.sf[c].x + t1*t1*cur.sf[c].y
                     + t2*t2*cur.sf[c].z + t3*t3*cur.sf[c].w;
            o.x = f2b(t0); o.y = f2b(t1); o.z = f2b(t2); o.w = f2b(t3);
            *(ushort4*)(hhT + d*72 + c*16 + q*4) = o;
        }
        partial += __shfl_xor(partial, 16);
        partial += __shfl_xor(partial, 32);
        if (lane < 16) trl[lane] = (cur.stot - partial) * (1.f/64.f);

        // phase2: dz[r][d] via A2 = hhT rows, B2 = Upk
        bf16x8 a20 = *(const bf16x8*)(hhT + d*72 + q*8);
        bf16x8 a21 = *(const bf16x8*)(hhT + d*72 + 32 + q*8);
        f32x4 dzac = {0,0,0,0};
        dzac = __builtin_amdgcn_mfma_f32_16x16x32_bf16(a20, cur.Uf[0], dzac, 0,0,0);
        dzac = __builtin_amdgcn_mfma_f32_16x16x32_bf16(a21, cur.Uf[1], dzac, 0,0,0);

        int st = sidx & 3;
        float wgt = (st == 0 || st == 3) ? 1.f : 2.f;
#pragma unroll
        for (int i = 0; i < 4; i++){
            float dz = dzac[i] * (1.f/64.f);
            float dl = -trl[q*4 + i];
            zacc[i] += wgt * dz;
            lacc[i] += wgt * dl;
            float zsv;
            if (st < 3){
                float aa = (st == 2) ? 1.0f : 0.5f;
                zsv = z[i] + aa * dt * dz;
            } else {
                z[i]  += (dt/6.f) * zacc[i];
                lp[i] += (dt/6.f) * lacc[i];
                zsv = z[i];
                zacc[i] = 0.f; lacc[i] = 0.f;
            }
            zsf[(q*4 + i)*20 + d] = zsv;
        }
        cur = nxt;
    }
    // logp per row; reduce z^2 over d (16-lane groups share q)
    float sq[4];
#pragma unroll
    for (int i = 0; i < 4; i++) sq[i] = z[i]*z[i];
#pragma unroll
    for (int off = 1; off < 16; off <<= 1){
#pragma unroll
        for (int i = 0; i < 4; i++) sq[i] += __shfl_xor(sq[i], off, 16);
    }
    if (d == 0){
#pragma unroll
        for (int i = 0; i < 4; i++){
            float logp = -0.5f * (16.f*1.8378770664093453f
                                 + 16.f*(-2.302585092994046f) + sq[i]*10.f);
            part[blockIdx.x*16 + q*4 + i] = logp - lp[i];
        }
    }
}

// ===== CNF fallback (R7, old hyp layout) ===================================
struct PF { float4 Wr[4]; float4 Ur[4]; float Bb, sw; };
__device__ __forceinline__ void load_pf(const float* __restrict__ g,
                                        int lane, int q, int d, PF& p){
    const float4* w4 = (const float4*)(g + lane*16);
    p.Wr[0] = w4[0]; p.Wr[1] = w4[1]; p.Wr[2] = w4[2]; p.Wr[3] = w4[3];
    const float4* u4 = (const float4*)(g + 1024 + d*64 + q*16);
    p.Ur[0] = u4[0]; p.Ur[1] = u4[1]; p.Ur[2] = u4[2]; p.Ur[3] = u4[3];
    p.Bb = g[2048 + lane];
    p.sw = g[2112 + lane];
}
__global__ void __launch_bounds__(64)
k_cnf_f(const float* __restrict__ z1, const float* __restrict__ hyp,
        float* __restrict__ part){
    __shared__ __align__(16) float zsl[16];
    __shared__ __align__(16) float hhl[64];
    const int lane = threadIdx.x;
    const int q = lane >> 4, d = lane & 15;
    const float dt = -0.5f;
    float z  = z1[(size_t)blockIdx.x*16 + d];
    float zs = z;
    float lp = 0.f, zacc = 0.f, lacc = 0.f;
    if (lane < 16) zsl[lane] = zs;
    PF cur, nxt;
    load_pf(hyp, lane, q, d, cur);
    for (int sidx = 0; sidx < 80; sidx++){
        __syncthreads();
        if (sidx < 79) load_pf(hyp + (size_t)(sidx + 1)*2304, lane, q, d, nxt);
        const float4* zp = (const float4*)zsl;
        float4 z0 = zp[0], z1v = zp[1], z2 = zp[2], z3 = zp[3];
        float a = cur.Bb;
        a += z0.x*cur.Wr[0].x + z0.y*cur.Wr[0].y + z0.z*cur.Wr[0].z + z0.w*cur.Wr[0].w;
        a += z1v.x*cur.Wr[1].x + z1v.y*cur.Wr[1].y + z1v.z*cur.Wr[1].z + z1v.w*cur.Wr[1].w;
        a += z2.x*cur.Wr[2].x + z2.y*cur.Wr[2].y + z2.z*cur.Wr[2].z + z2.w*cur.Wr[2].w;
        a += z3.x*cur.Wr[3].x + z3.y*cur.Wr[3].y + z3.z*cur.Wr[3].z + z3.w*cur.Wr[3].w;
        float hh = fast_tanh(a);
        float e = (1.f - hh*hh) * cur.sw;
#pragma unroll
        for (int off = 1; off < 64; off <<= 1)
            e += __shfl_xor(e, off);
        hhl[lane] = hh;
        __syncthreads();
        const float4* hp = (const float4*)(hhl + q*16);
        float4 h0 = hp[0], h1 = hp[1], h2 = hp[2], h3 = hp[3];
        float dzp = 0.f;
        dzp += h0.x*cur.Ur[0].x + h0.y*cur.Ur[0].y + h0.z*cur.Ur[0].z + h0.w*cur.Ur[0].w;
        dzp += h1.x*cur.Ur[1].x + h1.y*cur.Ur[1].y + h1.z*cur.Ur[1].z + h1.w*cur.Ur[1].w;
        dzp += h2.x*cur.Ur[2].x + h2.y*cur.Ur[2].y + h2.z*cur.Ur[2].z + h2.w*cur.Ur[2].w;
        dzp += h3.x*cur.Ur[3].x + h3.y*cur.Ur[3].y + h3.z*cur.Ur[3].z + h3.w*cur.Ur[3].w;
        dzp += __shfl_xor(dzp, 16);
        dzp += __shfl_xor(dzp, 32);
        float dz = dzp * (1.f/64.f);
        float dl = -e  * (1.f/64.f);
        int st = sidx & 3;
        float wgt = (st == 0 || st == 3) ? 1.f : 2.f;
        zacc += wgt * dz;
        lacc += wgt * dl;
        if (st < 3){
            float aa = (st == 2) ? 1.0f : 0.5f;
            zs = z + aa * dt * dz;
        } else {
            z  += (dt/6.f) * zacc;
            lp += (dt/6.f) * lacc;
            zs = z;
            zacc = 0.f; lacc = 0.f;
        }
        if (lane < 16) zsl[lane] = zs;
        cur = nxt;
    }
    float sq = z * z;
#pragma unroll
    for (int off = 1; off < 16; off <<= 1) sq += __shfl_xor(sq, off, 16);
    float logp = -0.5f * (16.f*1.8378770664093453f + 16.f*(-2.302585092994046f) + sq*10.f);
    if (lane == 0) part[blockIdx.x] = logp - lp;
}

__global__ void k_final(const float* __restrict__ part, float* __restrict__ out){
    __shared__ float red[256];
    int tid = threadIdx.x;
    float s = 0.f;
#pragma unroll
    for (int k = 0; k < 8; k++) s += part[tid + k*256];
    red[tid] = s;
    __syncthreads();
    for (int st = 128; st > 0; st >>= 1){
        if (tid < st) red[tid] += red[tid + st];
        __syncthreads();
    }
    if (tid == 0) out[1605632] = red[0] * (1.f/2048.f);
}

extern "C" void kernel_launch(void* const* d_in, const int* in_sizes, int n_in,
                              void* d_out, int out_size, void* d_ws, size_t ws_size,
                              hipStream_t stream){
    const float* x   = (const float*)d_in[0];
    const float* c0w = (const float*)d_in[1];
    const float* c0b = (const float*)d_in[2];
    const float* c1w = (const float*)d_in[3];
    const float* c1b = (const float*)d_in[4];
    const float* c2w = (const float*)d_in[5];
    const float* c2b = (const float*)d_in[6];
    const float* elw = (const float*)d_in[7];
    const float* elb = (const float*)d_in[8];
    const float* dlw = (const float*)d_in[9];
    const float* dlb = (const float*)d_in[10];
    const float* t0w = (const float*)d_in[11];
    const float* t0b = (const float*)d_in[12];
    const float* t1w = (const float*)d_in[13];
    const float* t1b = (const float*)d_in[14];
    const float* t2w = (const float*)d_in[15];
    const float* t2b = (const float*)d_in[16];
    const float* h1w = (const float*)d_in[17];
    const float* h1b = (const float*)d_in[18];
    const float* h2w = (const float*)d_in[19];
    const float* h2b = (const float*)d_in[20];
    const float* h3w = (const float*)d_in[21];
    const float* h3b = (const float*)d_in[22];

    float* ws   = (float*)d_ws;
    float* z1   = ws;                          // 32768 f
    float* hyp  = z1 + 32768;                  // 184320 f (max of both layouts)
    float* part = hyp + 184320;                // 2048 f
    float* p2ws = part + 2048;                 // 5120 f
    float* p3ws = p2ws + 5120;                 // 256000 f (80*3200)
    unsigned short* wc1  = (unsigned short*)(p3ws + 256000);  // 9216 each
    unsigned short* wc2  = wc1 + 9216;
    unsigned short* wt0  = wc2 + 9216;
    unsigned short* wt1  = wt0 + 9216;
    unsigned short* elwT = wt1 + 9216;         // 247808
    unsigned short* dlwT = elwT + 247808;      // 247808
    unsigned short* act  = dlwT + 247808;      // byte offset 2,985,984
    float* rec  = (float*)d_out;

    const size_t MISC = 2985984;
    int CH = 0;
    const int cands[6] = {2048, 1024, 512, 256, 128, 64};
    for (int c = 0; c < 6; c++){
        size_t need = MISC + (size_t)cands[c] * 111104;
        if (need <= ws_size){ CH = cands[c]; break; }
    }

    if (CH == 0){
        // tiny-ws fallback (old hyp layout + proven fused path)
        k_hyper<<<80, 256, 0, stream>>>(h1w, h1b, h2w, h2b, h3w, h3b, hyp);
        k_prep <<<64,   256, 0, stream>>>(c1w, c2w, t0w, t1w, elw, dlw, elb,
                                          wc1, wc2, wt0, wt1, wt1, wt1, z1, 0);
        k_enc_f<<<2048, 256, 0, stream>>>(x, c0w, c0b, wc1, c1b, wc2, c2b, elw, elb, z1);
        k_cnf_f<<<2048,  64, 0, stream>>>(z1, hyp, part);
        k_dec_f<<<2048, 256, 0, stream>>>(z1, dlw, dlb, wt0, t0b, wt1, t1b, t2w, t2b, rec);
        k_final<<<1,    256, 0, stream>>>(part, rec);
        return;
    }

    k_hyp1<<<80,           64, 0, stream>>>(h1w, h1b, h2w, h2b, p2ws);
    k_hyp2<<<dim3(13,80), 256, 0, stream>>>(p2ws, h3w, h3b, p3ws);
    k_hyp3<<<80,          256, 0, stream>>>(p3ws, hyp);

    k_prep<<<64, 256, 0, stream>>>(c1w, c2w, t0w, t1w, elw, dlw, elb,
                                   wc1, wc2, wt0, wt1, elwT, dlwT, z1, 1);

    unsigned short* R0 = act;                          // A0 / D0 / D2 : CH*21632
    unsigned short* R1 = R0 + (size_t)CH*21632;        // A1 ; D1 head : CH*18432
    unsigned short* R2 = R1 + (size_t)CH*18432;        // A2 ; D1 tail : CH*15488
    unsigned short* D1 = R1;                           // CH*25088 <= CH*33920

    for (int cb = 0; cb < Bsz; cb += CH){
        k_conv0<<<(CH*676 + 255)/256, 256, 0, stream>>>(x, c0w, c0b, R0, cb, CH);
        k_convM<26,24,24, 0, 21632, 18432><<<(CH*36 + 15)/16, 256, 0, stream>>>(R0, wc1, c1b, R1, CH);
        k_convM<24,22,22, 0, 18432, 15488><<<(CH*31 + 15)/16, 256, 0, stream>>>(R1, wc2, c2b, R2, CH);
        k_encg<<<dim3(CH/16, 4), 256, 0, stream>>>(R2, elwT, z1, cb, CH);
        k_halo<<<(CH*1460 + 255)/256, 256, 0, stream>>>(R0, D1, CH);
        k_decg<<<dim3(61, CH/16), 256, 0, stream>>>(z1, dlwT, dlb, R0, cb, CH);
        k_convM<26,24,28,58, 21632, 25088><<<(CH*36 + 15)/16, 256, 0, stream>>>(R0, wt0, t0b, D1, CH);
        k_convM<28,26,26, 0, 25088, 21632><<<(CH*43 + 15)/16, 256, 0, stream>>>(D1, wt1, t1b, R0, CH);
        k_convT2<<<(CH*784 + 255)/256, 256, 0, stream>>>(R0, t2w, t2b, rec, cb, CH);
    }
    k_cnfM <<<128,  64, 0, stream>>>(z1, hyp, part);
    k_final<<<1,   256, 0, stream>>>(part, rec);
}

// Round 9
// 636.483 us; speedup vs baseline: 9.3612x; 1.0247x over previous
//
#include <hip/hip_runtime.h>
#include <math.h>

#define Bsz 2048

using bf16x8 = __attribute__((ext_vector_type(8))) short;
using f32x4  = __attribute__((ext_vector_type(4))) float;

__device__ __forceinline__ float fast_tanh(float x){
    float e = __expf(2.0f * x);
    return 1.0f - 2.0f / (e + 1.0f);
}
__device__ __forceinline__ float fast_sigmoid(float x){
    return 1.0f / (1.0f + __expf(-x));
}
__device__ __forceinline__ unsigned short f2b(float f){
    union { float f; unsigned u; } v; v.f = f;
    unsigned r = v.u + 0x7FFFu + ((v.u >> 16) & 1u);
    return (unsigned short)(r >> 16);
}
__device__ __forceinline__ float b2f(unsigned short s){
    union { unsigned u; float f; } v; v.u = ((unsigned)s) << 16;
    return v.f;
}

__device__ __forceinline__ float stage_t(int sidx){
    int i  = sidx >> 2, st = sidx & 3;
    float t = 10.0f - 0.5f * (float)i;
    if (st == 1 || st == 2) t -= 0.25f;
    else if (st == 3)       t -= 0.5f;
    return t;
}

// ===== weight prep (+ z1 bias init for atomic encoder) ======================
__global__ void k_prep(const float* __restrict__ c1w, const float* __restrict__ c2w,
                       const float* __restrict__ t0w, const float* __restrict__ t1w,
                       const float* __restrict__ elw, const float* __restrict__ dlw,
                       const float* __restrict__ elb,
                       unsigned short* __restrict__ wc1, unsigned short* __restrict__ wc2,
                       unsigned short* __restrict__ wt0, unsigned short* __restrict__ wt1,
                       unsigned short* __restrict__ elwT, unsigned short* __restrict__ dlwT,
                       float* __restrict__ z1, int full){
    int gsz = gridDim.x * 256;
    for (int i = blockIdx.x*256 + threadIdx.x; i < 9216; i += gsz){
        int ci = i & 31, co = (i >> 5) & 31, s = i >> 10;
        wc1[i] = f2b(c1w[(co*32 + ci)*9 + s]);
        wc2[i] = f2b(c2w[(co*32 + ci)*9 + s]);
        wt0[i] = f2b(t0w[(ci*32 + co)*9 + (8 - s)]);
        wt1[i] = f2b(t1w[(ci*32 + co)*9 + (8 - s)]);
    }
    if (!full) return;
    for (int i = blockIdx.x*256 + threadIdx.x; i < 32768; i += gsz)
        z1[i] = elb[i & 15];
    for (int i = blockIdx.x*256 + threadIdx.x; i < 247808; i += gsz){
        int l = i / 15488, f2 = i - l*15488;
        int pos = f2 >> 5, ci = f2 & 31;
        elwT[i] = f2b(elw[(ci*484 + pos)*16 + l]);
    }
    for (int i = blockIdx.x*256 + threadIdx.x; i < 247808; i += gsz){
        int f2 = i >> 4, l = i & 15;
        int pos = f2 >> 5, ci = f2 & 31;
        dlwT[i] = f2b(dlw[l*15488 + ci*484 + pos]);
    }
}

// ===== conv0: 1->32, VALU ==================================================
__global__ void __launch_bounds__(256)
k_conv0(const float* __restrict__ x, const float* __restrict__ c0w,
        const float* __restrict__ c0b, unsigned short* __restrict__ A0,
        int cb, int CH){
    int gid = blockIdx.x*256 + threadIdx.x;
    if (gid >= CH*676) return;
    int b = gid / 676, pos = gid - b*676;
    int y = pos / 26, xx = pos - y*26;
    const float* xin = x + (size_t)(cb + b)*784;
    float v[9];
#pragma unroll
    for (int r = 0; r < 3; r++)
#pragma unroll
        for (int s = 0; s < 3; s++)
            v[r*3+s] = xin[(y+r)*28 + xx + s];
    unsigned short* ob = A0 + (size_t)b*21632 + pos*32;
#pragma unroll
    for (int g = 0; g < 8; g++){
        float a0 = c0b[g*4+0], a1 = c0b[g*4+1], a2 = c0b[g*4+2], a3 = c0b[g*4+3];
#pragma unroll
        for (int k = 0; k < 9; k++){
            a0 += v[k] * c0w[(g*4+0)*9 + k];
            a1 += v[k] * c0w[(g*4+1)*9 + k];
            a2 += v[k] * c0w[(g*4+2)*9 + k];
            a3 += v[k] * c0w[(g*4+3)*9 + k];
        }
        ushort4 o;
        o.x = f2b(fast_tanh(a0)); o.y = f2b(fast_tanh(a1));
        o.z = f2b(fast_tanh(a2)); o.w = f2b(fast_tanh(a3));
        *(ushort4*)(ob + g*4) = o;
    }
}

// ===== MFMA conv layer, tile-parallel across all images ====================
template<int IL, int OL, int OW, int OOFF, int INS, int OUTS>
__global__ void __launch_bounds__(256)
k_convM(const unsigned short* __restrict__ in, const unsigned short* __restrict__ wg,
        const float* __restrict__ bias, unsigned short* __restrict__ out, int CH){
    constexpr int N  = OL * OL;
    constexpr int NT = (N + 15) / 16;
    const int tid = threadIdx.x;
    const int wave = tid >> 6, lane = tid & 63;
    const int q = lane >> 4, nn = lane & 15;
    const int nw = gridDim.x * 4;

    bf16x8 af[2][9];
#pragma unroll
    for (int mt = 0; mt < 2; mt++)
#pragma unroll
        for (int s = 0; s < 9; s++)
            af[mt][s] = *(const bf16x8*)(wg + s*1024 + (mt*16 + nn)*32 + q*8);
    float4 bc0 = *(const float4*)(bias + q*4);
    float4 bc1 = *(const float4*)(bias + 16 + q*4);

    for (int t = blockIdx.x*4 + wave; t < CH*NT; t += nw){
        int img = t / NT, tt = t - img*NT;
        const unsigned short* inb = in + (size_t)img * INS;
        unsigned short* outb = out + (size_t)img * OUTS;
        int pos = tt*16 + nn;
        int pc  = pos < N ? pos : N - 1;
        int oy = pc / OL, ox = pc - oy*OL;
        const unsigned short* ib = inb + (oy*IL + ox)*32 + q*8;
        f32x4 acc0 = {0.f,0.f,0.f,0.f}, acc1 = {0.f,0.f,0.f,0.f};
#pragma unroll
        for (int r = 0; r < 3; r++){
            bf16x8 b0 = *(const bf16x8*)(ib + (r*IL + 0)*32);
            bf16x8 b1 = *(const bf16x8*)(ib + (r*IL + 1)*32);
            bf16x8 b2 = *(const bf16x8*)(ib + (r*IL + 2)*32);
            acc0 = __builtin_amdgcn_mfma_f32_16x16x32_bf16(af[0][r*3+0], b0, acc0, 0,0,0);
            acc1 = __builtin_amdgcn_mfma_f32_16x16x32_bf16(af[1][r*3+0], b0, acc1, 0,0,0);
            acc0 = __builtin_amdgcn_mfma_f32_16x16x32_bf16(af[0][r*3+1], b1, acc0, 0,0,0);
            acc1 = __builtin_amdgcn_mfma_f32_16x16x32_bf16(af[1][r*3+1], b1, acc1, 0,0,0);
            acc0 = __builtin_amdgcn_mfma_f32_16x16x32_bf16(af[0][r*3+2], b2, acc0, 0,0,0);
            acc1 = __builtin_amdgcn_mfma_f32_16x16x32_bf16(af[1][r*3+2], b2, acc1, 0,0,0);
        }
        if (pos < N){
            int opix = oy*OW + ox + OOFF;
            ushort4 o0, o1;
            o0.x = f2b(fast_tanh(acc0[0] + bc0.x)); o0.y = f2b(fast_tanh(acc0[1] + bc0.y));
            o0.z = f2b(fast_tanh(acc0[2] + bc0.z)); o0.w = f2b(fast_tanh(acc0[3] + bc0.w));
            o1.x = f2b(fast_tanh(acc1[0] + bc1.x)); o1.y = f2b(fast_tanh(acc1[1] + bc1.y));
            o1.z = f2b(fast_tanh(acc1[2] + bc1.z)); o1.w = f2b(fast_tanh(acc1[3] + bc1.w));
            *(ushort4*)(outb + opix*32 + q*4)      = o0;
            *(ushort4*)(outb + opix*32 + 16 + q*4) = o1;
        }
    }
}

// ===== encoder GEMM (A2 lives in Y buffer, stride 21632) ===================
__global__ void __launch_bounds__(256)
k_encg(const unsigned short* __restrict__ A2, const unsigned short* __restrict__ elwT,
       float* __restrict__ z1, int cb, int CH){
    int wave = threadIdx.x >> 6, lane = threadIdx.x & 63;
    int q = lane >> 4, nn = lane & 15;
    int imgb = blockIdx.x*16;
    const unsigned short* ap = A2 + (size_t)(imgb + nn)*21632 + q*8;
    const unsigned short* bp = elwT + (size_t)nn*15488 + q*8;
    f32x4 acc = {0.f,0.f,0.f,0.f};
    int s0 = blockIdx.y*121;
#pragma unroll 2
    for (int s = s0 + wave; s < s0 + 121; s += 4){
        bf16x8 a = *(const bf16x8*)(ap + s*32);
        bf16x8 b = *(const bf16x8*)(bp + s*32);
        acc = __builtin_amdgcn_mfma_f32_16x16x32_bf16(a, b, acc, 0,0,0);
    }
    float* zp = z1 + (size_t)(cb + imgb)*16;
#pragma unroll
    for (int i = 0; i < 4; i++)
        atomicAdd(zp + (q*4 + i)*16 + nn, acc[i]);
}

// ===== decoder GEMV + fused halo zeroing (blocks x>=61) ====================
__global__ void __launch_bounds__(256)
k_decg(const float* __restrict__ z1, const unsigned short* __restrict__ dlwT,
       const float* __restrict__ dlb, unsigned short* __restrict__ D0,
       unsigned short* __restrict__ D1, int cb, int CH){
    __shared__ float zl[256];
    int tid = threadIdx.x, ib = blockIdx.y;
    zl[tid] = z1[(size_t)(cb + ib*16 + (tid >> 4))*16 + (tid & 15)];
    __syncthreads();
    if (blockIdx.x >= 61){
        // halo zeroing for this y-slice's 16 images
        int hid = (blockIdx.x - 61)*256 + tid;   // 0..1279
        uint4 zq = {0,0,0,0};
        for (int p = hid; p < 16*676; p += 1280){
            int im = p / 676, px = p - im*676;
            int y = px / 26, x = px - y*26;
            if (y < 2 || y >= 24 || x < 2 || x >= 24){
                uint4* pt = (uint4*)(D0 + (size_t)(ib*16 + im)*21632 + px*32);
                pt[0] = zq; pt[1] = zq; pt[2] = zq; pt[3] = zq;
            }
        }
        for (int p = hid; p < 16*784; p += 1280){
            int im = p / 784, px = p - im*784;
            int y = px / 28, x = px - y*28;
            if (y < 2 || y >= 26 || x < 2 || x >= 26){
                uint4* pt = (uint4*)(D1 + (size_t)(ib*16 + im)*25088 + px*32);
                pt[0] = zq; pt[1] = zq; pt[2] = zq; pt[3] = zq;
            }
        }
        return;
    }
    int ci = tid & 31, po = tid >> 5;
    int pos = blockIdx.x*8 + po;
    if (pos >= 484) return;
    int y = pos / 22, xx = pos - y*22;
    float bias = dlb[ci*484 + pos];
    const unsigned short* w = dlwT + (size_t)(pos*32 + ci)*16;
    bf16x8 w0 = *(const bf16x8*)(w);
    bf16x8 w1 = *(const bf16x8*)(w + 8);
    float wf[16];
#pragma unroll
    for (int j = 0; j < 8; j++){
        wf[j]   = b2f((unsigned short)w0[j]);
        wf[8+j] = b2f((unsigned short)w1[j]);
    }
    int opix = ((y+2)*26 + xx + 2)*32 + ci;
#pragma unroll 1
    for (int i = 0; i < 16; i++){
        float a = bias;
#pragma unroll
        for (int l = 0; l < 16; l++) a += zl[i*16 + l] * wf[l];
        D0[(size_t)(ib*16 + i)*21632 + opix] = f2b(fast_tanh(a));
    }
}

// ===== convT2: 32->1 =======================================================
__global__ void __launch_bounds__(256)
k_convT2(const unsigned short* __restrict__ D2, const float* __restrict__ t2w,
         const float* __restrict__ t2b, float* __restrict__ out, int cb, int CH){
    int gid = blockIdx.x*256 + threadIdx.x;
    if (gid >= CH*784) return;
    int b = gid / 784, o = gid - b*784;
    int y = o / 28, xx = o - y*28;
    const unsigned short* db = D2 + (size_t)b*21632;
    float a = t2b[0];
#pragma unroll
    for (int r = 0; r < 3; r++){
        int iy = y + r - 2;
        if ((unsigned)iy >= 26u) continue;
#pragma unroll
        for (int s = 0; s < 3; s++){
            int ix = xx + s - 2;
            if ((unsigned)ix >= 26u) continue;
            const unsigned short* pp = db + (iy*26 + ix)*32;
            int wi = (2-r)*3 + (2-s);
#pragma unroll
            for (int g = 0; g < 4; g++){
                bf16x8 h = *(const bf16x8*)(pp + g*8);
#pragma unroll
                for (int j = 0; j < 8; j++)
                    a += b2f((unsigned short)h[j]) * t2w[(g*8+j)*9 + wi];
            }
        }
    }
    out[(size_t)(cb + b)*784 + o] = a;
}

// ===== FUSED FALLBACK (round-3, proven) ====================================
template<int LOUT, int INW, int OUTW, int OUTOFF>
__device__ __forceinline__ void conv_gemm(const unsigned short* __restrict__ Wg,
                                          const float* __restrict__ bias,
                                          const unsigned short* inL,
                                          unsigned short* outL, int tid){
    constexpr int N  = LOUT * LOUT;
    constexpr int NT = (N + 15) / 16;
    const int lane  = tid & 63;
    const int wave  = tid >> 6;
    const int mtile = wave & 1;
    const int quad  = lane >> 4;
    const int nn    = lane & 15;
    bf16x8 afr[9];
    const unsigned short* wp = Wg + (mtile*16 + nn)*32 + quad*8;
#pragma unroll
    for (int s = 0; s < 9; s++)
        afr[s] = *(const bf16x8*)(wp + s*1024);
    float4 bco = *(const float4*)(bias + mtile*16 + quad*4);
    for (int t = (wave >> 1); t < NT; t += 2){
        int pos = t*16 + nn;
        int pc  = pos < N ? pos : N - 1;
        int y = pc / LOUT, x = pc - y*LOUT;
        const unsigned short* ib = inL + (y*INW + x)*32 + quad*8;
        f32x4 acc = {0.f, 0.f, 0.f, 0.f};
#pragma unroll
        for (int r = 0; r < 3; r++)
#pragma unroll
            for (int s = 0; s < 3; s++)
                acc = __builtin_amdgcn_mfma_f32_16x16x32_bf16(
                        afr[r*3+s], *(const bf16x8*)(ib + (r*INW + s)*32), acc, 0, 0, 0);
        if (pos < N){
            ushort4 o;
            o.x = f2b(fast_tanh(acc[0] + bco.x));
            o.y = f2b(fast_tanh(acc[1] + bco.y));
            o.z = f2b(fast_tanh(acc[2] + bco.z));
            o.w = f2b(fast_tanh(acc[3] + bco.w));
            int opix = y*OUTW + x + OUTOFF;
            *(ushort4*)(outL + opix*32 + mtile*16 + quad*4) = o;
        }
    }
}

__global__ void __launch_bounds__(256)
k_enc_f(const float* __restrict__ x,
        const float* __restrict__ c0w, const float* __restrict__ c0b,
        const unsigned short* __restrict__ wc1, const float* __restrict__ c1b,
        const unsigned short* __restrict__ wc2, const float* __restrict__ c2b,
        const float* __restrict__ elw, const float* __restrict__ elb,
        float* __restrict__ z1){
    __shared__ float X[784];
    __shared__ __align__(16) unsigned short H0[21632];
    __shared__ __align__(16) unsigned short H1[18432];
    __shared__ __align__(16) unsigned short H2[15488];
    __shared__ float red[16*17];
    const int tid = threadIdx.x, b = blockIdx.x;
    for (int i = tid; i < 784; i += 256) X[i] = x[b*784 + i];
    __syncthreads();
    for (int pos = tid; pos < 676; pos += 256){
        int y = pos / 26, xx = pos - y*26;
        float v[9];
#pragma unroll
        for (int r = 0; r < 3; r++)
#pragma unroll
            for (int s = 0; s < 3; s++)
                v[r*3+s] = X[(y+r)*28 + xx + s];
#pragma unroll
        for (int g = 0; g < 8; g++){
            float a0 = c0b[g*4+0], a1 = c0b[g*4+1], a2 = c0b[g*4+2], a3 = c0b[g*4+3];
#pragma unroll
            for (int k = 0; k < 9; k++){
                a0 += v[k] * c0w[(g*4+0)*9 + k];
                a1 += v[k] * c0w[(g*4+1)*9 + k];
                a2 += v[k] * c0w[(g*4+2)*9 + k];
                a3 += v[k] * c0w[(g*4+3)*9 + k];
            }
            ushort4 o;
            o.x = f2b(fast_tanh(a0)); o.y = f2b(fast_tanh(a1));
            o.z = f2b(fast_tanh(a2)); o.w = f2b(fast_tanh(a3));
            *(ushort4*)(H0 + pos*32 + g*4) = o;
        }
    }
    __syncthreads();
    conv_gemm<24, 26, 24, 0>(wc1, c1b, H0, H1, tid);
    __syncthreads();
    conv_gemm<22, 24, 22, 0>(wc2, c2b, H1, H2, tid);
    __syncthreads();
    {
        int fg = tid >> 4, l = tid & 15;
        float a = 0.f;
        for (int ci = 0; ci < 32; ci++)
            for (int pos = fg; pos < 484; pos += 16)
                a += b2f(H2[pos*32 + ci]) * elw[(ci*484 + pos)*16 + l];
        red[fg*17 + l] = a;
        __syncthreads();
        if (tid < 16){
            float s = elb[tid];
#pragma unroll
            for (int g = 0; g < 16; g++) s += red[g*17 + tid];
            z1[b*16 + tid] = s;
        }
    }
}

__global__ void __launch_bounds__(256)
k_dec_f(const float* __restrict__ z1,
        const float* __restrict__ dlw, const float* __restrict__ dlb,
        const unsigned short* __restrict__ wt0, const float* __restrict__ t0b,
        const unsigned short* __restrict__ wt1, const float* __restrict__ t1b,
        const float* __restrict__ t2w, const float* __restrict__ t2b,
        float* __restrict__ out){
    __shared__ __align__(16) unsigned short D0[21632];
    __shared__ __align__(16) unsigned short D1[25088];
    __shared__ __align__(16) unsigned short D2[28800];
    const int tid = threadIdx.x, b = blockIdx.x;
    {
        uint4 zq = {0,0,0,0};
        for (int i = tid; i < 2704; i += 256) ((uint4*)D0)[i] = zq;
        for (int i = tid; i < 3136; i += 256) ((uint4*)D1)[i] = zq;
        for (int i = tid; i < 3600; i += 256) ((uint4*)D2)[i] = zq;
    }
    float zz[16];
#pragma unroll
    for (int l = 0; l < 16; l++) zz[l] = z1[b*16 + l];
    __syncthreads();
    for (int f = tid; f < 15488; f += 256){
        float a = dlb[f];
#pragma unroll
        for (int l = 0; l < 16; l++) a += zz[l] * dlw[l*15488 + f];
        int ci = f / 484, pos = f - ci*484;
        int y = pos / 22, xx = pos - y*22;
        D0[((y+2)*26 + xx + 2)*32 + ci] = f2b(fast_tanh(a));
    }
    __syncthreads();
    conv_gemm<24, 26, 28, 58>(wt0, t0b, D0, D1, tid);
    __syncthreads();
    conv_gemm<26, 28, 30, 62>(wt1, t1b, D1, D2, tid);
    __syncthreads();
    for (int o = tid; o < 784; o += 256){
        int y = o / 28, xx = o - y*28;
        float a = t2b[0];
#pragma unroll
        for (int r = 0; r < 3; r++)
#pragma unroll
            for (int s = 0; s < 3; s++){
                const unsigned short* pp = D2 + ((y+r)*30 + xx + s)*32;
                int wi = (2-r)*3 + (2-s);
#pragma unroll
                for (int g = 0; g < 4; g++){
                    bf16x8 h = *(const bf16x8*)(pp + g*8);
#pragma unroll
                    for (int j = 0; j < 8; j++)
                        a += b2f((unsigned short)h[j]) * t2w[(g*8+j)*9 + wi];
                }
            }
        out[(size_t)b*784 + o] = a;
    }
}

// ===== hypernetwork, parallel 3-kernel path ================================
__global__ void __launch_bounds__(64)
k_hyp1(const float* __restrict__ h1w, const float* __restrict__ h1b,
       const float* __restrict__ h2w, const float* __restrict__ h2b,
       float* __restrict__ p2ws){
    __shared__ float p1l[64];
    int sidx = blockIdx.x, tid = threadIdx.x;
    float t = stage_t(sidx);
    p1l[tid] = fast_tanh(t * h1w[tid] + h1b[tid]);
    __syncthreads();
    float a0 = h2b[tid], a1 = 0.f, a2 = 0.f, a3 = 0.f;
#pragma unroll
    for (int k = 0; k < 64; k += 4){
        a0 += p1l[k]   * h2w[(k)*64   + tid];
        a1 += p1l[k+1] * h2w[(k+1)*64 + tid];
        a2 += p1l[k+2] * h2w[(k+2)*64 + tid];
        a3 += p1l[k+3] * h2w[(k+3)*64 + tid];
    }
    p2ws[sidx*64 + tid] = fast_tanh((a0 + a1) + (a2 + a3));
}

__global__ void __launch_bounds__(256)
k_hyp2(const float* __restrict__ p2ws, const float* __restrict__ h3w,
       const float* __restrict__ h3b, float* __restrict__ p3ws){
    __shared__ float p2l[64];
    int sidx = blockIdx.y, tid = threadIdx.x;
    if (tid < 64) p2l[tid] = p2ws[sidx*64 + tid];
    __syncthreads();
    int m = blockIdx.x*256 + tid;
    if (m >= 3136) return;
    const float* hp = h3w + m;
    float a0 = h3b[m], a1 = 0.f, a2 = 0.f, a3 = 0.f;
#pragma unroll
    for (int k = 0; k < 64; k += 4){
        a0 += p2l[k]   * hp[(size_t)(k)*3136];
        a1 += p2l[k+1] * hp[(size_t)(k+1)*3136];
        a2 += p2l[k+2] * hp[(size_t)(k+2)*3136];
        a3 += p2l[k+3] * hp[(size_t)(k+3)*3136];
    }
    p3ws[(size_t)sidx*3200 + m] = (a0 + a1) + (a2 + a3);
}

// k_hyp3: per-lane pre-swizzled MFMA param fragments, stage stride 2048 f
__global__ void __launch_bounds__(256)
k_hyp3(const float* __restrict__ p3ws, float* __restrict__ hyp){
    __shared__ float sred[64];
    int sidx = blockIdx.x, tid = threadIdx.x;
    const float* p3 = p3ws + (size_t)sidx*3200;
    float* g = hyp + (size_t)sidx*2048;
    unsigned short* gW = (unsigned short*)g;
    unsigned short* gU = (unsigned short*)(g + 1024);

    {   // Wpk: tid = c*64 + lane
        int lane = tid & 63, c = tid >> 6;
        int q = lane >> 4, m = lane & 15;
        ushort4 o0 = {0,0,0,0}, o1 = {0,0,0,0};
        if (q < 2){
            const float* wp = p3 + (c*16 + m)*16 + q*8;
            o0.x = f2b(wp[0]); o0.y = f2b(wp[1]); o0.z = f2b(wp[2]); o0.w = f2b(wp[3]);
            o1.x = f2b(wp[4]); o1.y = f2b(wp[5]); o1.z = f2b(wp[6]); o1.w = f2b(wp[7]);
        }
        *(ushort4*)(gW + tid*8)     = o0;
        *(ushort4*)(gW + tid*8 + 4) = o1;
    }
    if (tid < 128){  // Upk: tid = kb*64 + lane
        int lane = tid & 63, kb = tid >> 6;
        int q = lane >> 4, d = lane & 15;
        unsigned short uo[8];
#pragma unroll
        for (int j = 0; j < 8; j++){
            int w = kb*32 + q*8 + j;
            float u = p3[1024 + w*16 + d] * fast_sigmoid(p3[2048 + w*16 + d]);
            uo[j] = f2b(u);
        }
        *(ushort4*)(gU + tid*8)     = *(ushort4*)&uo[0];
        *(ushort4*)(gU + tid*8 + 4) = *(ushort4*)&uo[4];
    } else if (tid < 192){  // Bb
        int w = tid - 128;
        g[1536 + w] = p3[3072 + w];
    } else {                // s[w]
        int w = tid - 192;
        float s = 0.f;
#pragma unroll
        for (int d = 0; d < 16; d++){
            float u = p3[1024 + w*16 + d] * fast_sigmoid(p3[2048 + w*16 + d]);
            s += p3[w*16 + d] * u;
        }
        g[1600 + w] = s;
        sred[w] = s;
    }
    __syncthreads();
    if (tid == 0){
        float st = 0.f;
#pragma unroll
        for (int w = 0; w < 64; w++) st += sred[w];
        g[1664] = st;
    }
}

// ===== single-block hyper (fallback only, OLD layout stride 2304) ==========
__global__ void k_hyper(const float* __restrict__ h1w, const float* __restrict__ h1b,
                        const float* __restrict__ h2w, const float* __restrict__ h2b,
                        const float* __restrict__ h3w, const float* __restrict__ h3b,
                        float* __restrict__ hyp){
    int sidx = blockIdx.x;
    float t = stage_t(sidx);
    __shared__ float p1[64], p2[64];
    __shared__ float p3[3136];
    int tid = threadIdx.x;
    if (tid < 64) p1[tid] = fast_tanh(t * h1w[tid] + h1b[tid]);
    __syncthreads();
    if (tid < 64){
        float a = h2b[tid];
#pragma unroll
        for (int k = 0; k < 64; k++) a += p1[k] * h2w[k*64 + tid];
        p2[tid] = fast_tanh(a);
    }
    __syncthreads();
    for (int m = tid; m < 3136; m += 256){
        float a = h3b[m];
#pragma unroll
        for (int k = 0; k < 64; k++) a += p2[k] * h3w[k*3136 + m];
        p3[m] = a;
    }
    __syncthreads();
    float* g = hyp + (size_t)sidx * 2304;
    for (int m = tid; m < 1024; m += 256){
        g[m] = p3[m];
        float u = p3[1024 + m] * fast_sigmoid(p3[2048 + m]);
        g[1024 + (m & 15)*64 + (m >> 4)] = u;
        p3[1024 + m] = u;
    }
    if (tid < 64) g[2048 + tid] = p3[3072 + tid];
    __syncthreads();
    if (tid < 64){
        float s = 0.f;
#pragma unroll
        for (int d = 0; d < 16; d++) s += p3[tid*16 + d] * p3[1024 + tid*16 + d];
        g[2112 + tid] = s;
    }
}

// ===== CNF RK4 (MFMA): 16 rows/wave, 128 single-wave blocks ================
struct PM {
    bf16x8 Wf[4];     // A1 frags, chunks of 16 w
    bf16x8 Uf[2];     // B2 frags, k-blocks of 32 w
    float4 Bbf[4];    // Bb[c*16+q*4 ..+3]
    float4 sf[4];     // s [c*16+q*4 ..+3]
    float stot;
};
__device__ __forceinline__ void loadPM(const float* __restrict__ g, int lane, int q, PM& p){
    const unsigned short* gW = (const unsigned short*)g;
    const unsigned short* gU = (const unsigned short*)(g + 1024);
#pragma unroll
    for (int c = 0; c < 4; c++)
        p.Wf[c] = *(const bf16x8*)(gW + (c*64 + lane)*8);
#pragma unroll
    for (int kb = 0; kb < 2; kb++)
        p.Uf[kb] = *(const bf16x8*)(gU + (kb*64 + lane)*8);
#pragma unroll
    for (int c = 0; c < 4; c++){
        p.Bbf[c] = *(const float4*)(g + 1536 + c*16 + q*4);
        p.sf[c]  = *(const float4*)(g + 1600 + c*16 + q*4);
    }
    p.stot = g[1664];
}

__global__ void __launch_bounds__(64)
k_cnfM(const float* __restrict__ z1, const float* __restrict__ hyp,
       float* __restrict__ part){
    __shared__ __align__(16) unsigned short zsb[16*24];   // [row][d] stride 24 sh
    __shared__ __align__(16) unsigned short hhT[16*72];   // [r][w]   stride 72 sh
    const int lane = threadIdx.x;
    const int q = lane >> 4, d = lane & 15;
    const float dt = -0.5f;

    float z[4], zacc[4], lacc[4], lp[4];
#pragma unroll
    for (int i = 0; i < 4; i++){
        z[i] = z1[(size_t)(blockIdx.x*16 + q*4 + i)*16 + d];
        zacc[i] = 0.f; lacc[i] = 0.f; lp[i] = 0.f;
        zsb[(q*4 + i)*24 + d] = f2b(z[i]);
    }
    PM pm0, pm1;
    loadPM(hyp, lane, q, pm0);

#pragma unroll 2
    for (int sidx = 0; sidx < 80; sidx++){
        PM& cur = (sidx & 1) ? pm1 : pm0;
        PM& nxt = (sidx & 1) ? pm0 : pm1;
        if (sidx < 79) loadPM(hyp + (size_t)(sidx + 1)*2048, lane, q, nxt);

        bf16x8 zb;
        if (q < 2) zb = *(const bf16x8*)(zsb + d*24 + q*8);
        else { bf16x8 zz2 = {0,0,0,0,0,0,0,0}; zb = zz2; }

        // phase1: HH[w][r]
        f32x4 h0 = {0,0,0,0}, h1 = {0,0,0,0}, h2 = {0,0,0,0}, h3 = {0,0,0,0};
        h0 = __builtin_amdgcn_mfma_f32_16x16x32_bf16(cur.Wf[0], zb, h0, 0,0,0);
        h1 = __builtin_amdgcn_mfma_f32_16x16x32_bf16(cur.Wf[1], zb, h1, 0,0,0);
        h2 = __builtin_amdgcn_mfma_f32_16x16x32_bf16(cur.Wf[2], zb, h2, 0,0,0);
        h3 = __builtin_amdgcn_mfma_f32_16x16x32_bf16(cur.Wf[3], zb, h3, 0,0,0);

        // tanh + trace partial + hhT write (rows r = d)
        float partial = 0.f;
        f32x4 hc[4] = {h0, h1, h2, h3};
#pragma unroll
        for (int c = 0; c < 4; c++){
            ushort4 o;
            float t0 = fast_tanh(hc[c][0] + cur.Bbf[c].x);
            float t1 = fast_tanh(hc[c][1] + cur.Bbf[c].y);
            float t2 = fast_tanh(hc[c][2] + cur.Bbf[c].z);
            float t3 = fast_tanh(hc[c][3] + cur.Bbf[c].w);
            partial += t0*t0*cur.sf[c].x + t1*t1*cur.sf[c].y
                     + t2*t2*cur.sf[c].z + t3*t3*cur.sf[c].w;
            o.x = f2b(t0); o.y = f2b(t1); o.z = f2b(t2); o.w = f2b(t3);
            *(ushort4*)(hhT + d*72 + c*16 + q*4) = o;
        }
        partial += __shfl_xor(partial, 16);
        partial += __shfl_xor(partial, 32);
        float trFull = (cur.stot - partial) * (1.f/64.f);   // tr for row d, all q

        // phase2: dz[r][d]
        bf16x8 a20 = *(const bf16x8*)(hhT + d*72 + q*8);
        bf16x8 a21 = *(const bf16x8*)(hhT + d*72 + 32 + q*8);
        f32x4 dzac = {0,0,0,0};
        dzac = __builtin_amdgcn_mfma_f32_16x16x32_bf16(a20, cur.Uf[0], dzac, 0,0,0);
        dzac = __builtin_amdgcn_mfma_f32_16x16x32_bf16(a21, cur.Uf[1], dzac, 0,0,0);

        int st = sidx & 3;
        float wgt = (st == 0 || st == 3) ? 1.f : 2.f;
#pragma unroll
        for (int i = 0; i < 4; i++){
            float dz = dzac[i] * (1.f/64.f);
            float dl = -__shfl(trFull, q*4 + i);   // tr[row q*4+i] from lane q*4+i
            zacc[i] += wgt * dz;
            lacc[i] += wgt * dl;
            float zsv;
            if (st < 3){
                float aa = (st == 2) ? 1.0f : 0.5f;
                zsv = z[i] + aa * dt * dz;
            } else {
                z[i]  += (dt/6.f) * zacc[i];
                lp[i] += (dt/6.f) * lacc[i];
                zsv = z[i];
                zacc[i] = 0.f; lacc[i] = 0.f;
            }
            zsb[(q*4 + i)*24 + d] = f2b(zsv);
        }
    }
    float sq[4];
#pragma unroll
    for (int i = 0; i < 4; i++) sq[i] = z[i]*z[i];
#pragma unroll
    for (int off = 1; off < 16; off <<= 1){
#pragma unroll
        for (int i = 0; i < 4; i++) sq[i] += __shfl_xor(sq[i], off, 16);
    }
    if (d == 0){
#pragma unroll
        for (int i = 0; i < 4; i++){
            float logp = -0.5f * (16.f*1.8378770664093453f
                                 + 16.f*(-2.302585092994046f) + sq[i]*10.f);
            part[blockIdx.x*16 + q*4 + i] = logp - lp[i];
        }
    }
}

// ===== CNF fallback (R7, old hyp layout) ===================================
struct PF { float4 Wr[4]; float4 Ur[4]; float Bb, sw; };
__device__ __forceinline__ void load_pf(const float* __restrict__ g,
                                        int lane, int q, int d, PF& p){
    const float4* w4 = (const float4*)(g + lane*16);
    p.Wr[0] = w4[0]; p.Wr[1] = w4[1]; p.Wr[2] = w4[2]; p.Wr[3] = w4[3];
    const float4* u4 = (const float4*)(g + 1024 + d*64 + q*16);
    p.Ur[0] = u4[0]; p.Ur[1] = u4[1]; p.Ur[2] = u4[2]; p.Ur[3] = u4[3];
    p.Bb = g[2048 + lane];
    p.sw = g[2112 + lane];
}
__global__ void __launch_bounds__(64)
k_cnf_f(const float* __restrict__ z1, const float* __restrict__ hyp,
        float* __restrict__ part){
    __shared__ __align__(16) float zsl[16];
    __shared__ __align__(16) float hhl[64];
    const int lane = threadIdx.x;
    const int q = lane >> 4, d = lane & 15;
    const float dt = -0.5f;
    float z  = z1[(size_t)blockIdx.x*16 + d];
    float zs = z;
    float lp = 0.f, zacc = 0.f, lacc = 0.f;
    if (lane < 16) zsl[lane] = zs;
    PF cur, nxt;
    load_pf(hyp, lane, q, d, cur);
    for (int sidx = 0; sidx < 80; sidx++){
        __syncthreads();
        if (sidx < 79) load_pf(hyp + (size_t)(sidx + 1)*2304, lane, q, d, nxt);
        const float4* zp = (const float4*)zsl;
        float4 z0 = zp[0], z1v = zp[1], z2 = zp[2], z3 = zp[3];
        float a = cur.Bb;
        a += z0.x*cur.Wr[0].x + z0.y*cur.Wr[0].y + z0.z*cur.Wr[0].z + z0.w*cur.Wr[0].w;
        a += z1v.x*cur.Wr[1].x + z1v.y*cur.Wr[1].y + z1v.z*cur.Wr[1].z + z1v.w*cur.Wr[1].w;
        a += z2.x*cur.Wr[2].x + z2.y*cur.Wr[2].y + z2.z*cur.Wr[2].z + z2.w*cur.Wr[2].w;
        a += z3.x*cur.Wr[3].x + z3.y*cur.Wr[3].y + z3.z*cur.Wr[3].z + z3.w*cur.Wr[3].w;
        float hh = fast_tanh(a);
        float e = (1.f - hh*hh) * cur.sw;
#pragma unroll
        for (int off = 1; off < 64; off <<= 1)
            e += __shfl_xor(e, off);
        hhl[lane] = hh;
        __syncthreads();
        const float4* hp = (const float4*)(hhl + q*16);
        float4 h0 = hp[0], h1 = hp[1], h2 = hp[2], h3 = hp[3];
        float dzp = 0.f;
        dzp += h0.x*cur.Ur[0].x + h0.y*cur.Ur[0].y + h0.z*cur.Ur[0].z + h0.w*cur.Ur[0].w;
        dzp += h1.x*cur.Ur[1].x + h1.y*cur.Ur[1].y + h1.z*cur.Ur[1].z + h1.w*cur.Ur[1].w;
        dzp += h2.x*cur.Ur[2].x + h2.y*cur.Ur[2].y + h2.z*cur.Ur[2].z + h2.w*cur.Ur[2].w;
        dzp += h3.x*cur.Ur[3].x + h3.y*cur.Ur[3].y + h3.z*cur.Ur[3].z + h3.w*cur.Ur[3].w;
        dzp += __shfl_xor(dzp, 16);
        dzp += __shfl_xor(dzp, 32);
        float dz = dzp * (1.f/64.f);
        float dl = -e  * (1.f/64.f);
        int st = sidx & 3;
        float wgt = (st == 0 || st == 3) ? 1.f : 2.f;
        zacc += wgt * dz;
        lacc += wgt * dl;
        if (st < 3){
            float aa = (st == 2) ? 1.0f : 0.5f;
            zs = z + aa * dt * dz;
        } else {
            z  += (dt/6.f) * zacc;
            lp += (dt/6.f) * lacc;
            zs = z;
            zacc = 0.f; lacc = 0.f;
        }
        if (lane < 16) zsl[lane] = zs;
        cur = nxt;
    }
    float sq = z * z;
#pragma unroll
    for (int off = 1; off < 16; off <<= 1) sq += __shfl_xor(sq, off, 16);
    float logp = -0.5f * (16.f*1.8378770664093453f + 16.f*(-2.302585092994046f) + sq*10.f);
    if (lane == 0) part[blockIdx.x] = logp - lp;
}

__global__ void k_final(const float* __restrict__ part, float* __restrict__ out){
    __shared__ float red[256];
    int tid = threadIdx.x;
    float s = 0.f;
#pragma unroll
    for (int k = 0; k < 8; k++) s += part[tid + k*256];
    red[tid] = s;
    __syncthreads();
    for (int st = 128; st > 0; st >>= 1){
        if (tid < st) red[tid] += red[tid + st];
        __syncthreads();
    }
    if (tid == 0) out[1605632] = red[0] * (1.f/2048.f);
}

extern "C" void kernel_launch(void* const* d_in, const int* in_sizes, int n_in,
                              void* d_out, int out_size, void* d_ws, size_t ws_size,
                              hipStream_t stream){
    const float* x   = (const float*)d_in[0];
    const float* c0w = (const float*)d_in[1];
    const float* c0b = (const float*)d_in[2];
    const float* c1w = (const float*)d_in[3];
    const float* c1b = (const float*)d_in[4];
    const float* c2w = (const float*)d_in[5];
    const float* c2b = (const float*)d_in[6];
    const float* elw = (const float*)d_in[7];
    const float* elb = (const float*)d_in[8];
    const float* dlw = (const float*)d_in[9];
    const float* dlb = (const float*)d_in[10];
    const float* t0w = (const float*)d_in[11];
    const float* t0b = (const float*)d_in[12];
    const float* t1w = (const float*)d_in[13];
    const float* t1b = (const float*)d_in[14];
    const float* t2w = (const float*)d_in[15];
    const float* t2b = (const float*)d_in[16];
    const float* h1w = (const float*)d_in[17];
    const float* h1b = (const float*)d_in[18];
    const float* h2w = (const float*)d_in[19];
    const float* h2b = (const float*)d_in[20];
    const float* h3w = (const float*)d_in[21];
    const float* h3b = (const float*)d_in[22];

    float* ws   = (float*)d_ws;
    float* z1   = ws;                          // 32768 f
    float* hyp  = z1 + 32768;                  // 184320 f (max of both layouts)
    float* part = hyp + 184320;                // 2048 f
    float* p2ws = part + 2048;                 // 5120 f
    float* p3ws = p2ws + 5120;                 // 256000 f (80*3200)
    unsigned short* wc1  = (unsigned short*)(p3ws + 256000);  // 9216 each
    unsigned short* wc2  = wc1 + 9216;
    unsigned short* wt0  = wc2 + 9216;
    unsigned short* wt1  = wt0 + 9216;
    unsigned short* elwT = wt1 + 9216;         // 247808
    unsigned short* dlwT = elwT + 247808;      // 247808
    unsigned short* act  = dlwT + 247808;      // byte offset 2,985,984
    float* rec  = (float*)d_out;

    // X/Y alternating activation buffers: per-image 21632 (Y) + 25088 (X)
    // shorts = 93440 B
    const size_t MISC = 2985984;
    int CH = 0;
    const int cands[6] = {2048, 1024, 512, 256, 128, 64};
    for (int c = 0; c < 6; c++){
        size_t need = MISC + (size_t)cands[c] * 93440;
        if (need <= ws_size){ CH = cands[c]; break; }
    }

    if (CH == 0){
        // tiny-ws fallback (old hyp layout + proven fused path)
        k_hyper<<<80, 256, 0, stream>>>(h1w, h1b, h2w, h2b, h3w, h3b, hyp);
        k_prep <<<64,   256, 0, stream>>>(c1w, c2w, t0w, t1w, elw, dlw, elb,
                                          wc1, wc2, wt0, wt1, wt1, wt1, z1, 0);
        k_enc_f<<<2048, 256, 0, stream>>>(x, c0w, c0b, wc1, c1b, wc2, c2b, elw, elb, z1);
        k_cnf_f<<<2048,  64, 0, stream>>>(z1, hyp, part);
        k_dec_f<<<2048, 256, 0, stream>>>(z1, dlw, dlb, wt0, t0b, wt1, t1b, t2w, t2b, rec);
        k_final<<<1,    256, 0, stream>>>(part, rec);
        return;
    }

    k_hyp1<<<80,           64, 0, stream>>>(h1w, h1b, h2w, h2b, p2ws);
    k_hyp2<<<dim3(13,80), 256, 0, stream>>>(p2ws, h3w, h3b, p3ws);
    k_hyp3<<<80,          256, 0, stream>>>(p3ws, hyp);

    k_prep<<<64, 256, 0, stream>>>(c1w, c2w, t0w, t1w, elw, dlw, elb,
                                   wc1, wc2, wt0, wt1, elwT, dlwT, z1, 1);

    unsigned short* Y = act;                           // CH*21632: A0/A2/D0/D2
    unsigned short* X = Y + (size_t)CH*21632;          // CH*25088: A1/D1

    for (int cb = 0; cb < Bsz; cb += CH){
        k_conv0<<<(CH*676 + 255)/256, 256, 0, stream>>>(x, c0w, c0b, Y, cb, CH);
        k_convM<26,24,24, 0, 21632, 25088><<<(CH*36 + 15)/16, 256, 0, stream>>>(Y, wc1, c1b, X, CH);
        k_convM<24,22,22, 0, 25088, 21632><<<(CH*31 + 15)/16, 256, 0, stream>>>(X, wc2, c2b, Y, CH);
        k_encg<<<dim3(CH/16, 4), 256, 0, stream>>>(Y, elwT, z1, cb, CH);
        k_decg<<<dim3(66, CH/16), 256, 0, stream>>>(z1, dlwT, dlb, Y, X, cb, CH);
        k_convM<26,24,28,58, 21632, 25088><<<(CH*36 + 15)/16, 256, 0, stream>>>(Y, wt0, t0b, X, CH);
        k_convM<28,26,26, 0, 25088, 21632><<<(CH*43 + 15)/16, 256, 0, stream>>>(X, wt1, t1b, Y, CH);
        k_convT2<<<(CH*784 + 255)/256, 256, 0, stream>>>(Y, t2w, t2b, rec, cb, CH);
    }
    k_cnfM <<<128,  64, 0, stream>>>(z1, hyp, part);
    k_final<<<1,   256, 0, stream>>>(part, rec);
}